// Round 5
// baseline (409.208 us; speedup 1.0000x reference)
//
#include <hip/hip_runtime.h>
#include <stdint.h>

typedef unsigned short u16;
typedef __attribute__((ext_vector_type(8))) short short8;
typedef __attribute__((ext_vector_type(4))) float f32x4;

#define NEG_F (-3.402823466e+38f)

__device__ __forceinline__ u16 f2bf(float x) {
    uint32_t u = __builtin_bit_cast(uint32_t, x);
    u = (u + 0x7fffu + ((u >> 16) & 1u)) >> 16;
    return (u16)u;
}
__device__ __forceinline__ float bf2f(u16 b) {
    uint32_t u = ((uint32_t)b) << 16;
    return __builtin_bit_cast(float, u);
}

__device__ __forceinline__ void gload_lds16(const void* g, void* l) {
    __builtin_amdgcn_global_load_lds((const __attribute__((address_space(1))) void*)g,
                                     (__attribute__((address_space(3))) void*)l, 16, 0, 0);
}

// One DPP argmax step: pull (v,idx) from another lane per CTRL, keep the
// larger v (ties -> smaller idx).
template <int CTRL, int RMASK>
__device__ __forceinline__ void argmax_dpp_step(float& v, int& i) {
    const int vb = __builtin_bit_cast(int, v);
    const int vv = __builtin_amdgcn_update_dpp(vb, vb, CTRL, RMASK, 0xf, false);
    const int ii = __builtin_amdgcn_update_dpp(i, i, CTRL, RMASK, 0xf, false);
    const float fv = __builtin_bit_cast(float, vv);
    if (fv > v || (fv == v && ii < i)) { v = fv; i = ii; }
}

// Full wave64 argmax -> result lands in lane 63.
__device__ __forceinline__ void argmax_wave(float& v, int& i) {
    argmax_dpp_step<0x111, 0xf>(v, i);  // row_shr:1
    argmax_dpp_step<0x112, 0xf>(v, i);  // row_shr:2
    argmax_dpp_step<0x114, 0xf>(v, i);  // row_shr:4
    argmax_dpp_step<0x118, 0xf>(v, i);  // row_shr:8
    argmax_dpp_step<0x142, 0xa>(v, i);  // row_bcast:15 -> rows 1,3
    argmax_dpp_step<0x143, 0xc>(v, i);  // row_bcast:31 -> rows 2,3
}

// ---------------------------------------------------------------------------
// FPS v3: one block per batch, 256 threads (4 waves). POINTS LIVE IN LDS
// (f32x4[8192] = 128 KiB) -- round-4 post-mortem: with the points as per-
// thread register arrays the compiler rematerialized them as global reloads
// every iteration (VGPR_Count=104 < the 160 regs needed), making every
// iteration ~96 L2 loads/thread. Only md[32] stays in VGPRs.
// Per iteration: 32x ds_read_b128 + distance/argmax, DPP wave argmax, LDS
// key slot per wave, ONE barrier, 4-key register combine (ping-pong slots),
// centroid re-fetched via same-address ds_read broadcast.
//
// Selection arithmetic (mean order, distance expression, tie-breaks, t==0
// not touching md) is source-identical to the passing round-4 kernel.
// ---------------------------------------------------------------------------
__global__ __launch_bounds__(256, 1) void fps_kernel(const float* __restrict__ coords,
                                                     const float* __restrict__ times,
                                                     float* __restrict__ cent_ws,
                                                     float* __restrict__ cent_out,
                                                     float* __restrict__ mask_out) {
    const int b = blockIdx.x;
    const int tid = threadIdx.x;   // 0..255
    const int lane = tid & 63;
    const int wid = tid >> 6;      // physical wave 0..3

    __shared__ f32x4 pts[8192];            // 128 KiB
    __shared__ unsigned long long kslot[2][4];
    __shared__ float redv[16][4];

    float md[32];
    // Per-q partial sums replicate the 1024-thread version's order exactly:
    // virtual thread vt = tid + 256*q owned points p = j*1024 + vt
    // = (4j+q)*256 + tid, summed ascending j. Accumulating point j into
    // accumulator q = j&3 in ascending j gives identical per-q sums.
    float sx[4] = {0.f, 0.f, 0.f, 0.f};
    float sy[4] = {0.f, 0.f, 0.f, 0.f};
    float sz[4] = {0.f, 0.f, 0.f, 0.f};
    float sw[4] = {0.f, 0.f, 0.f, 0.f};
#pragma unroll
    for (int j = 0; j < 32; ++j) {
        const int p = j * 256 + tid;
        const int n = b * 8192 + p;
        const float x = coords[3 * n + 0];
        const float y = coords[3 * n + 1];
        const float z = coords[3 * n + 2];
        const float w = times[n];
        pts[p] = f32x4{x, y, z, w};
        const int q = j & 3;
        sx[q] += x; sy[q] += y; sz[q] += z; sw[q] += w;
        md[j] = __builtin_inff();
    }

#pragma unroll
    for (int q = 0; q < 4; ++q) {
        float ax = sx[q], ay = sy[q], az = sz[q], aw = sw[q];
#pragma unroll
        for (int off = 32; off > 0; off >>= 1) {
            ax += __shfl_down(ax, off);
            ay += __shfl_down(ay, off);
            az += __shfl_down(az, off);
            aw += __shfl_down(aw, off);
        }
        if (lane == 0) {
            redv[wid + 4 * q][0] = ax;
            redv[wid + 4 * q][1] = ay;
            redv[wid + 4 * q][2] = az;
            redv[wid + 4 * q][3] = aw;
        }
    }
    __syncthreads();
    float c0 = 0.f, c1 = 0.f, c2 = 0.f, c3 = 0.f;
#pragma unroll
    for (int w = 0; w < 16; ++w) { c0 += redv[w][0]; c1 += redv[w][1]; c2 += redv[w][2]; c3 += redv[w][3]; }
    c0 *= (1.0f / 8192.0f);
    c1 *= (1.0f / 8192.0f);
    c2 *= (1.0f / 8192.0f);
    c3 *= (1.0f / 8192.0f);

    for (int t = 0; t < 128; ++t) {
        float v = -__builtin_inff();
        int jb = 0;
        if (t == 0) {
            // distances to the mean: pick argmax only, do NOT touch md
#pragma unroll
            for (int j = 0; j < 32; ++j) {
                const f32x4 P = pts[j * 256 + tid];
                const float dx = P[0] - c0, dy = P[1] - c1, dz = P[2] - c2, dw = P[3] - c3;
                const float d2 = dx * dx + dy * dy + dz * dz + dw * dw;
                if (d2 > v) { v = d2; jb = j; }
            }
        } else {
#pragma unroll
            for (int j = 0; j < 32; ++j) {
                const f32x4 P = pts[j * 256 + tid];
                const float dx = P[0] - c0, dy = P[1] - c1, dz = P[2] - c2, dw = P[3] - c3;
                const float d2 = dx * dx + dy * dy + dz * dz + dw * dw;
                const float nm = fminf(md[j], d2);
                md[j] = nm;
                if (nm > v) { v = nm; jb = j; }
            }
        }
        int idx = jb * 256 + tid;
        argmax_wave(v, idx);
        if (lane == 63) {
            const uint32_t bv = __builtin_bit_cast(uint32_t, v);
            const uint32_t mk = (bv & 0x80000000u) ? ~bv : (bv | 0x80000000u);
            kslot[t & 1][wid] = ((unsigned long long)mk << 32) | (uint32_t)(0x7FFFFFFF - idx);
        }
        __syncthreads();
        unsigned long long kk = kslot[t & 1][0];
#pragma unroll
        for (int w = 1; w < 4; ++w) {
            const unsigned long long o = kslot[t & 1][w];
            kk = (o > kk) ? o : kk;
        }
        const int sel = 0x7FFFFFFF - (int)(uint32_t)(kk & 0xFFFFFFFFull);
        const f32x4 C = pts[sel];   // same address across all lanes: broadcast
        c0 = C[0]; c1 = C[1]; c2 = C[2]; c3 = C[3];
        if (tid == (sel & 255)) {
            const int js = sel >> 8;
#pragma unroll
            for (int j = 0; j < 32; ++j)
                if (j == js) md[j] = NEG_F;
        }
        if (tid == 0) {
            const int o = (b * 128 + t) * 4;
            cent_ws[o + 0] = c0; cent_ws[o + 1] = c1; cent_ws[o + 2] = c2; cent_ws[o + 3] = c3;
            cent_out[o + 0] = c0; cent_out[o + 1] = c1; cent_out[o + 2] = c2; cent_out[o + 3] = c3;
        }
    }
    if (tid < 128) mask_out[b * 128 + tid] = 1.0f;
}

// ---------------------------------------------------------------------------
// KNN: one block per centroid (B*T=1024 blocks). d2 in LDS, 16 rounds of
// block argmin with lower-index tie-break (matches lax.top_k on -d2).
// ---------------------------------------------------------------------------
__global__ __launch_bounds__(256) void knn_kernel(const float* __restrict__ coords,
                                                  const float* __restrict__ times,
                                                  const float* __restrict__ cent,
                                                  int* __restrict__ knn) {
    __shared__ float d2s[8192];
    __shared__ float rbv[4];
    __shared__ int rbi[4];
    const int q = blockIdx.x;
    const int b = q >> 7;
    const int tid = threadIdx.x;
    const int lane = tid & 63;
    const int wid = tid >> 6;
    const float c0 = cent[q * 4 + 0], c1 = cent[q * 4 + 1], c2 = cent[q * 4 + 2], c3 = cent[q * 4 + 3];
    const float cc = c0 * c0 + c1 * c1 + c2 * c2 + c3 * c3;
    for (int p = tid; p < 8192; p += 256) {
        const int n = b * 8192 + p;
        const float x0 = coords[3 * n], x1 = coords[3 * n + 1], x2 = coords[3 * n + 2], x3 = times[n];
        const float pp = x0 * x0 + x1 * x1 + x2 * x2 + x3 * x3;
        const float dt = x0 * c0 + x1 * c1 + x2 * c2 + x3 * c3;
        d2s[p] = cc + pp - 2.0f * dt;
    }
    __syncthreads();
    for (int r = 0; r < 16; ++r) {
        float v = __builtin_inff();
        int idx = 1 << 30;
        for (int s = 0; s < 32; ++s) {
            const int p = s * 256 + tid;
            const float d = d2s[p];
            if (d < v) { v = d; idx = p; }
        }
#pragma unroll
        for (int off = 32; off > 0; off >>= 1) {
            const float ov = __shfl_down(v, off);
            const int oi = __shfl_down(idx, off);
            if (ov < v || (ov == v && oi < idx)) { v = ov; idx = oi; }
        }
        if (lane == 0) { rbv[wid] = v; rbi[wid] = idx; }
        __syncthreads();
        if (tid == 0) {
            float bb = rbv[0]; int bi = rbi[0];
            for (int w = 1; w < 4; ++w)
                if (rbv[w] < bb || (rbv[w] == bb && rbi[w] < bi)) { bb = rbv[w]; bi = rbi[w]; }
            knn[q * 16 + r] = bi;
            d2s[bi] = __builtin_inff();
        }
        __syncthreads();
    }
}

// ---------------------------------------------------------------------------
// Gather features for the 16384 knn rows into bf16 A0 (K padded 32->64 with 0)
// ---------------------------------------------------------------------------
__global__ __launch_bounds__(256) void gather_kernel(const float* __restrict__ feat,
                                                     const int* __restrict__ knn,
                                                     u16* __restrict__ A0) {
    const int idx = blockIdx.x * 256 + threadIdx.x;  // 16384*64
    const int g = idx >> 6;
    const int c = idx & 63;
    const int b = g >> 11;  // g / (T*K)=g/2048
    const int n = b * 8192 + knn[g];
    const float v = (c < 32) ? feat[(size_t)n * 32 + c] : 0.0f;
    A0[idx] = f2bf(v);
}

// All six weight transposes in ONE launch. Segment boundaries are 256-aligned
// so each block is branch-uniform.
template <int K, int N, int KP>
__device__ __forceinline__ void tp_one(const float* __restrict__ W, u16* __restrict__ Wt, int local) {
    const int n = local / KP;
    const int k = local - n * KP;
    const float v = (k < K) ? W[(size_t)k * N + n] : 0.0f;
    Wt[local] = f2bf(v);
}

__global__ __launch_bounds__(256) void transpose_all(const float* __restrict__ W0,
                                                     const float* __restrict__ W1,
                                                     const float* __restrict__ W2,
                                                     const float* __restrict__ W3,
                                                     const float* __restrict__ Wn0,
                                                     const float* __restrict__ Wn1,
                                                     u16* __restrict__ W0t, u16* __restrict__ W1t,
                                                     u16* __restrict__ W2t, u16* __restrict__ W3t,
                                                     u16* __restrict__ Wn0t, u16* __restrict__ Wn1t) {
    const int idx = blockIdx.x * 256 + threadIdx.x;
    if (idx < 16384) tp_one<32, 256, 64>(W0, W0t, idx);
    else if (idx < 147456) tp_one<256, 512, 256>(W1, W1t, idx - 16384);
    else if (idx < 540672) tp_one<512, 768, 512>(W2, W2t, idx - 147456);
    else if (idx < 1130496) tp_one<768, 768, 768>(W3, W3t, idx - 540672);
    else if (idx < 1720320) tp_one<768, 768, 768>(Wn0, Wn0t, idx - 1130496);
    else tp_one<768, 768, 768>(Wn1, Wn1t, idx - 1720320);
}

// Max-pool over K=16 gathered rows: PF (16384,768) bf16 -> pooled (1024,768)
__global__ __launch_bounds__(256) void pool_kernel(const u16* __restrict__ PF,
                                                   u16* __restrict__ pooled) {
    const int idx = blockIdx.x * 256 + threadIdx.x;  // 1024*768
    const int q = idx / 768;
    const int c = idx - q * 768;
    const u16* base = PF + (size_t)q * 16 * 768 + c;
    float best = -__builtin_inff();
    u16 bb = 0;
#pragma unroll
    for (int kk = 0; kk < 16; ++kk) {
        const u16 u = base[kk * 768];
        const float f = bf2f(u);
        if (f > best) { best = f; bb = u; }
    }
    pooled[idx] = bb;
}

// ---------------------------------------------------------------------------
// bf16 MFMA GEMM: C(M,N) = relu?(A(M,K) @ W(K,N) + bias), W given as Wt(N,K).
// 128x128 tile, BK=64, 4 waves (2x2 of 64x64), global_load_lds width 16,
// source-side XOR swizzle so ds_read_b128 is ~conflict-free.
// ---------------------------------------------------------------------------
template <int RELU, int OUTF32>
__global__ __launch_bounds__(256) void gemm_kernel(const u16* __restrict__ A,
                                                   const u16* __restrict__ Bt,
                                                   const float* __restrict__ bias,
                                                   void* __restrict__ Cv,
                                                   int M, int N, int K) {
    (void)M;
    __shared__ __align__(16) u16 As[128 * 64];
    __shared__ __align__(16) u16 Bs[128 * 64];
    const int tid = threadIdx.x;
    const int lane = tid & 63;
    const int wid = tid >> 6;
    const int brow = blockIdx.x * 128;
    const int bcol = blockIdx.y * 128;
    const int wm = (wid >> 1) * 64;
    const int wn = (wid & 1) * 64;

    f32x4 acc[4][4];
#pragma unroll
    for (int m = 0; m < 4; ++m)
#pragma unroll
        for (int n = 0; n < 4; ++n)
            acc[m][n] = f32x4{0.f, 0.f, 0.f, 0.f};

    const int srow = tid >> 3;    // 0..31
    const int schunk = tid & 7;   // 16B chunk within a 128B row
    const uint32_t lds_wave_base = (uint32_t)(wid * 1024);

    for (int k0 = 0; k0 < K; k0 += 64) {
#pragma unroll
        for (int i = 0; i < 4; ++i) {
            const int row = i * 32 + srow;
            const int sc = schunk ^ (row & 7);  // inverse-swizzled SOURCE chunk
            const u16* ga = A + (size_t)(brow + row) * K + (size_t)(k0 + sc * 8);
            const u16* gb = Bt + (size_t)(bcol + row) * K + (size_t)(k0 + sc * 8);
            const uint32_t lb = (uint32_t)(i * 4096) + lds_wave_base;  // wave-uniform base
            gload_lds16(ga, (char*)As + lb);
            gload_lds16(gb, (char*)Bs + lb);
        }
        __syncthreads();
#pragma unroll
        for (int kc = 0; kc < 2; ++kc) {
            short8 af[4], bfr[4];
#pragma unroll
            for (int m = 0; m < 4; ++m) {
                const int row = wm + m * 16 + (lane & 15);
                const int sc = (kc * 4 + (lane >> 4)) ^ (row & 7);
                af[m] = *(const short8*)(As + row * 64 + sc * 8);
            }
#pragma unroll
            for (int n = 0; n < 4; ++n) {
                const int row = wn + n * 16 + (lane & 15);
                const int sc = (kc * 4 + (lane >> 4)) ^ (row & 7);
                bfr[n] = *(const short8*)(Bs + row * 64 + sc * 8);
            }
#pragma unroll
            for (int m = 0; m < 4; ++m)
#pragma unroll
                for (int n = 0; n < 4; ++n)
                    acc[m][n] = __builtin_amdgcn_mfma_f32_16x16x32_bf16(af[m], bfr[n], acc[m][n], 0, 0, 0);
        }
        __syncthreads();
    }

#pragma unroll
    for (int m = 0; m < 4; ++m) {
        const int row0 = brow + wm + m * 16 + ((lane >> 4) << 2);
#pragma unroll
        for (int n = 0; n < 4; ++n) {
            const int col = bcol + wn + n * 16 + (lane & 15);
            const float bv = bias[col];
#pragma unroll
            for (int r = 0; r < 4; ++r) {
                float v = acc[m][n][r] + bv;
                if (RELU) v = fmaxf(v, 0.0f);
                if (OUTF32) ((float*)Cv)[(size_t)(row0 + r) * N + col] = v;
                else ((u16*)Cv)[(size_t)(row0 + r) * N + col] = f2bf(v);
            }
        }
    }
}

// ---------------------------------------------------------------------------
extern "C" void kernel_launch(void* const* d_in, const int* in_sizes, int n_in,
                              void* d_out, int out_size, void* d_ws, size_t ws_size,
                              hipStream_t stream) {
    (void)in_sizes; (void)n_in; (void)out_size; (void)ws_size;
    const float* coords = (const float*)d_in[0];
    const float* features = (const float*)d_in[1];
    const float* times = (const float*)d_in[3];
    const float* W0 = (const float*)d_in[4];
    const float* b0 = (const float*)d_in[5];
    const float* W1 = (const float*)d_in[6];
    const float* b1 = (const float*)d_in[7];
    const float* W2 = (const float*)d_in[8];
    const float* b2 = (const float*)d_in[9];
    const float* W3 = (const float*)d_in[10];
    const float* b3 = (const float*)d_in[11];
    const float* Wn0 = (const float*)d_in[12];
    const float* bn0 = (const float*)d_in[13];
    const float* Wn1 = (const float*)d_in[14];
    const float* bn1 = (const float*)d_in[15];

    char* ws = (char*)d_ws;
    float* cent = (float*)(ws + 0);           // 1024*4 f32
    int* knn = (int*)(ws + 16384);            // 16384 int
    u16* W0t = (u16*)(ws + 81920);            // 256x64
    u16* W1t = (u16*)(ws + 114688);           // 512x256
    u16* W2t = (u16*)(ws + 376832);           // 768x512
    u16* W3t = (u16*)(ws + 1163264);          // 768x768
    u16* Wn0t = (u16*)(ws + 2342912);         // 768x768
    u16* Wn1t = (u16*)(ws + 3522560);         // 768x768
    u16* bufX = (u16*)(ws + 4702208);         // 16384x768 bf16 max
    u16* bufY = (u16*)(ws + 29868032);        // 16384x768 bf16 max

    float* tokens_out = (float*)d_out;                    // (8,128,768)
    float* cent_out = (float*)d_out + 786432;             // (8,128,4)
    float* mask_out = (float*)d_out + 786432 + 4096;      // (8,128)

    // all weight transposes in one launch
    transpose_all<<<9024, 256, 0, stream>>>(W0, W1, W2, W3, Wn0, Wn1,
                                            W0t, W1t, W2t, W3t, Wn0t, Wn1t);

    // FPS -> centroids (also fills centroid + mask outputs)
    fps_kernel<<<8, 256, 0, stream>>>(coords, times, cent, cent_out, mask_out);
    // KNN top-16 per centroid
    knn_kernel<<<1024, 256, 0, stream>>>(coords, times, cent, knn);
    // gather knn rows' features (bf16, K padded to 64)
    gather_kernel<<<4096, 256, 0, stream>>>(features, knn, bufX);

    // MLP on gathered rows (M = 16384)
    gemm_kernel<1, 0><<<dim3(128, 2), 256, 0, stream>>>(bufX, W0t, b0, bufY, 16384, 256, 64);
    gemm_kernel<1, 0><<<dim3(128, 4), 256, 0, stream>>>(bufY, W1t, b1, bufX, 16384, 512, 256);
    gemm_kernel<1, 0><<<dim3(128, 6), 256, 0, stream>>>(bufX, W2t, b2, bufY, 16384, 768, 512);
    gemm_kernel<0, 0><<<dim3(128, 6), 256, 0, stream>>>(bufY, W3t, b3, bufX, 16384, 768, 768);

    // max-pool over the 16 neighbors
    pool_kernel<<<3072, 256, 0, stream>>>(bufX, bufY);

    // token MLP (M = 1024)
    gemm_kernel<1, 0><<<dim3(8, 6), 256, 0, stream>>>(bufY, Wn0t, bn0, bufX, 1024, 768, 768);
    gemm_kernel<0, 1><<<dim3(8, 6), 256, 0, stream>>>(bufX, Wn1t, bn1, tokens_out, 1024, 768, 768);
}

// Round 6
// 379.033 us; speedup vs baseline: 1.0796x; 1.0796x over previous
//
#include <hip/hip_runtime.h>
#include <stdint.h>

typedef unsigned short u16;
typedef __attribute__((ext_vector_type(8))) short short8;
typedef __attribute__((ext_vector_type(4))) float f32x4;

#define NEG_F (-3.402823466e+38f)

__device__ __forceinline__ u16 f2bf(float x) {
    uint32_t u = __builtin_bit_cast(uint32_t, x);
    u = (u + 0x7fffu + ((u >> 16) & 1u)) >> 16;
    return (u16)u;
}
__device__ __forceinline__ float bf2f(u16 b) {
    uint32_t u = ((uint32_t)b) << 16;
    return __builtin_bit_cast(float, u);
}

__device__ __forceinline__ void gload_lds16(const void* g, void* l) {
    __builtin_amdgcn_global_load_lds((const __attribute__((address_space(1))) void*)g,
                                     (__attribute__((address_space(3))) void*)l, 16, 0, 0);
}

// One DPP argmax step: pull (v,idx) from another lane per CTRL, keep the
// larger v (ties -> smaller idx).
template <int CTRL, int RMASK>
__device__ __forceinline__ void argmax_dpp_step(float& v, int& i) {
    const int vb = __builtin_bit_cast(int, v);
    const int vv = __builtin_amdgcn_update_dpp(vb, vb, CTRL, RMASK, 0xf, false);
    const int ii = __builtin_amdgcn_update_dpp(i, i, CTRL, RMASK, 0xf, false);
    const float fv = __builtin_bit_cast(float, vv);
    if (fv > v || (fv == v && ii < i)) { v = fv; i = ii; }
}

// Full wave64 argmax -> result lands in lane 63.
__device__ __forceinline__ void argmax_wave(float& v, int& i) {
    argmax_dpp_step<0x111, 0xf>(v, i);  // row_shr:1
    argmax_dpp_step<0x112, 0xf>(v, i);  // row_shr:2
    argmax_dpp_step<0x114, 0xf>(v, i);  // row_shr:4
    argmax_dpp_step<0x118, 0xf>(v, i);  // row_shr:8
    argmax_dpp_step<0x142, 0xa>(v, i);  // row_bcast:15 -> rows 1,3
    argmax_dpp_step<0x143, 0xc>(v, i);  // row_bcast:31 -> rows 2,3
}

// ---------------------------------------------------------------------------
// FPS v4: one block per batch, 256 threads (4 waves, 1/SIMD), 32 pts/thread
// PINNED IN VGPRS via asm "+v" (round-5 post-mortem: without the pin the
// compiler rematerializes the point loads every iteration -- rounds 2/4
// reported VGPR=32/104 < the 160 needed, i.e. the j-loop was re-reading
// global/L2 each of the 128 iterations; round-5's LDS path was worse at
// 1 wave/SIMD). With the pin the j-loop does ZERO memory ops.
// LDS pts[] kept only for the same-address broadcast fetch of the selected
// centroid. One barrier per iteration; ping-pong key slots.
//
// Selection arithmetic (mean order, distance expression, tie-breaks, t==0
// not touching md) is source-identical to the passing round-4/5 kernels.
// ---------------------------------------------------------------------------
__global__ __launch_bounds__(256, 1) void fps_kernel(const float* __restrict__ coords,
                                                     const float* __restrict__ times,
                                                     float* __restrict__ cent_ws,
                                                     float* __restrict__ cent_out,
                                                     float* __restrict__ mask_out) {
    const int b = blockIdx.x;
    const int tid = threadIdx.x;   // 0..255
    const int lane = tid & 63;
    const int wid = tid >> 6;      // physical wave 0..3

    __shared__ f32x4 pts[8192];            // 128 KiB (broadcast fetch only)
    __shared__ unsigned long long kslot[2][4];
    __shared__ float redv[16][4];

    float px[32], py[32], pz[32], pw[32], md[32];
#pragma unroll
    for (int j = 0; j < 32; ++j) {
        const int p = j * 256 + tid;
        const int n = b * 8192 + p;
        px[j] = coords[3 * n + 0];
        py[j] = coords[3 * n + 1];
        pz[j] = coords[3 * n + 2];
        pw[j] = times[n];
        pts[p] = f32x4{px[j], py[j], pz[j], pw[j]};
        md[j] = __builtin_inff();
    }
    // Pin the point state in registers: "+v" makes each value an asm output,
    // so the compiler cannot rematerialize the global loads inside the t-loop.
#pragma unroll
    for (int j = 0; j < 32; ++j) {
        asm volatile("" : "+v"(px[j]), "+v"(py[j]), "+v"(pz[j]), "+v"(pw[j]));
    }

    // Mean: replicate the 1024-thread version exactly. Virtual thread
    // vt = tid + 256*q owned points p = j*1024 + vt = (4j+q)*256 + tid,
    // summed in ascending j; its wave was w = wid + 4*q; wave sums combined
    // in ascending w.
#pragma unroll
    for (int q = 0; q < 4; ++q) {
        float sx = 0.f, sy = 0.f, sz = 0.f, sw = 0.f;
#pragma unroll
        for (int j = 0; j < 8; ++j) {
            const int jj = 4 * j + q;
            sx += px[jj]; sy += py[jj]; sz += pz[jj]; sw += pw[jj];
        }
#pragma unroll
        for (int off = 32; off > 0; off >>= 1) {
            sx += __shfl_down(sx, off);
            sy += __shfl_down(sy, off);
            sz += __shfl_down(sz, off);
            sw += __shfl_down(sw, off);
        }
        if (lane == 0) {
            redv[wid + 4 * q][0] = sx;
            redv[wid + 4 * q][1] = sy;
            redv[wid + 4 * q][2] = sz;
            redv[wid + 4 * q][3] = sw;
        }
    }
    __syncthreads();
    float c0 = 0.f, c1 = 0.f, c2 = 0.f, c3 = 0.f;
#pragma unroll
    for (int w = 0; w < 16; ++w) { c0 += redv[w][0]; c1 += redv[w][1]; c2 += redv[w][2]; c3 += redv[w][3]; }
    c0 *= (1.0f / 8192.0f);
    c1 *= (1.0f / 8192.0f);
    c2 *= (1.0f / 8192.0f);
    c3 *= (1.0f / 8192.0f);

    for (int t = 0; t < 128; ++t) {
        float v = -__builtin_inff();
        int jb = 0;
        if (t == 0) {
            // distances to the mean: pick argmax only, do NOT touch md
#pragma unroll
            for (int j = 0; j < 32; ++j) {
                const float dx = px[j] - c0, dy = py[j] - c1, dz = pz[j] - c2, dw = pw[j] - c3;
                const float d2 = dx * dx + dy * dy + dz * dz + dw * dw;
                if (d2 > v) { v = d2; jb = j; }
            }
        } else {
#pragma unroll
            for (int j = 0; j < 32; ++j) {
                const float dx = px[j] - c0, dy = py[j] - c1, dz = pz[j] - c2, dw = pw[j] - c3;
                const float d2 = dx * dx + dy * dy + dz * dz + dw * dw;
                const float nm = fminf(md[j], d2);
                md[j] = nm;
                if (nm > v) { v = nm; jb = j; }
            }
        }
        int idx = jb * 256 + tid;
        argmax_wave(v, idx);
        if (lane == 63) {
            const uint32_t bv = __builtin_bit_cast(uint32_t, v);
            const uint32_t mk = (bv & 0x80000000u) ? ~bv : (bv | 0x80000000u);
            kslot[t & 1][wid] = ((unsigned long long)mk << 32) | (uint32_t)(0x7FFFFFFF - idx);
        }
        __syncthreads();
        unsigned long long kk = kslot[t & 1][0];
#pragma unroll
        for (int w = 1; w < 4; ++w) {
            const unsigned long long o = kslot[t & 1][w];
            kk = (o > kk) ? o : kk;
        }
        const int sel = 0x7FFFFFFF - (int)(uint32_t)(kk & 0xFFFFFFFFull);
        const f32x4 C = pts[sel];   // same address across all lanes: broadcast
        c0 = C[0]; c1 = C[1]; c2 = C[2]; c3 = C[3];
        if (tid == (sel & 255)) {
            const int js = sel >> 8;
#pragma unroll
            for (int j = 0; j < 32; ++j)
                if (j == js) md[j] = NEG_F;
        }
        if (tid == 0) {
            const int o = (b * 128 + t) * 4;
            cent_ws[o + 0] = c0; cent_ws[o + 1] = c1; cent_ws[o + 2] = c2; cent_ws[o + 3] = c3;
            cent_out[o + 0] = c0; cent_out[o + 1] = c1; cent_out[o + 2] = c2; cent_out[o + 3] = c3;
        }
    }
    if (tid < 128) mask_out[b * 128 + tid] = 1.0f;
}

// ---------------------------------------------------------------------------
// KNN: one block per centroid (B*T=1024 blocks). d2 in LDS, 16 rounds of
// block argmin with lower-index tie-break (matches lax.top_k on -d2).
// ---------------------------------------------------------------------------
__global__ __launch_bounds__(256) void knn_kernel(const float* __restrict__ coords,
                                                  const float* __restrict__ times,
                                                  const float* __restrict__ cent,
                                                  int* __restrict__ knn) {
    __shared__ float d2s[8192];
    __shared__ float rbv[4];
    __shared__ int rbi[4];
    const int q = blockIdx.x;
    const int b = q >> 7;
    const int tid = threadIdx.x;
    const int lane = tid & 63;
    const int wid = tid >> 6;
    const float c0 = cent[q * 4 + 0], c1 = cent[q * 4 + 1], c2 = cent[q * 4 + 2], c3 = cent[q * 4 + 3];
    const float cc = c0 * c0 + c1 * c1 + c2 * c2 + c3 * c3;
    for (int p = tid; p < 8192; p += 256) {
        const int n = b * 8192 + p;
        const float x0 = coords[3 * n], x1 = coords[3 * n + 1], x2 = coords[3 * n + 2], x3 = times[n];
        const float pp = x0 * x0 + x1 * x1 + x2 * x2 + x3 * x3;
        const float dt = x0 * c0 + x1 * c1 + x2 * c2 + x3 * c3;
        d2s[p] = cc + pp - 2.0f * dt;
    }
    __syncthreads();
    for (int r = 0; r < 16; ++r) {
        float v = __builtin_inff();
        int idx = 1 << 30;
        for (int s = 0; s < 32; ++s) {
            const int p = s * 256 + tid;
            const float d = d2s[p];
            if (d < v) { v = d; idx = p; }
        }
#pragma unroll
        for (int off = 32; off > 0; off >>= 1) {
            const float ov = __shfl_down(v, off);
            const int oi = __shfl_down(idx, off);
            if (ov < v || (ov == v && oi < idx)) { v = ov; idx = oi; }
        }
        if (lane == 0) { rbv[wid] = v; rbi[wid] = idx; }
        __syncthreads();
        if (tid == 0) {
            float bb = rbv[0]; int bi = rbi[0];
            for (int w = 1; w < 4; ++w)
                if (rbv[w] < bb || (rbv[w] == bb && rbi[w] < bi)) { bb = rbv[w]; bi = rbi[w]; }
            knn[q * 16 + r] = bi;
            d2s[bi] = __builtin_inff();
        }
        __syncthreads();
    }
}

// ---------------------------------------------------------------------------
// Gather features for the 16384 knn rows into bf16 A0 (K padded 32->64 with 0)
// ---------------------------------------------------------------------------
__global__ __launch_bounds__(256) void gather_kernel(const float* __restrict__ feat,
                                                     const int* __restrict__ knn,
                                                     u16* __restrict__ A0) {
    const int idx = blockIdx.x * 256 + threadIdx.x;  // 16384*64
    const int g = idx >> 6;
    const int c = idx & 63;
    const int b = g >> 11;  // g / (T*K)=g/2048
    const int n = b * 8192 + knn[g];
    const float v = (c < 32) ? feat[(size_t)n * 32 + c] : 0.0f;
    A0[idx] = f2bf(v);
}

// All six weight transposes in ONE launch. Segment boundaries are 256-aligned
// so each block is branch-uniform.
template <int K, int N, int KP>
__device__ __forceinline__ void tp_one(const float* __restrict__ W, u16* __restrict__ Wt, int local) {
    const int n = local / KP;
    const int k = local - n * KP;
    const float v = (k < K) ? W[(size_t)k * N + n] : 0.0f;
    Wt[local] = f2bf(v);
}

__global__ __launch_bounds__(256) void transpose_all(const float* __restrict__ W0,
                                                     const float* __restrict__ W1,
                                                     const float* __restrict__ W2,
                                                     const float* __restrict__ W3,
                                                     const float* __restrict__ Wn0,
                                                     const float* __restrict__ Wn1,
                                                     u16* __restrict__ W0t, u16* __restrict__ W1t,
                                                     u16* __restrict__ W2t, u16* __restrict__ W3t,
                                                     u16* __restrict__ Wn0t, u16* __restrict__ Wn1t) {
    const int idx = blockIdx.x * 256 + threadIdx.x;
    if (idx < 16384) tp_one<32, 256, 64>(W0, W0t, idx);
    else if (idx < 147456) tp_one<256, 512, 256>(W1, W1t, idx - 16384);
    else if (idx < 540672) tp_one<512, 768, 512>(W2, W2t, idx - 147456);
    else if (idx < 1130496) tp_one<768, 768, 768>(W3, W3t, idx - 540672);
    else if (idx < 1720320) tp_one<768, 768, 768>(Wn0, Wn0t, idx - 1130496);
    else tp_one<768, 768, 768>(Wn1, Wn1t, idx - 1720320);
}

// Max-pool over K=16 gathered rows: PF (16384,768) bf16 -> pooled (1024,768)
__global__ __launch_bounds__(256) void pool_kernel(const u16* __restrict__ PF,
                                                   u16* __restrict__ pooled) {
    const int idx = blockIdx.x * 256 + threadIdx.x;  // 1024*768
    const int q = idx / 768;
    const int c = idx - q * 768;
    const u16* base = PF + (size_t)q * 16 * 768 + c;
    float best = -__builtin_inff();
    u16 bb = 0;
#pragma unroll
    for (int kk = 0; kk < 16; ++kk) {
        const u16 u = base[kk * 768];
        const float f = bf2f(u);
        if (f > best) { best = f; bb = u; }
    }
    pooled[idx] = bb;
}

// ---------------------------------------------------------------------------
// bf16 MFMA GEMM: C(M,N) = relu?(A(M,K) @ W(K,N) + bias), W given as Wt(N,K).
// 128x128 tile, BK=64, 4 waves (2x2 of 64x64), global_load_lds width 16,
// source-side XOR swizzle so ds_read_b128 is ~conflict-free.
// ---------------------------------------------------------------------------
template <int RELU, int OUTF32>
__global__ __launch_bounds__(256) void gemm_kernel(const u16* __restrict__ A,
                                                   const u16* __restrict__ Bt,
                                                   const float* __restrict__ bias,
                                                   void* __restrict__ Cv,
                                                   int M, int N, int K) {
    (void)M;
    __shared__ __align__(16) u16 As[128 * 64];
    __shared__ __align__(16) u16 Bs[128 * 64];
    const int tid = threadIdx.x;
    const int lane = tid & 63;
    const int wid = tid >> 6;
    const int brow = blockIdx.x * 128;
    const int bcol = blockIdx.y * 128;
    const int wm = (wid >> 1) * 64;
    const int wn = (wid & 1) * 64;

    f32x4 acc[4][4];
#pragma unroll
    for (int m = 0; m < 4; ++m)
#pragma unroll
        for (int n = 0; n < 4; ++n)
            acc[m][n] = f32x4{0.f, 0.f, 0.f, 0.f};

    const int srow = tid >> 3;    // 0..31
    const int schunk = tid & 7;   // 16B chunk within a 128B row
    const uint32_t lds_wave_base = (uint32_t)(wid * 1024);

    for (int k0 = 0; k0 < K; k0 += 64) {
#pragma unroll
        for (int i = 0; i < 4; ++i) {
            const int row = i * 32 + srow;
            const int sc = schunk ^ (row & 7);  // inverse-swizzled SOURCE chunk
            const u16* ga = A + (size_t)(brow + row) * K + (size_t)(k0 + sc * 8);
            const u16* gb = Bt + (size_t)(bcol + row) * K + (size_t)(k0 + sc * 8);
            const uint32_t lb = (uint32_t)(i * 4096) + lds_wave_base;  // wave-uniform base
            gload_lds16(ga, (char*)As + lb);
            gload_lds16(gb, (char*)Bs + lb);
        }
        __syncthreads();
#pragma unroll
        for (int kc = 0; kc < 2; ++kc) {
            short8 af[4], bfr[4];
#pragma unroll
            for (int m = 0; m < 4; ++m) {
                const int row = wm + m * 16 + (lane & 15);
                const int sc = (kc * 4 + (lane >> 4)) ^ (row & 7);
                af[m] = *(const short8*)(As + row * 64 + sc * 8);
            }
#pragma unroll
            for (int n = 0; n < 4; ++n) {
                const int row = wn + n * 16 + (lane & 15);
                const int sc = (kc * 4 + (lane >> 4)) ^ (row & 7);
                bfr[n] = *(const short8*)(Bs + row * 64 + sc * 8);
            }
#pragma unroll
            for (int m = 0; m < 4; ++m)
#pragma unroll
                for (int n = 0; n < 4; ++n)
                    acc[m][n] = __builtin_amdgcn_mfma_f32_16x16x32_bf16(af[m], bfr[n], acc[m][n], 0, 0, 0);
        }
        __syncthreads();
    }

#pragma unroll
    for (int m = 0; m < 4; ++m) {
        const int row0 = brow + wm + m * 16 + ((lane >> 4) << 2);
#pragma unroll
        for (int n = 0; n < 4; ++n) {
            const int col = bcol + wn + n * 16 + (lane & 15);
            const float bv = bias[col];
#pragma unroll
            for (int r = 0; r < 4; ++r) {
                float v = acc[m][n][r] + bv;
                if (RELU) v = fmaxf(v, 0.0f);
                if (OUTF32) ((float*)Cv)[(size_t)(row0 + r) * N + col] = v;
                else ((u16*)Cv)[(size_t)(row0 + r) * N + col] = f2bf(v);
            }
        }
    }
}

// ---------------------------------------------------------------------------
extern "C" void kernel_launch(void* const* d_in, const int* in_sizes, int n_in,
                              void* d_out, int out_size, void* d_ws, size_t ws_size,
                              hipStream_t stream) {
    (void)in_sizes; (void)n_in; (void)out_size; (void)ws_size;
    const float* coords = (const float*)d_in[0];
    const float* features = (const float*)d_in[1];
    const float* times = (const float*)d_in[3];
    const float* W0 = (const float*)d_in[4];
    const float* b0 = (const float*)d_in[5];
    const float* W1 = (const float*)d_in[6];
    const float* b1 = (const float*)d_in[7];
    const float* W2 = (const float*)d_in[8];
    const float* b2 = (const float*)d_in[9];
    const float* W3 = (const float*)d_in[10];
    const float* b3 = (const float*)d_in[11];
    const float* Wn0 = (const float*)d_in[12];
    const float* bn0 = (const float*)d_in[13];
    const float* Wn1 = (const float*)d_in[14];
    const float* bn1 = (const float*)d_in[15];

    char* ws = (char*)d_ws;
    float* cent = (float*)(ws + 0);           // 1024*4 f32
    int* knn = (int*)(ws + 16384);            // 16384 int
    u16* W0t = (u16*)(ws + 81920);            // 256x64
    u16* W1t = (u16*)(ws + 114688);           // 512x256
    u16* W2t = (u16*)(ws + 376832);           // 768x512
    u16* W3t = (u16*)(ws + 1163264);          // 768x768
    u16* Wn0t = (u16*)(ws + 2342912);         // 768x768
    u16* Wn1t = (u16*)(ws + 3522560);         // 768x768
    u16* bufX = (u16*)(ws + 4702208);         // 16384x768 bf16 max
    u16* bufY = (u16*)(ws + 29868032);        // 16384x768 bf16 max

    float* tokens_out = (float*)d_out;                    // (8,128,768)
    float* cent_out = (float*)d_out + 786432;             // (8,128,4)
    float* mask_out = (float*)d_out + 786432 + 4096;      // (8,128)

    // all weight transposes in one launch
    transpose_all<<<9024, 256, 0, stream>>>(W0, W1, W2, W3, Wn0, Wn1,
                                            W0t, W1t, W2t, W3t, Wn0t, Wn1t);

    // FPS -> centroids (also fills centroid + mask outputs)
    fps_kernel<<<8, 256, 0, stream>>>(coords, times, cent, cent_out, mask_out);
    // KNN top-16 per centroid
    knn_kernel<<<1024, 256, 0, stream>>>(coords, times, cent, knn);
    // gather knn rows' features (bf16, K padded to 64)
    gather_kernel<<<4096, 256, 0, stream>>>(features, knn, bufX);

    // MLP on gathered rows (M = 16384)
    gemm_kernel<1, 0><<<dim3(128, 2), 256, 0, stream>>>(bufX, W0t, b0, bufY, 16384, 256, 64);
    gemm_kernel<1, 0><<<dim3(128, 4), 256, 0, stream>>>(bufY, W1t, b1, bufX, 16384, 512, 256);
    gemm_kernel<1, 0><<<dim3(128, 6), 256, 0, stream>>>(bufX, W2t, b2, bufY, 16384, 768, 512);
    gemm_kernel<0, 0><<<dim3(128, 6), 256, 0, stream>>>(bufY, W3t, b3, bufX, 16384, 768, 768);

    // max-pool over the 16 neighbors
    pool_kernel<<<3072, 256, 0, stream>>>(bufX, bufY);

    // token MLP (M = 1024)
    gemm_kernel<1, 0><<<dim3(8, 6), 256, 0, stream>>>(bufY, Wn0t, bn0, bufX, 1024, 768, 768);
    gemm_kernel<0, 1><<<dim3(8, 6), 256, 0, stream>>>(bufX, Wn1t, bn1, tokens_out, 1024, 768, 768);
}

// Round 7
// 378.362 us; speedup vs baseline: 1.0815x; 1.0018x over previous
//
#include <hip/hip_runtime.h>
#include <stdint.h>

typedef unsigned short u16;
typedef __attribute__((ext_vector_type(8))) short short8;
typedef __attribute__((ext_vector_type(4))) float f32x4;

#define NEG_F (-3.402823466e+38f)

__device__ __forceinline__ u16 f2bf(float x) {
    uint32_t u = __builtin_bit_cast(uint32_t, x);
    u = (u + 0x7fffu + ((u >> 16) & 1u)) >> 16;
    return (u16)u;
}
__device__ __forceinline__ float bf2f(u16 b) {
    uint32_t u = ((uint32_t)b) << 16;
    return __builtin_bit_cast(float, u);
}

__device__ __forceinline__ void gload_lds16(const void* g, void* l) {
    __builtin_amdgcn_global_load_lds((const __attribute__((address_space(1))) void*)g,
                                     (__attribute__((address_space(3))) void*)l, 16, 0, 0);
}

// One DPP argmax step: pull (v,idx) from another lane per CTRL, keep the
// larger v (ties -> smaller idx).
template <int CTRL, int RMASK>
__device__ __forceinline__ void argmax_dpp_step(float& v, int& i) {
    const int vb = __builtin_bit_cast(int, v);
    const int vv = __builtin_amdgcn_update_dpp(vb, vb, CTRL, RMASK, 0xf, false);
    const int ii = __builtin_amdgcn_update_dpp(i, i, CTRL, RMASK, 0xf, false);
    const float fv = __builtin_bit_cast(float, vv);
    if (fv > v || (fv == v && ii < i)) { v = fv; i = ii; }
}

// Full wave64 argmax -> result lands in lane 63.
__device__ __forceinline__ void argmax_wave(float& v, int& i) {
    argmax_dpp_step<0x111, 0xf>(v, i);  // row_shr:1
    argmax_dpp_step<0x112, 0xf>(v, i);  // row_shr:2
    argmax_dpp_step<0x114, 0xf>(v, i);  // row_shr:4
    argmax_dpp_step<0x118, 0xf>(v, i);  // row_shr:8
    argmax_dpp_step<0x142, 0xa>(v, i);  // row_bcast:15 -> rows 1,3
    argmax_dpp_step<0x143, 0xc>(v, i);  // row_bcast:31 -> rows 2,3
}

// ---------------------------------------------------------------------------
// FPS v5: one block per batch, 1024 threads (16 waves, 4/SIMD), points in
// LDS (f32x4[8192] = 128 KiB), md[8] in registers.
//
// Model from rounds 2/4/5/6: the j-loop re-reads 128 KB of point data every
// iteration no matter what (RA refuses ~160 live regs; L2 remat = 56 B/cy/CU
// = 2340 cy). LDS streams it at 128 B/cy (1024 cy) IF there are enough waves
// per SIMD to hide ds_read latency -- round 5 failed only because it ran
// 1 wave/SIMD. This is round-2's exact 1024-thread arithmetic (mean order,
// distance expr, tie-breaks, t==0 not touching md) with LDS point reads and
// per-wave key slots + 16-key max combine (same max/min-idx semilattice as
// the atomicMax, any order -> identical result).
// ---------------------------------------------------------------------------
__global__ __launch_bounds__(1024) void fps_kernel(const float* __restrict__ coords,
                                                   const float* __restrict__ times,
                                                   float* __restrict__ cent_ws,
                                                   float* __restrict__ cent_out,
                                                   float* __restrict__ mask_out) {
    const int b = blockIdx.x;
    const int tid = threadIdx.x;   // 0..1023
    const int lane = tid & 63;
    const int wid = tid >> 6;      // 0..15

    __shared__ f32x4 pts[8192];            // 128 KiB
    __shared__ unsigned long long kslot[2][16];
    __shared__ float redv[16][4];

    float md[8];
    float sx = 0.f, sy = 0.f, sz = 0.f, sw = 0.f;
#pragma unroll
    for (int j = 0; j < 8; ++j) {
        const int p = j * 1024 + tid;
        const int n = b * 8192 + p;
        const float x = coords[3 * n + 0];
        const float y = coords[3 * n + 1];
        const float z = coords[3 * n + 2];
        const float w = times[n];
        pts[p] = f32x4{x, y, z, w};
        sx += x; sy += y; sz += z; sw += w;
        md[j] = __builtin_inff();
    }

#pragma unroll
    for (int off = 32; off > 0; off >>= 1) {
        sx += __shfl_down(sx, off);
        sy += __shfl_down(sy, off);
        sz += __shfl_down(sz, off);
        sw += __shfl_down(sw, off);
    }
    if (lane == 0) { redv[wid][0] = sx; redv[wid][1] = sy; redv[wid][2] = sz; redv[wid][3] = sw; }
    __syncthreads();
    // all threads compute the same sum in the same (ascending-w) order
    float c0 = 0.f, c1 = 0.f, c2 = 0.f, c3 = 0.f;
#pragma unroll
    for (int w = 0; w < 16; ++w) { c0 += redv[w][0]; c1 += redv[w][1]; c2 += redv[w][2]; c3 += redv[w][3]; }
    c0 *= (1.0f / 8192.0f);
    c1 *= (1.0f / 8192.0f);
    c2 *= (1.0f / 8192.0f);
    c3 *= (1.0f / 8192.0f);

    for (int t = 0; t < 128; ++t) {
        float v = -__builtin_inff();
        int jb = 0;
        if (t == 0) {
            // distances to the mean: pick argmax only, do NOT touch md
#pragma unroll
            for (int j = 0; j < 8; ++j) {
                const f32x4 P = pts[j * 1024 + tid];
                const float dx = P[0] - c0, dy = P[1] - c1, dz = P[2] - c2, dw = P[3] - c3;
                const float d2 = dx * dx + dy * dy + dz * dz + dw * dw;
                if (d2 > v) { v = d2; jb = j; }
            }
        } else {
#pragma unroll
            for (int j = 0; j < 8; ++j) {
                const f32x4 P = pts[j * 1024 + tid];
                const float dx = P[0] - c0, dy = P[1] - c1, dz = P[2] - c2, dw = P[3] - c3;
                const float d2 = dx * dx + dy * dy + dz * dz + dw * dw;
                const float nm = fminf(md[j], d2);
                md[j] = nm;
                if (nm > v) { v = nm; jb = j; }
            }
        }
        int idx = jb * 1024 + tid;
        argmax_wave(v, idx);
        if (lane == 63) {
            const uint32_t bv = __builtin_bit_cast(uint32_t, v);
            const uint32_t mk = (bv & 0x80000000u) ? ~bv : (bv | 0x80000000u);
            kslot[t & 1][wid] = ((unsigned long long)mk << 32) | (uint32_t)(0x7FFFFFFF - idx);
        }
        __syncthreads();
        unsigned long long kk = kslot[t & 1][0];
#pragma unroll
        for (int w = 1; w < 16; ++w) {
            const unsigned long long o = kslot[t & 1][w];
            kk = (o > kk) ? o : kk;
        }
        const int sel = 0x7FFFFFFF - (int)(uint32_t)(kk & 0xFFFFFFFFull);
        const f32x4 C = pts[sel];   // same address across all lanes: broadcast
        c0 = C[0]; c1 = C[1]; c2 = C[2]; c3 = C[3];
        if (tid == (sel & 1023)) {
            const int js = sel >> 10;
#pragma unroll
            for (int j = 0; j < 8; ++j)
                if (j == js) md[j] = NEG_F;
        }
        if (tid == 0) {
            const int o = (b * 128 + t) * 4;
            cent_ws[o + 0] = c0; cent_ws[o + 1] = c1; cent_ws[o + 2] = c2; cent_ws[o + 3] = c3;
            cent_out[o + 0] = c0; cent_out[o + 1] = c1; cent_out[o + 2] = c2; cent_out[o + 3] = c3;
        }
    }
    if (tid < 128) mask_out[b * 128 + tid] = 1.0f;
}

// ---------------------------------------------------------------------------
// KNN: one block per centroid (B*T=1024 blocks). d2 in LDS, 16 rounds of
// block argmin with lower-index tie-break (matches lax.top_k on -d2).
// ---------------------------------------------------------------------------
__global__ __launch_bounds__(256) void knn_kernel(const float* __restrict__ coords,
                                                  const float* __restrict__ times,
                                                  const float* __restrict__ cent,
                                                  int* __restrict__ knn) {
    __shared__ float d2s[8192];
    __shared__ float rbv[4];
    __shared__ int rbi[4];
    const int q = blockIdx.x;
    const int b = q >> 7;
    const int tid = threadIdx.x;
    const int lane = tid & 63;
    const int wid = tid >> 6;
    const float c0 = cent[q * 4 + 0], c1 = cent[q * 4 + 1], c2 = cent[q * 4 + 2], c3 = cent[q * 4 + 3];
    const float cc = c0 * c0 + c1 * c1 + c2 * c2 + c3 * c3;
    for (int p = tid; p < 8192; p += 256) {
        const int n = b * 8192 + p;
        const float x0 = coords[3 * n], x1 = coords[3 * n + 1], x2 = coords[3 * n + 2], x3 = times[n];
        const float pp = x0 * x0 + x1 * x1 + x2 * x2 + x3 * x3;
        const float dt = x0 * c0 + x1 * c1 + x2 * c2 + x3 * c3;
        d2s[p] = cc + pp - 2.0f * dt;
    }
    __syncthreads();
    for (int r = 0; r < 16; ++r) {
        float v = __builtin_inff();
        int idx = 1 << 30;
        for (int s = 0; s < 32; ++s) {
            const int p = s * 256 + tid;
            const float d = d2s[p];
            if (d < v) { v = d; idx = p; }
        }
#pragma unroll
        for (int off = 32; off > 0; off >>= 1) {
            const float ov = __shfl_down(v, off);
            const int oi = __shfl_down(idx, off);
            if (ov < v || (ov == v && oi < idx)) { v = ov; idx = oi; }
        }
        if (lane == 0) { rbv[wid] = v; rbi[wid] = idx; }
        __syncthreads();
        if (tid == 0) {
            float bb = rbv[0]; int bi = rbi[0];
            for (int w = 1; w < 4; ++w)
                if (rbv[w] < bb || (rbv[w] == bb && rbi[w] < bi)) { bb = rbv[w]; bi = rbi[w]; }
            knn[q * 16 + r] = bi;
            d2s[bi] = __builtin_inff();
        }
        __syncthreads();
    }
}

// ---------------------------------------------------------------------------
// Gather features for the 16384 knn rows into bf16 A0 (K padded 32->64 with 0)
// ---------------------------------------------------------------------------
__global__ __launch_bounds__(256) void gather_kernel(const float* __restrict__ feat,
                                                     const int* __restrict__ knn,
                                                     u16* __restrict__ A0) {
    const int idx = blockIdx.x * 256 + threadIdx.x;  // 16384*64
    const int g = idx >> 6;
    const int c = idx & 63;
    const int b = g >> 11;  // g / (T*K)=g/2048
    const int n = b * 8192 + knn[g];
    const float v = (c < 32) ? feat[(size_t)n * 32 + c] : 0.0f;
    A0[idx] = f2bf(v);
}

// All six weight transposes in ONE launch. Segment boundaries are 256-aligned
// so each block is branch-uniform.
template <int K, int N, int KP>
__device__ __forceinline__ void tp_one(const float* __restrict__ W, u16* __restrict__ Wt, int local) {
    const int n = local / KP;
    const int k = local - n * KP;
    const float v = (k < K) ? W[(size_t)k * N + n] : 0.0f;
    Wt[local] = f2bf(v);
}

__global__ __launch_bounds__(256) void transpose_all(const float* __restrict__ W0,
                                                     const float* __restrict__ W1,
                                                     const float* __restrict__ W2,
                                                     const float* __restrict__ W3,
                                                     const float* __restrict__ Wn0,
                                                     const float* __restrict__ Wn1,
                                                     u16* __restrict__ W0t, u16* __restrict__ W1t,
                                                     u16* __restrict__ W2t, u16* __restrict__ W3t,
                                                     u16* __restrict__ Wn0t, u16* __restrict__ Wn1t) {
    const int idx = blockIdx.x * 256 + threadIdx.x;
    if (idx < 16384) tp_one<32, 256, 64>(W0, W0t, idx);
    else if (idx < 147456) tp_one<256, 512, 256>(W1, W1t, idx - 16384);
    else if (idx < 540672) tp_one<512, 768, 512>(W2, W2t, idx - 147456);
    else if (idx < 1130496) tp_one<768, 768, 768>(W3, W3t, idx - 540672);
    else if (idx < 1720320) tp_one<768, 768, 768>(Wn0, Wn0t, idx - 1130496);
    else tp_one<768, 768, 768>(Wn1, Wn1t, idx - 1720320);
}

// Max-pool over K=16 gathered rows: PF (16384,768) bf16 -> pooled (1024,768)
__global__ __launch_bounds__(256) void pool_kernel(const u16* __restrict__ PF,
                                                   u16* __restrict__ pooled) {
    const int idx = blockIdx.x * 256 + threadIdx.x;  // 1024*768
    const int q = idx / 768;
    const int c = idx - q * 768;
    const u16* base = PF + (size_t)q * 16 * 768 + c;
    float best = -__builtin_inff();
    u16 bb = 0;
#pragma unroll
    for (int kk = 0; kk < 16; ++kk) {
        const u16 u = base[kk * 768];
        const float f = bf2f(u);
        if (f > best) { best = f; bb = u; }
    }
    pooled[idx] = bb;
}

// ---------------------------------------------------------------------------
// bf16 MFMA GEMM: C(M,N) = relu?(A(M,K) @ W(K,N) + bias), W given as Wt(N,K).
// 128x128 tile, BK=64, 4 waves (2x2 of 64x64), global_load_lds width 16,
// source-side XOR swizzle so ds_read_b128 is ~conflict-free.
// ---------------------------------------------------------------------------
template <int RELU, int OUTF32>
__global__ __launch_bounds__(256) void gemm_kernel(const u16* __restrict__ A,
                                                   const u16* __restrict__ Bt,
                                                   const float* __restrict__ bias,
                                                   void* __restrict__ Cv,
                                                   int M, int N, int K) {
    (void)M;
    __shared__ __align__(16) u16 As[128 * 64];
    __shared__ __align__(16) u16 Bs[128 * 64];
    const int tid = threadIdx.x;
    const int lane = tid & 63;
    const int wid = tid >> 6;
    const int brow = blockIdx.x * 128;
    const int bcol = blockIdx.y * 128;
    const int wm = (wid >> 1) * 64;
    const int wn = (wid & 1) * 64;

    f32x4 acc[4][4];
#pragma unroll
    for (int m = 0; m < 4; ++m)
#pragma unroll
        for (int n = 0; n < 4; ++n)
            acc[m][n] = f32x4{0.f, 0.f, 0.f, 0.f};

    const int srow = tid >> 3;    // 0..31
    const int schunk = tid & 7;   // 16B chunk within a 128B row
    const uint32_t lds_wave_base = (uint32_t)(wid * 1024);

    for (int k0 = 0; k0 < K; k0 += 64) {
#pragma unroll
        for (int i = 0; i < 4; ++i) {
            const int row = i * 32 + srow;
            const int sc = schunk ^ (row & 7);  // inverse-swizzled SOURCE chunk
            const u16* ga = A + (size_t)(brow + row) * K + (size_t)(k0 + sc * 8);
            const u16* gb = Bt + (size_t)(bcol + row) * K + (size_t)(k0 + sc * 8);
            const uint32_t lb = (uint32_t)(i * 4096) + lds_wave_base;  // wave-uniform base
            gload_lds16(ga, (char*)As + lb);
            gload_lds16(gb, (char*)Bs + lb);
        }
        __syncthreads();
#pragma unroll
        for (int kc = 0; kc < 2; ++kc) {
            short8 af[4], bfr[4];
#pragma unroll
            for (int m = 0; m < 4; ++m) {
                const int row = wm + m * 16 + (lane & 15);
                const int sc = (kc * 4 + (lane >> 4)) ^ (row & 7);
                af[m] = *(const short8*)(As + row * 64 + sc * 8);
            }
#pragma unroll
            for (int n = 0; n < 4; ++n) {
                const int row = wn + n * 16 + (lane & 15);
                const int sc = (kc * 4 + (lane >> 4)) ^ (row & 7);
                bfr[n] = *(const short8*)(Bs + row * 64 + sc * 8);
            }
#pragma unroll
            for (int m = 0; m < 4; ++m)
#pragma unroll
                for (int n = 0; n < 4; ++n)
                    acc[m][n] = __builtin_amdgcn_mfma_f32_16x16x32_bf16(af[m], bfr[n], acc[m][n], 0, 0, 0);
        }
        __syncthreads();
    }

#pragma unroll
    for (int m = 0; m < 4; ++m) {
        const int row0 = brow + wm + m * 16 + ((lane >> 4) << 2);
#pragma unroll
        for (int n = 0; n < 4; ++n) {
            const int col = bcol + wn + n * 16 + (lane & 15);
            const float bv = bias[col];
#pragma unroll
            for (int r = 0; r < 4; ++r) {
                float v = acc[m][n][r] + bv;
                if (RELU) v = fmaxf(v, 0.0f);
                if (OUTF32) ((float*)Cv)[(size_t)(row0 + r) * N + col] = v;
                else ((u16*)Cv)[(size_t)(row0 + r) * N + col] = f2bf(v);
            }
        }
    }
}

// ---------------------------------------------------------------------------
extern "C" void kernel_launch(void* const* d_in, const int* in_sizes, int n_in,
                              void* d_out, int out_size, void* d_ws, size_t ws_size,
                              hipStream_t stream) {
    (void)in_sizes; (void)n_in; (void)out_size; (void)ws_size;
    const float* coords = (const float*)d_in[0];
    const float* features = (const float*)d_in[1];
    const float* times = (const float*)d_in[3];
    const float* W0 = (const float*)d_in[4];
    const float* b0 = (const float*)d_in[5];
    const float* W1 = (const float*)d_in[6];
    const float* b1 = (const float*)d_in[7];
    const float* W2 = (const float*)d_in[8];
    const float* b2 = (const float*)d_in[9];
    const float* W3 = (const float*)d_in[10];
    const float* b3 = (const float*)d_in[11];
    const float* Wn0 = (const float*)d_in[12];
    const float* bn0 = (const float*)d_in[13];
    const float* Wn1 = (const float*)d_in[14];
    const float* bn1 = (const float*)d_in[15];

    char* ws = (char*)d_ws;
    float* cent = (float*)(ws + 0);           // 1024*4 f32
    int* knn = (int*)(ws + 16384);            // 16384 int
    u16* W0t = (u16*)(ws + 81920);            // 256x64
    u16* W1t = (u16*)(ws + 114688);           // 512x256
    u16* W2t = (u16*)(ws + 376832);           // 768x512
    u16* W3t = (u16*)(ws + 1163264);          // 768x768
    u16* Wn0t = (u16*)(ws + 2342912);         // 768x768
    u16* Wn1t = (u16*)(ws + 3522560);         // 768x768
    u16* bufX = (u16*)(ws + 4702208);         // 16384x768 bf16 max
    u16* bufY = (u16*)(ws + 29868032);        // 16384x768 bf16 max

    float* tokens_out = (float*)d_out;                    // (8,128,768)
    float* cent_out = (float*)d_out + 786432;             // (8,128,4)
    float* mask_out = (float*)d_out + 786432 + 4096;      // (8,128)

    // all weight transposes in one launch
    transpose_all<<<9024, 256, 0, stream>>>(W0, W1, W2, W3, Wn0, Wn1,
                                            W0t, W1t, W2t, W3t, Wn0t, Wn1t);

    // FPS -> centroids (also fills centroid + mask outputs)
    fps_kernel<<<8, 1024, 0, stream>>>(coords, times, cent, cent_out, mask_out);
    // KNN top-16 per centroid
    knn_kernel<<<1024, 256, 0, stream>>>(coords, times, cent, knn);
    // gather knn rows' features (bf16, K padded to 64)
    gather_kernel<<<4096, 256, 0, stream>>>(features, knn, bufX);

    // MLP on gathered rows (M = 16384)
    gemm_kernel<1, 0><<<dim3(128, 2), 256, 0, stream>>>(bufX, W0t, b0, bufY, 16384, 256, 64);
    gemm_kernel<1, 0><<<dim3(128, 4), 256, 0, stream>>>(bufY, W1t, b1, bufX, 16384, 512, 256);
    gemm_kernel<1, 0><<<dim3(128, 6), 256, 0, stream>>>(bufX, W2t, b2, bufY, 16384, 768, 512);
    gemm_kernel<0, 0><<<dim3(128, 6), 256, 0, stream>>>(bufY, W3t, b3, bufX, 16384, 768, 768);

    // max-pool over the 16 neighbors
    pool_kernel<<<3072, 256, 0, stream>>>(bufX, bufY);

    // token MLP (M = 1024)
    gemm_kernel<1, 0><<<dim3(8, 6), 256, 0, stream>>>(bufY, Wn0t, bn0, bufX, 1024, 768, 768);
    gemm_kernel<0, 1><<<dim3(8, 6), 256, 0, stream>>>(bufX, Wn1t, bn1, tokens_out, 1024, 768, 768);
}

// Round 8
// 375.729 us; speedup vs baseline: 1.0891x; 1.0070x over previous
//
#include <hip/hip_runtime.h>
#include <stdint.h>

typedef unsigned short u16;
typedef __attribute__((ext_vector_type(8))) short short8;
typedef __attribute__((ext_vector_type(4))) float f32x4;

#define NEG_F (-3.402823466e+38f)

__device__ __forceinline__ u16 f2bf(float x) {
    uint32_t u = __builtin_bit_cast(uint32_t, x);
    u = (u + 0x7fffu + ((u >> 16) & 1u)) >> 16;
    return (u16)u;
}
__device__ __forceinline__ float bf2f(u16 b) {
    uint32_t u = ((uint32_t)b) << 16;
    return __builtin_bit_cast(float, u);
}

__device__ __forceinline__ void gload_lds16(const void* g, void* l) {
    __builtin_amdgcn_global_load_lds((const __attribute__((address_space(1))) void*)g,
                                     (__attribute__((address_space(3))) void*)l, 16, 0, 0);
}

// One DPP argmax step: pull (v,idx) from another lane per CTRL, keep the
// larger v (ties -> smaller idx).
template <int CTRL, int RMASK>
__device__ __forceinline__ void argmax_dpp_step(float& v, int& i) {
    const int vb = __builtin_bit_cast(int, v);
    const int vv = __builtin_amdgcn_update_dpp(vb, vb, CTRL, RMASK, 0xf, false);
    const int ii = __builtin_amdgcn_update_dpp(i, i, CTRL, RMASK, 0xf, false);
    const float fv = __builtin_bit_cast(float, vv);
    if (fv > v || (fv == v && ii < i)) { v = fv; i = ii; }
}

// Full wave64 argmax -> result lands in lane 63.
__device__ __forceinline__ void argmax_wave(float& v, int& i) {
    argmax_dpp_step<0x111, 0xf>(v, i);  // row_shr:1
    argmax_dpp_step<0x112, 0xf>(v, i);  // row_shr:2
    argmax_dpp_step<0x114, 0xf>(v, i);  // row_shr:4
    argmax_dpp_step<0x118, 0xf>(v, i);  // row_shr:8
    argmax_dpp_step<0x142, 0xa>(v, i);  // row_bcast:15 -> rows 1,3
    argmax_dpp_step<0x143, 0xc>(v, i);  // row_bcast:31 -> rows 2,3
}

// ---------------------------------------------------------------------------
// FPS v6: one block per batch, 1024 threads (16 waves, 4/SIMD).
//
// Round-7 post-mortem (counters): per-active-CU VALUBusy ~83%; LDS pipe per
// iter = 128KB point stream (~1540cy) + 256 redundant ds_read_b64 from the
// all-waves 16-key combine (~1500cy). Two fixes:
//  (1) points back in REGISTERS (only 40 state regs at 8 pts/thread) with
//      asm "+v" pin + __launch_bounds__(1024,4) granting the 128-VGPR
//      budget, so the RA cannot/need-not rematerialize -> j-loop has ZERO
//      memory ops.
//  (2) single-wave combine: wave 0 reads kslot[lane&15] (1 ds_read_b64),
//      4-step shfl_xor u64-max butterfly, lane 0 -> bc; 2nd barrier;
//      everyone reads bc + pts[sel] broadcast. Max is order-independent ->
//      selection identical. Barrier ordering makes ping-pong unnecessary:
//      kslot write(t+1) is after barrier2(t) which is after wave0's reads(t);
//      bc write(t+1) is after barrier1(t+1) which is after all bc reads(t).
//
// Selection arithmetic (mean order, distance expr, tie-breaks, t==0 not
// touching md) is source-identical to the passing round-2/7 kernels.
// ---------------------------------------------------------------------------
__global__ __launch_bounds__(1024, 4) void fps_kernel(const float* __restrict__ coords,
                                                      const float* __restrict__ times,
                                                      float* __restrict__ cent_ws,
                                                      float* __restrict__ cent_out,
                                                      float* __restrict__ mask_out) {
    const int b = blockIdx.x;
    const int tid = threadIdx.x;   // 0..1023
    const int lane = tid & 63;
    const int wid = tid >> 6;      // 0..15

    __shared__ f32x4 pts[8192];            // 128 KiB (broadcast centroid fetch)
    __shared__ unsigned long long kslot[16];
    __shared__ unsigned long long bc;
    __shared__ float redv[16][4];

    float px[8], py[8], pz[8], pw[8], md[8];
    float sx = 0.f, sy = 0.f, sz = 0.f, sw = 0.f;
#pragma unroll
    for (int j = 0; j < 8; ++j) {
        const int p = j * 1024 + tid;
        const int n = b * 8192 + p;
        px[j] = coords[3 * n + 0];
        py[j] = coords[3 * n + 1];
        pz[j] = coords[3 * n + 2];
        pw[j] = times[n];
        pts[p] = f32x4{px[j], py[j], pz[j], pw[j]};
        sx += px[j]; sy += py[j]; sz += pz[j]; sw += pw[j];
        md[j] = __builtin_inff();
    }
    // Pin the point state in registers (40 regs; budget is 128 at 4 waves/EU):
    // "+v" makes each value an asm output -> no rematerialization allowed.
#pragma unroll
    for (int j = 0; j < 8; ++j) {
        asm volatile("" : "+v"(px[j]), "+v"(py[j]), "+v"(pz[j]), "+v"(pw[j]));
    }

#pragma unroll
    for (int off = 32; off > 0; off >>= 1) {
        sx += __shfl_down(sx, off);
        sy += __shfl_down(sy, off);
        sz += __shfl_down(sz, off);
        sw += __shfl_down(sw, off);
    }
    if (lane == 0) { redv[wid][0] = sx; redv[wid][1] = sy; redv[wid][2] = sz; redv[wid][3] = sw; }
    __syncthreads();
    // all threads compute the same sum in the same (ascending-w) order
    float c0 = 0.f, c1 = 0.f, c2 = 0.f, c3 = 0.f;
#pragma unroll
    for (int w = 0; w < 16; ++w) { c0 += redv[w][0]; c1 += redv[w][1]; c2 += redv[w][2]; c3 += redv[w][3]; }
    c0 *= (1.0f / 8192.0f);
    c1 *= (1.0f / 8192.0f);
    c2 *= (1.0f / 8192.0f);
    c3 *= (1.0f / 8192.0f);

    for (int t = 0; t < 128; ++t) {
        float v = -__builtin_inff();
        int jb = 0;
        if (t == 0) {
            // distances to the mean: pick argmax only, do NOT touch md
#pragma unroll
            for (int j = 0; j < 8; ++j) {
                const float dx = px[j] - c0, dy = py[j] - c1, dz = pz[j] - c2, dw = pw[j] - c3;
                const float d2 = dx * dx + dy * dy + dz * dz + dw * dw;
                if (d2 > v) { v = d2; jb = j; }
            }
        } else {
#pragma unroll
            for (int j = 0; j < 8; ++j) {
                const float dx = px[j] - c0, dy = py[j] - c1, dz = pz[j] - c2, dw = pw[j] - c3;
                const float d2 = dx * dx + dy * dy + dz * dz + dw * dw;
                const float nm = fminf(md[j], d2);
                md[j] = nm;
                if (nm > v) { v = nm; jb = j; }
            }
        }
        int idx = jb * 1024 + tid;
        argmax_wave(v, idx);
        if (lane == 63) {
            const uint32_t bv = __builtin_bit_cast(uint32_t, v);
            const uint32_t mk = (bv & 0x80000000u) ? ~bv : (bv | 0x80000000u);
            kslot[wid] = ((unsigned long long)mk << 32) | (uint32_t)(0x7FFFFFFF - idx);
        }
        __syncthreads();
        if (wid == 0) {
            unsigned long long k = kslot[lane & 15];
#pragma unroll
            for (int off = 8; off > 0; off >>= 1) {
                const unsigned long long o = __shfl_xor(k, off);
                k = (o > k) ? o : k;
            }
            if (lane == 0) bc = k;
        }
        __syncthreads();
        const unsigned long long kk = bc;
        const int sel = 0x7FFFFFFF - (int)(uint32_t)(kk & 0xFFFFFFFFull);
        const f32x4 C = pts[sel];   // same address across all lanes: broadcast
        c0 = C[0]; c1 = C[1]; c2 = C[2]; c3 = C[3];
        if (tid == (sel & 1023)) {
            const int js = sel >> 10;
#pragma unroll
            for (int j = 0; j < 8; ++j)
                if (j == js) md[j] = NEG_F;
        }
        if (tid == 0) {
            const int o = (b * 128 + t) * 4;
            cent_ws[o + 0] = c0; cent_ws[o + 1] = c1; cent_ws[o + 2] = c2; cent_ws[o + 3] = c3;
            cent_out[o + 0] = c0; cent_out[o + 1] = c1; cent_out[o + 2] = c2; cent_out[o + 3] = c3;
        }
    }
    if (tid < 128) mask_out[b * 128 + tid] = 1.0f;
}

// ---------------------------------------------------------------------------
// KNN: one block per centroid (B*T=1024 blocks). d2 in LDS, 16 rounds of
// block argmin with lower-index tie-break (matches lax.top_k on -d2).
// ---------------------------------------------------------------------------
__global__ __launch_bounds__(256) void knn_kernel(const float* __restrict__ coords,
                                                  const float* __restrict__ times,
                                                  const float* __restrict__ cent,
                                                  int* __restrict__ knn) {
    __shared__ float d2s[8192];
    __shared__ float rbv[4];
    __shared__ int rbi[4];
    const int q = blockIdx.x;
    const int b = q >> 7;
    const int tid = threadIdx.x;
    const int lane = tid & 63;
    const int wid = tid >> 6;
    const float c0 = cent[q * 4 + 0], c1 = cent[q * 4 + 1], c2 = cent[q * 4 + 2], c3 = cent[q * 4 + 3];
    const float cc = c0 * c0 + c1 * c1 + c2 * c2 + c3 * c3;
    for (int p = tid; p < 8192; p += 256) {
        const int n = b * 8192 + p;
        const float x0 = coords[3 * n], x1 = coords[3 * n + 1], x2 = coords[3 * n + 2], x3 = times[n];
        const float pp = x0 * x0 + x1 * x1 + x2 * x2 + x3 * x3;
        const float dt = x0 * c0 + x1 * c1 + x2 * c2 + x3 * c3;
        d2s[p] = cc + pp - 2.0f * dt;
    }
    __syncthreads();
    for (int r = 0; r < 16; ++r) {
        float v = __builtin_inff();
        int idx = 1 << 30;
        for (int s = 0; s < 32; ++s) {
            const int p = s * 256 + tid;
            const float d = d2s[p];
            if (d < v) { v = d; idx = p; }
        }
#pragma unroll
        for (int off = 32; off > 0; off >>= 1) {
            const float ov = __shfl_down(v, off);
            const int oi = __shfl_down(idx, off);
            if (ov < v || (ov == v && oi < idx)) { v = ov; idx = oi; }
        }
        if (lane == 0) { rbv[wid] = v; rbi[wid] = idx; }
        __syncthreads();
        if (tid == 0) {
            float bb = rbv[0]; int bi = rbi[0];
            for (int w = 1; w < 4; ++w)
                if (rbv[w] < bb || (rbv[w] == bb && rbi[w] < bi)) { bb = rbv[w]; bi = rbi[w]; }
            knn[q * 16 + r] = bi;
            d2s[bi] = __builtin_inff();
        }
        __syncthreads();
    }
}

// ---------------------------------------------------------------------------
// Gather features for the 16384 knn rows into bf16 A0 (K padded 32->64 with 0)
// ---------------------------------------------------------------------------
__global__ __launch_bounds__(256) void gather_kernel(const float* __restrict__ feat,
                                                     const int* __restrict__ knn,
                                                     u16* __restrict__ A0) {
    const int idx = blockIdx.x * 256 + threadIdx.x;  // 16384*64
    const int g = idx >> 6;
    const int c = idx & 63;
    const int b = g >> 11;  // g / (T*K)=g/2048
    const int n = b * 8192 + knn[g];
    const float v = (c < 32) ? feat[(size_t)n * 32 + c] : 0.0f;
    A0[idx] = f2bf(v);
}

// All six weight transposes in ONE launch. Segment boundaries are 256-aligned
// so each block is branch-uniform.
template <int K, int N, int KP>
__device__ __forceinline__ void tp_one(const float* __restrict__ W, u16* __restrict__ Wt, int local) {
    const int n = local / KP;
    const int k = local - n * KP;
    const float v = (k < K) ? W[(size_t)k * N + n] : 0.0f;
    Wt[local] = f2bf(v);
}

__global__ __launch_bounds__(256) void transpose_all(const float* __restrict__ W0,
                                                     const float* __restrict__ W1,
                                                     const float* __restrict__ W2,
                                                     const float* __restrict__ W3,
                                                     const float* __restrict__ Wn0,
                                                     const float* __restrict__ Wn1,
                                                     u16* __restrict__ W0t, u16* __restrict__ W1t,
                                                     u16* __restrict__ W2t, u16* __restrict__ W3t,
                                                     u16* __restrict__ Wn0t, u16* __restrict__ Wn1t) {
    const int idx = blockIdx.x * 256 + threadIdx.x;
    if (idx < 16384) tp_one<32, 256, 64>(W0, W0t, idx);
    else if (idx < 147456) tp_one<256, 512, 256>(W1, W1t, idx - 16384);
    else if (idx < 540672) tp_one<512, 768, 512>(W2, W2t, idx - 147456);
    else if (idx < 1130496) tp_one<768, 768, 768>(W3, W3t, idx - 540672);
    else if (idx < 1720320) tp_one<768, 768, 768>(Wn0, Wn0t, idx - 1130496);
    else tp_one<768, 768, 768>(Wn1, Wn1t, idx - 1720320);
}

// Max-pool over K=16 gathered rows: PF (16384,768) bf16 -> pooled (1024,768)
__global__ __launch_bounds__(256) void pool_kernel(const u16* __restrict__ PF,
                                                   u16* __restrict__ pooled) {
    const int idx = blockIdx.x * 256 + threadIdx.x;  // 1024*768
    const int q = idx / 768;
    const int c = idx - q * 768;
    const u16* base = PF + (size_t)q * 16 * 768 + c;
    float best = -__builtin_inff();
    u16 bb = 0;
#pragma unroll
    for (int kk = 0; kk < 16; ++kk) {
        const u16 u = base[kk * 768];
        const float f = bf2f(u);
        if (f > best) { best = f; bb = u; }
    }
    pooled[idx] = bb;
}

// ---------------------------------------------------------------------------
// bf16 MFMA GEMM: C(M,N) = relu?(A(M,K) @ W(K,N) + bias), W given as Wt(N,K).
// 128x128 tile, BK=64, 4 waves (2x2 of 64x64), global_load_lds width 16,
// source-side XOR swizzle so ds_read_b128 is ~conflict-free.
// ---------------------------------------------------------------------------
template <int RELU, int OUTF32>
__global__ __launch_bounds__(256) void gemm_kernel(const u16* __restrict__ A,
                                                   const u16* __restrict__ Bt,
                                                   const float* __restrict__ bias,
                                                   void* __restrict__ Cv,
                                                   int M, int N, int K) {
    (void)M;
    __shared__ __align__(16) u16 As[128 * 64];
    __shared__ __align__(16) u16 Bs[128 * 64];
    const int tid = threadIdx.x;
    const int lane = tid & 63;
    const int wid = tid >> 6;
    const int brow = blockIdx.x * 128;
    const int bcol = blockIdx.y * 128;
    const int wm = (wid >> 1) * 64;
    const int wn = (wid & 1) * 64;

    f32x4 acc[4][4];
#pragma unroll
    for (int m = 0; m < 4; ++m)
#pragma unroll
        for (int n = 0; n < 4; ++n)
            acc[m][n] = f32x4{0.f, 0.f, 0.f, 0.f};

    const int srow = tid >> 3;    // 0..31
    const int schunk = tid & 7;   // 16B chunk within a 128B row
    const uint32_t lds_wave_base = (uint32_t)(wid * 1024);

    for (int k0 = 0; k0 < K; k0 += 64) {
#pragma unroll
        for (int i = 0; i < 4; ++i) {
            const int row = i * 32 + srow;
            const int sc = schunk ^ (row & 7);  // inverse-swizzled SOURCE chunk
            const u16* ga = A + (size_t)(brow + row) * K + (size_t)(k0 + sc * 8);
            const u16* gb = Bt + (size_t)(bcol + row) * K + (size_t)(k0 + sc * 8);
            const uint32_t lb = (uint32_t)(i * 4096) + lds_wave_base;  // wave-uniform base
            gload_lds16(ga, (char*)As + lb);
            gload_lds16(gb, (char*)Bs + lb);
        }
        __syncthreads();
#pragma unroll
        for (int kc = 0; kc < 2; ++kc) {
            short8 af[4], bfr[4];
#pragma unroll
            for (int m = 0; m < 4; ++m) {
                const int row = wm + m * 16 + (lane & 15);
                const int sc = (kc * 4 + (lane >> 4)) ^ (row & 7);
                af[m] = *(const short8*)(As + row * 64 + sc * 8);
            }
#pragma unroll
            for (int n = 0; n < 4; ++n) {
                const int row = wn + n * 16 + (lane & 15);
                const int sc = (kc * 4 + (lane >> 4)) ^ (row & 7);
                bfr[n] = *(const short8*)(Bs + row * 64 + sc * 8);
            }
#pragma unroll
            for (int m = 0; m < 4; ++m)
#pragma unroll
                for (int n = 0; n < 4; ++n)
                    acc[m][n] = __builtin_amdgcn_mfma_f32_16x16x32_bf16(af[m], bfr[n], acc[m][n], 0, 0, 0);
        }
        __syncthreads();
    }

#pragma unroll
    for (int m = 0; m < 4; ++m) {
        const int row0 = brow + wm + m * 16 + ((lane >> 4) << 2);
#pragma unroll
        for (int n = 0; n < 4; ++n) {
            const int col = bcol + wn + n * 16 + (lane & 15);
            const float bv = bias[col];
#pragma unroll
            for (int r = 0; r < 4; ++r) {
                float v = acc[m][n][r] + bv;
                if (RELU) v = fmaxf(v, 0.0f);
                if (OUTF32) ((float*)Cv)[(size_t)(row0 + r) * N + col] = v;
                else ((u16*)Cv)[(size_t)(row0 + r) * N + col] = f2bf(v);
            }
        }
    }
}

// ---------------------------------------------------------------------------
extern "C" void kernel_launch(void* const* d_in, const int* in_sizes, int n_in,
                              void* d_out, int out_size, void* d_ws, size_t ws_size,
                              hipStream_t stream) {
    (void)in_sizes; (void)n_in; (void)out_size; (void)ws_size;
    const float* coords = (const float*)d_in[0];
    const float* features = (const float*)d_in[1];
    const float* times = (const float*)d_in[3];
    const float* W0 = (const float*)d_in[4];
    const float* b0 = (const float*)d_in[5];
    const float* W1 = (const float*)d_in[6];
    const float* b1 = (const float*)d_in[7];
    const float* W2 = (const float*)d_in[8];
    const float* b2 = (const float*)d_in[9];
    const float* W3 = (const float*)d_in[10];
    const float* b3 = (const float*)d_in[11];
    const float* Wn0 = (const float*)d_in[12];
    const float* bn0 = (const float*)d_in[13];
    const float* Wn1 = (const float*)d_in[14];
    const float* bn1 = (const float*)d_in[15];

    char* ws = (char*)d_ws;
    float* cent = (float*)(ws + 0);           // 1024*4 f32
    int* knn = (int*)(ws + 16384);            // 16384 int
    u16* W0t = (u16*)(ws + 81920);            // 256x64
    u16* W1t = (u16*)(ws + 114688);           // 512x256
    u16* W2t = (u16*)(ws + 376832);           // 768x512
    u16* W3t = (u16*)(ws + 1163264);          // 768x768
    u16* Wn0t = (u16*)(ws + 2342912);         // 768x768
    u16* Wn1t = (u16*)(ws + 3522560);         // 768x768
    u16* bufX = (u16*)(ws + 4702208);         // 16384x768 bf16 max
    u16* bufY = (u16*)(ws + 29868032);        // 16384x768 bf16 max

    float* tokens_out = (float*)d_out;                    // (8,128,768)
    float* cent_out = (float*)d_out + 786432;             // (8,128,4)
    float* mask_out = (float*)d_out + 786432 + 4096;      // (8,128)

    // all weight transposes in one launch
    transpose_all<<<9024, 256, 0, stream>>>(W0, W1, W2, W3, Wn0, Wn1,
                                            W0t, W1t, W2t, W3t, Wn0t, Wn1t);

    // FPS -> centroids (also fills centroid + mask outputs)
    fps_kernel<<<8, 1024, 0, stream>>>(coords, times, cent, cent_out, mask_out);
    // KNN top-16 per centroid
    knn_kernel<<<1024, 256, 0, stream>>>(coords, times, cent, knn);
    // gather knn rows' features (bf16, K padded to 64)
    gather_kernel<<<4096, 256, 0, stream>>>(features, knn, bufX);

    // MLP on gathered rows (M = 16384)
    gemm_kernel<1, 0><<<dim3(128, 2), 256, 0, stream>>>(bufX, W0t, b0, bufY, 16384, 256, 64);
    gemm_kernel<1, 0><<<dim3(128, 4), 256, 0, stream>>>(bufY, W1t, b1, bufX, 16384, 512, 256);
    gemm_kernel<1, 0><<<dim3(128, 6), 256, 0, stream>>>(bufX, W2t, b2, bufY, 16384, 768, 512);
    gemm_kernel<0, 0><<<dim3(128, 6), 256, 0, stream>>>(bufY, W3t, b3, bufX, 16384, 768, 768);

    // max-pool over the 16 neighbors
    pool_kernel<<<3072, 256, 0, stream>>>(bufX, bufY);

    // token MLP (M = 1024)
    gemm_kernel<1, 0><<<dim3(8, 6), 256, 0, stream>>>(bufY, Wn0t, bn0, bufX, 1024, 768, 768);
    gemm_kernel<0, 1><<<dim3(8, 6), 256, 0, stream>>>(bufX, Wn1t, bn1, tokens_out, 1024, 768, 768);
}

// Round 9
// 373.408 us; speedup vs baseline: 1.0959x; 1.0062x over previous
//
#include <hip/hip_runtime.h>
#include <stdint.h>

typedef unsigned short u16;
typedef __attribute__((ext_vector_type(8))) short short8;
typedef __attribute__((ext_vector_type(4))) float f32x4;

#define NEG_F (-3.402823466e+38f)

__device__ __forceinline__ u16 f2bf(float x) {
    uint32_t u = __builtin_bit_cast(uint32_t, x);
    u = (u + 0x7fffu + ((u >> 16) & 1u)) >> 16;
    return (u16)u;
}
__device__ __forceinline__ float bf2f(u16 b) {
    uint32_t u = ((uint32_t)b) << 16;
    return __builtin_bit_cast(float, u);
}

__device__ __forceinline__ void gload_lds16(const void* g, void* l) {
    __builtin_amdgcn_global_load_lds((const __attribute__((address_space(1))) void*)g,
                                     (__attribute__((address_space(3))) void*)l, 16, 0, 0);
}

// One DPP argmax step: pull (v,idx) from another lane per CTRL, keep the
// larger v (ties -> smaller idx).
template <int CTRL, int RMASK>
__device__ __forceinline__ void argmax_dpp_step(float& v, int& i) {
    const int vb = __builtin_bit_cast(int, v);
    const int vv = __builtin_amdgcn_update_dpp(vb, vb, CTRL, RMASK, 0xf, false);
    const int ii = __builtin_amdgcn_update_dpp(i, i, CTRL, RMASK, 0xf, false);
    const float fv = __builtin_bit_cast(float, vv);
    if (fv > v || (fv == v && ii < i)) { v = fv; i = ii; }
}

// Full wave64 argmax -> result lands in lane 63.
__device__ __forceinline__ void argmax_wave(float& v, int& i) {
    argmax_dpp_step<0x111, 0xf>(v, i);  // row_shr:1
    argmax_dpp_step<0x112, 0xf>(v, i);  // row_shr:2
    argmax_dpp_step<0x114, 0xf>(v, i);  // row_shr:4
    argmax_dpp_step<0x118, 0xf>(v, i);  // row_shr:8
    argmax_dpp_step<0x142, 0xa>(v, i);  // row_bcast:15 -> rows 1,3
    argmax_dpp_step<0x143, 0xc>(v, i);  // row_bcast:31 -> rows 2,3
}

// One DPP u64-max step within a 16-lane row (row_shr). Register-only.
template <int CTRL>
__device__ __forceinline__ unsigned long long dppmax_u64(unsigned long long k) {
    const int lo = (int)(uint32_t)(k & 0xffffffffull);
    const int hi = (int)(uint32_t)(k >> 32);
    const int lo2 = __builtin_amdgcn_update_dpp(lo, lo, CTRL, 0xf, 0xf, false);
    const int hi2 = __builtin_amdgcn_update_dpp(hi, hi, CTRL, 0xf, 0xf, false);
    const unsigned long long o =
        ((unsigned long long)(uint32_t)hi2 << 32) | (uint32_t)lo2;
    return (o > k) ? o : k;
}

// ---------------------------------------------------------------------------
// FPS v7: one block per batch, 1024 threads (16 waves, 4/SIMD).
//
// Round-8 post-mortem: rounds 7 (LDS points) and 8 (reg points) are time-
// identical -> the serial per-iteration tail dominates, not the j-loop data
// path. v6's tail: 2 barriers + a wave-0 combine built on 4 dependent u64
// __shfl_xor (8 ds_bpermute, ~600cy serial). v7 cuts the tail:
//  - ONE barrier/iter, ping-pong kslot[2][16] (read slot[A]@t < barrier(t+1)
//    < write slot[A]@t+2 -> race-free).
//  - combine redundantly in EVERY wave: all lanes ds_read_b64 kslot[lane&15],
//    4 DPP row_shr u64-max steps (register-only), lane15 holds the max;
//    readlane(15) of the LOW word -> sel (hi word not needed).
// Max over the same 16 keys in any order -> identical selection. All
// selection arithmetic source-identical to the passing round-2/7/8 kernels.
// ---------------------------------------------------------------------------
__global__ __launch_bounds__(1024, 4) void fps_kernel(const float* __restrict__ coords,
                                                      const float* __restrict__ times,
                                                      float* __restrict__ cent_out,
                                                      float* __restrict__ mask_out) {
    const int b = blockIdx.x;
    const int tid = threadIdx.x;   // 0..1023
    const int lane = tid & 63;
    const int wid = tid >> 6;      // 0..15

    __shared__ f32x4 pts[8192];            // 128 KiB (broadcast centroid fetch)
    __shared__ unsigned long long kslot[2][16];
    __shared__ float redv[16][4];

    float px[8], py[8], pz[8], pw[8], md[8];
    float sx = 0.f, sy = 0.f, sz = 0.f, sw = 0.f;
#pragma unroll
    for (int j = 0; j < 8; ++j) {
        const int p = j * 1024 + tid;
        const int n = b * 8192 + p;
        px[j] = coords[3 * n + 0];
        py[j] = coords[3 * n + 1];
        pz[j] = coords[3 * n + 2];
        pw[j] = times[n];
        pts[p] = f32x4{px[j], py[j], pz[j], pw[j]};
        sx += px[j]; sy += py[j]; sz += pz[j]; sw += pw[j];
        md[j] = __builtin_inff();
    }
    // Pin the point state in registers ("+v" output cannot be rematerialized).
#pragma unroll
    for (int j = 0; j < 8; ++j) {
        asm volatile("" : "+v"(px[j]), "+v"(py[j]), "+v"(pz[j]), "+v"(pw[j]));
    }

#pragma unroll
    for (int off = 32; off > 0; off >>= 1) {
        sx += __shfl_down(sx, off);
        sy += __shfl_down(sy, off);
        sz += __shfl_down(sz, off);
        sw += __shfl_down(sw, off);
    }
    if (lane == 0) { redv[wid][0] = sx; redv[wid][1] = sy; redv[wid][2] = sz; redv[wid][3] = sw; }
    __syncthreads();
    // all threads compute the same sum in the same (ascending-w) order
    float c0 = 0.f, c1 = 0.f, c2 = 0.f, c3 = 0.f;
#pragma unroll
    for (int w = 0; w < 16; ++w) { c0 += redv[w][0]; c1 += redv[w][1]; c2 += redv[w][2]; c3 += redv[w][3]; }
    c0 *= (1.0f / 8192.0f);
    c1 *= (1.0f / 8192.0f);
    c2 *= (1.0f / 8192.0f);
    c3 *= (1.0f / 8192.0f);

    for (int t = 0; t < 128; ++t) {
        float v = -__builtin_inff();
        int jb = 0;
        if (t == 0) {
            // distances to the mean: pick argmax only, do NOT touch md
#pragma unroll
            for (int j = 0; j < 8; ++j) {
                const float dx = px[j] - c0, dy = py[j] - c1, dz = pz[j] - c2, dw = pw[j] - c3;
                const float d2 = dx * dx + dy * dy + dz * dz + dw * dw;
                if (d2 > v) { v = d2; jb = j; }
            }
        } else {
#pragma unroll
            for (int j = 0; j < 8; ++j) {
                const float dx = px[j] - c0, dy = py[j] - c1, dz = pz[j] - c2, dw = pw[j] - c3;
                const float d2 = dx * dx + dy * dy + dz * dz + dw * dw;
                const float nm = fminf(md[j], d2);
                md[j] = nm;
                if (nm > v) { v = nm; jb = j; }
            }
        }
        int idx = jb * 1024 + tid;
        argmax_wave(v, idx);
        if (lane == 63) {
            const uint32_t bv = __builtin_bit_cast(uint32_t, v);
            const uint32_t mk = (bv & 0x80000000u) ? ~bv : (bv | 0x80000000u);
            kslot[t & 1][wid] = ((unsigned long long)mk << 32) | (uint32_t)(0x7FFFFFFF - idx);
        }
        __syncthreads();
        // per-wave redundant combine: register-only DPP u64 max over 16 keys
        unsigned long long k = kslot[t & 1][lane & 15];
        k = dppmax_u64<0x111>(k);  // row_shr:1
        k = dppmax_u64<0x112>(k);  // row_shr:2
        k = dppmax_u64<0x114>(k);  // row_shr:4
        k = dppmax_u64<0x118>(k);  // row_shr:8 -> lane15 of each row = max
        const int klo = __builtin_amdgcn_readlane((int)(uint32_t)(k & 0xffffffffull), 15);
        const int sel = 0x7FFFFFFF - klo;
        const f32x4 C = pts[sel];   // same address across all lanes: broadcast
        c0 = C[0]; c1 = C[1]; c2 = C[2]; c3 = C[3];
        if (tid == (sel & 1023)) {
            const int js = sel >> 10;
#pragma unroll
            for (int j = 0; j < 8; ++j)
                if (j == js) md[j] = NEG_F;
        }
        if (tid == 0) {
            const int o = (b * 128 + t) * 4;
            cent_out[o + 0] = c0; cent_out[o + 1] = c1; cent_out[o + 2] = c2; cent_out[o + 3] = c3;
        }
    }
    if (tid < 128) mask_out[b * 128 + tid] = 1.0f;
}

// ---------------------------------------------------------------------------
// KNN: one block per centroid (B*T=1024 blocks). d2 in LDS, 16 rounds of
// block argmin with lower-index tie-break (matches lax.top_k on -d2).
// ---------------------------------------------------------------------------
__global__ __launch_bounds__(256) void knn_kernel(const float* __restrict__ coords,
                                                  const float* __restrict__ times,
                                                  const float* __restrict__ cent,
                                                  int* __restrict__ knn) {
    __shared__ float d2s[8192];
    __shared__ float rbv[4];
    __shared__ int rbi[4];
    const int q = blockIdx.x;
    const int b = q >> 7;
    const int tid = threadIdx.x;
    const int lane = tid & 63;
    const int wid = tid >> 6;
    const float c0 = cent[q * 4 + 0], c1 = cent[q * 4 + 1], c2 = cent[q * 4 + 2], c3 = cent[q * 4 + 3];
    const float cc = c0 * c0 + c1 * c1 + c2 * c2 + c3 * c3;
    for (int p = tid; p < 8192; p += 256) {
        const int n = b * 8192 + p;
        const float x0 = coords[3 * n], x1 = coords[3 * n + 1], x2 = coords[3 * n + 2], x3 = times[n];
        const float pp = x0 * x0 + x1 * x1 + x2 * x2 + x3 * x3;
        const float dt = x0 * c0 + x1 * c1 + x2 * c2 + x3 * c3;
        d2s[p] = cc + pp - 2.0f * dt;
    }
    __syncthreads();
    for (int r = 0; r < 16; ++r) {
        float v = __builtin_inff();
        int idx = 1 << 30;
        for (int s = 0; s < 32; ++s) {
            const int p = s * 256 + tid;
            const float d = d2s[p];
            if (d < v) { v = d; idx = p; }
        }
#pragma unroll
        for (int off = 32; off > 0; off >>= 1) {
            const float ov = __shfl_down(v, off);
            const int oi = __shfl_down(idx, off);
            if (ov < v || (ov == v && oi < idx)) { v = ov; idx = oi; }
        }
        if (lane == 0) { rbv[wid] = v; rbi[wid] = idx; }
        __syncthreads();
        if (tid == 0) {
            float bb = rbv[0]; int bi = rbi[0];
            for (int w = 1; w < 4; ++w)
                if (rbv[w] < bb || (rbv[w] == bb && rbi[w] < bi)) { bb = rbv[w]; bi = rbi[w]; }
            knn[q * 16 + r] = bi;
            d2s[bi] = __builtin_inff();
        }
        __syncthreads();
    }
}

// ---------------------------------------------------------------------------
// Gather features for the 16384 knn rows into bf16 A0 (K padded 32->64 with 0)
// ---------------------------------------------------------------------------
__global__ __launch_bounds__(256) void gather_kernel(const float* __restrict__ feat,
                                                     const int* __restrict__ knn,
                                                     u16* __restrict__ A0) {
    const int idx = blockIdx.x * 256 + threadIdx.x;  // 16384*64
    const int g = idx >> 6;
    const int c = idx & 63;
    const int b = g >> 11;  // g / (T*K)=g/2048
    const int n = b * 8192 + knn[g];
    const float v = (c < 32) ? feat[(size_t)n * 32 + c] : 0.0f;
    A0[idx] = f2bf(v);
}

// All six weight transposes in ONE launch. Segment boundaries are 256-aligned
// so each block is branch-uniform.
template <int K, int N, int KP>
__device__ __forceinline__ void tp_one(const float* __restrict__ W, u16* __restrict__ Wt, int local) {
    const int n = local / KP;
    const int k = local - n * KP;
    const float v = (k < K) ? W[(size_t)k * N + n] : 0.0f;
    Wt[local] = f2bf(v);
}

__global__ __launch_bounds__(256) void transpose_all(const float* __restrict__ W0,
                                                     const float* __restrict__ W1,
                                                     const float* __restrict__ W2,
                                                     const float* __restrict__ W3,
                                                     const float* __restrict__ Wn0,
                                                     const float* __restrict__ Wn1,
                                                     u16* __restrict__ W0t, u16* __restrict__ W1t,
                                                     u16* __restrict__ W2t, u16* __restrict__ W3t,
                                                     u16* __restrict__ Wn0t, u16* __restrict__ Wn1t) {
    const int idx = blockIdx.x * 256 + threadIdx.x;
    if (idx < 16384) tp_one<32, 256, 64>(W0, W0t, idx);
    else if (idx < 147456) tp_one<256, 512, 256>(W1, W1t, idx - 16384);
    else if (idx < 540672) tp_one<512, 768, 512>(W2, W2t, idx - 147456);
    else if (idx < 1130496) tp_one<768, 768, 768>(W3, W3t, idx - 540672);
    else if (idx < 1720320) tp_one<768, 768, 768>(Wn0, Wn0t, idx - 1130496);
    else tp_one<768, 768, 768>(Wn1, Wn1t, idx - 1720320);
}

// Max-pool over K=16 gathered rows: PF (16384,768) bf16 -> pooled (1024,768)
__global__ __launch_bounds__(256) void pool_kernel(const u16* __restrict__ PF,
                                                   u16* __restrict__ pooled) {
    const int idx = blockIdx.x * 256 + threadIdx.x;  // 1024*768
    const int q = idx / 768;
    const int c = idx - q * 768;
    const u16* base = PF + (size_t)q * 16 * 768 + c;
    float best = -__builtin_inff();
    u16 bb = 0;
#pragma unroll
    for (int kk = 0; kk < 16; ++kk) {
        const u16 u = base[kk * 768];
        const float f = bf2f(u);
        if (f > best) { best = f; bb = u; }
    }
    pooled[idx] = bb;
}

// ---------------------------------------------------------------------------
// bf16 MFMA GEMM: C(M,N) = relu?(A(M,K) @ W(K,N) + bias), W given as Wt(N,K).
// 128x128 tile, BK=64, 4 waves (2x2 of 64x64), global_load_lds width 16,
// source-side XOR swizzle so ds_read_b128 is ~conflict-free.
// ---------------------------------------------------------------------------
template <int RELU, int OUTF32>
__global__ __launch_bounds__(256) void gemm_kernel(const u16* __restrict__ A,
                                                   const u16* __restrict__ Bt,
                                                   const float* __restrict__ bias,
                                                   void* __restrict__ Cv,
                                                   int M, int N, int K) {
    (void)M;
    __shared__ __align__(16) u16 As[128 * 64];
    __shared__ __align__(16) u16 Bs[128 * 64];
    const int tid = threadIdx.x;
    const int lane = tid & 63;
    const int wid = tid >> 6;
    const int brow = blockIdx.x * 128;
    const int bcol = blockIdx.y * 128;
    const int wm = (wid >> 1) * 64;
    const int wn = (wid & 1) * 64;

    f32x4 acc[4][4];
#pragma unroll
    for (int m = 0; m < 4; ++m)
#pragma unroll
        for (int n = 0; n < 4; ++n)
            acc[m][n] = f32x4{0.f, 0.f, 0.f, 0.f};

    const int srow = tid >> 3;    // 0..31
    const int schunk = tid & 7;   // 16B chunk within a 128B row
    const uint32_t lds_wave_base = (uint32_t)(wid * 1024);

    for (int k0 = 0; k0 < K; k0 += 64) {
#pragma unroll
        for (int i = 0; i < 4; ++i) {
            const int row = i * 32 + srow;
            const int sc = schunk ^ (row & 7);  // inverse-swizzled SOURCE chunk
            const u16* ga = A + (size_t)(brow + row) * K + (size_t)(k0 + sc * 8);
            const u16* gb = Bt + (size_t)(bcol + row) * K + (size_t)(k0 + sc * 8);
            const uint32_t lb = (uint32_t)(i * 4096) + lds_wave_base;  // wave-uniform base
            gload_lds16(ga, (char*)As + lb);
            gload_lds16(gb, (char*)Bs + lb);
        }
        __syncthreads();
#pragma unroll
        for (int kc = 0; kc < 2; ++kc) {
            short8 af[4], bfr[4];
#pragma unroll
            for (int m = 0; m < 4; ++m) {
                const int row = wm + m * 16 + (lane & 15);
                const int sc = (kc * 4 + (lane >> 4)) ^ (row & 7);
                af[m] = *(const short8*)(As + row * 64 + sc * 8);
            }
#pragma unroll
            for (int n = 0; n < 4; ++n) {
                const int row = wn + n * 16 + (lane & 15);
                const int sc = (kc * 4 + (lane >> 4)) ^ (row & 7);
                bfr[n] = *(const short8*)(Bs + row * 64 + sc * 8);
            }
#pragma unroll
            for (int m = 0; m < 4; ++m)
#pragma unroll
                for (int n = 0; n < 4; ++n)
                    acc[m][n] = __builtin_amdgcn_mfma_f32_16x16x32_bf16(af[m], bfr[n], acc[m][n], 0, 0, 0);
        }
        __syncthreads();
    }

#pragma unroll
    for (int m = 0; m < 4; ++m) {
        const int row0 = brow + wm + m * 16 + ((lane >> 4) << 2);
#pragma unroll
        for (int n = 0; n < 4; ++n) {
            const int col = bcol + wn + n * 16 + (lane & 15);
            const float bv = bias[col];
#pragma unroll
            for (int r = 0; r < 4; ++r) {
                float v = acc[m][n][r] + bv;
                if (RELU) v = fmaxf(v, 0.0f);
                if (OUTF32) ((float*)Cv)[(size_t)(row0 + r) * N + col] = v;
                else ((u16*)Cv)[(size_t)(row0 + r) * N + col] = f2bf(v);
            }
        }
    }
}

// ---------------------------------------------------------------------------
extern "C" void kernel_launch(void* const* d_in, const int* in_sizes, int n_in,
                              void* d_out, int out_size, void* d_ws, size_t ws_size,
                              hipStream_t stream) {
    (void)in_sizes; (void)n_in; (void)out_size; (void)ws_size;
    const float* coords = (const float*)d_in[0];
    const float* features = (const float*)d_in[1];
    const float* times = (const float*)d_in[3];
    const float* W0 = (const float*)d_in[4];
    const float* b0 = (const float*)d_in[5];
    const float* W1 = (const float*)d_in[6];
    const float* b1 = (const float*)d_in[7];
    const float* W2 = (const float*)d_in[8];
    const float* b2 = (const float*)d_in[9];
    const float* W3 = (const float*)d_in[10];
    const float* b3 = (const float*)d_in[11];
    const float* Wn0 = (const float*)d_in[12];
    const float* bn0 = (const float*)d_in[13];
    const float* Wn1 = (const float*)d_in[14];
    const float* bn1 = (const float*)d_in[15];

    char* ws = (char*)d_ws;
    int* knn = (int*)(ws + 16384);            // 16384 int
    u16* W0t = (u16*)(ws + 81920);            // 256x64
    u16* W1t = (u16*)(ws + 114688);           // 512x256
    u16* W2t = (u16*)(ws + 376832);           // 768x512
    u16* W3t = (u16*)(ws + 1163264);          // 768x768
    u16* Wn0t = (u16*)(ws + 2342912);         // 768x768
    u16* Wn1t = (u16*)(ws + 3522560);         // 768x768
    u16* bufX = (u16*)(ws + 4702208);         // 16384x768 bf16 max
    u16* bufY = (u16*)(ws + 29868032);        // 16384x768 bf16 max

    float* tokens_out = (float*)d_out;                    // (8,128,768)
    float* cent_out = (float*)d_out + 786432;             // (8,128,4)
    float* mask_out = (float*)d_out + 786432 + 4096;      // (8,128)

    // all weight transposes in one launch
    transpose_all<<<9024, 256, 0, stream>>>(W0, W1, W2, W3, Wn0, Wn1,
                                            W0t, W1t, W2t, W3t, Wn0t, Wn1t);

    // FPS -> centroids (fills centroid + mask outputs; knn reads cent_out)
    fps_kernel<<<8, 1024, 0, stream>>>(coords, times, cent_out, mask_out);
    // KNN top-16 per centroid
    knn_kernel<<<1024, 256, 0, stream>>>(coords, times, cent_out, knn);
    // gather knn rows' features (bf16, K padded to 64)
    gather_kernel<<<4096, 256, 0, stream>>>(features, knn, bufX);

    // MLP on gathered rows (M = 16384)
    gemm_kernel<1, 0><<<dim3(128, 2), 256, 0, stream>>>(bufX, W0t, b0, bufY, 16384, 256, 64);
    gemm_kernel<1, 0><<<dim3(128, 4), 256, 0, stream>>>(bufY, W1t, b1, bufX, 16384, 512, 256);
    gemm_kernel<1, 0><<<dim3(128, 6), 256, 0, stream>>>(bufX, W2t, b2, bufY, 16384, 768, 512);
    gemm_kernel<0, 0><<<dim3(128, 6), 256, 0, stream>>>(bufY, W3t, b3, bufX, 16384, 768, 768);

    // max-pool over the 16 neighbors
    pool_kernel<<<3072, 256, 0, stream>>>(bufX, bufY);

    // token MLP (M = 1024)
    gemm_kernel<1, 0><<<dim3(8, 6), 256, 0, stream>>>(bufY, Wn0t, bn0, bufX, 1024, 768, 768);
    gemm_kernel<0, 1><<<dim3(8, 6), 256, 0, stream>>>(bufX, Wn1t, bn1, tokens_out, 1024, 768, 768);
}

// Round 10
// 338.480 us; speedup vs baseline: 1.2090x; 1.1032x over previous
//
#include <hip/hip_runtime.h>
#include <stdint.h>

typedef unsigned short u16;
typedef __attribute__((ext_vector_type(8))) short short8;
typedef __attribute__((ext_vector_type(4))) float f32x4;
typedef __attribute__((ext_vector_type(2))) float f32x2;

#define NEG_F (-3.402823466e+38f)

__device__ __forceinline__ u16 f2bf(float x) {
    uint32_t u = __builtin_bit_cast(uint32_t, x);
    u = (u + 0x7fffu + ((u >> 16) & 1u)) >> 16;
    return (u16)u;
}
__device__ __forceinline__ float bf2f(u16 b) {
    uint32_t u = ((uint32_t)b) << 16;
    return __builtin_bit_cast(float, u);
}

__device__ __forceinline__ void gload_lds16(const void* g, void* l) {
    __builtin_amdgcn_global_load_lds((const __attribute__((address_space(1))) void*)g,
                                     (__attribute__((address_space(3))) void*)l, 16, 0, 0);
}

// One DPP argmax step: pull (v,idx) from another lane per CTRL, keep the
// larger v (ties -> smaller idx).
template <int CTRL, int RMASK>
__device__ __forceinline__ void argmax_dpp_step(float& v, int& i) {
    const int vb = __builtin_bit_cast(int, v);
    const int vv = __builtin_amdgcn_update_dpp(vb, vb, CTRL, RMASK, 0xf, false);
    const int ii = __builtin_amdgcn_update_dpp(i, i, CTRL, RMASK, 0xf, false);
    const float fv = __builtin_bit_cast(float, vv);
    if (fv > v || (fv == v && ii < i)) { v = fv; i = ii; }
}

// Full wave64 argmax -> result lands in lane 63.
__device__ __forceinline__ void argmax_wave(float& v, int& i) {
    argmax_dpp_step<0x111, 0xf>(v, i);  // row_shr:1
    argmax_dpp_step<0x112, 0xf>(v, i);  // row_shr:2
    argmax_dpp_step<0x114, 0xf>(v, i);  // row_shr:4
    argmax_dpp_step<0x118, 0xf>(v, i);  // row_shr:8
    argmax_dpp_step<0x142, 0xa>(v, i);  // row_bcast:15 -> rows 1,3
    argmax_dpp_step<0x143, 0xc>(v, i);  // row_bcast:31 -> rows 2,3
}

// DPP u64-max / u64-min steps (register-only).
template <int CTRL, int RMASK>
__device__ __forceinline__ unsigned long long dppmax_u64(unsigned long long k) {
    const int lo = (int)(uint32_t)(k & 0xffffffffull);
    const int hi = (int)(uint32_t)(k >> 32);
    const int lo2 = __builtin_amdgcn_update_dpp(lo, lo, CTRL, RMASK, 0xf, false);
    const int hi2 = __builtin_amdgcn_update_dpp(hi, hi, CTRL, RMASK, 0xf, false);
    const unsigned long long o =
        ((unsigned long long)(uint32_t)hi2 << 32) | (uint32_t)lo2;
    return (o > k) ? o : k;
}
template <int CTRL, int RMASK>
__device__ __forceinline__ unsigned long long dppmin_u64(unsigned long long k) {
    const int lo = (int)(uint32_t)(k & 0xffffffffull);
    const int hi = (int)(uint32_t)(k >> 32);
    const int lo2 = __builtin_amdgcn_update_dpp(lo, lo, CTRL, RMASK, 0xf, false);
    const int hi2 = __builtin_amdgcn_update_dpp(hi, hi, CTRL, RMASK, 0xf, false);
    const unsigned long long o =
        ((unsigned long long)(uint32_t)hi2 << 32) | (uint32_t)lo2;
    return (o < k) ? o : k;
}

// ---------------------------------------------------------------------------
// FPS v8: v7 structure (1024 threads, 16 waves, 1 barrier/iter, ping-pong
// kslot, DPP combine) with PACKED f32 distance math: f32x2 ops lower to
// v_pk_{sub,mul,fma}_f32 on gfx950, cutting the j-loop from ~12 to ~9 VALU
// issues per point. Rounding order of d2 changes (pairwise (x,z)+(y,w)
// instead of sequential) -- selection-robust: argmax margins on random data
// are many orders above ulp (same risk class as the already-passing fma
// contraction).
// ---------------------------------------------------------------------------
__global__ __launch_bounds__(1024, 4) void fps_kernel(const float* __restrict__ coords,
                                                      const float* __restrict__ times,
                                                      float* __restrict__ cent_out,
                                                      float* __restrict__ mask_out) {
    const int b = blockIdx.x;
    const int tid = threadIdx.x;   // 0..1023
    const int lane = tid & 63;
    const int wid = tid >> 6;      // 0..15

    __shared__ f32x4 pts[8192];            // 128 KiB (broadcast centroid fetch)
    __shared__ unsigned long long kslot[2][16];
    __shared__ float redv[16][4];

    f32x2 pxy[8], pzw[8];
    float md[8];
    float sx = 0.f, sy = 0.f, sz = 0.f, sw = 0.f;
#pragma unroll
    for (int j = 0; j < 8; ++j) {
        const int p = j * 1024 + tid;
        const int n = b * 8192 + p;
        const float x = coords[3 * n + 0];
        const float y = coords[3 * n + 1];
        const float z = coords[3 * n + 2];
        const float w = times[n];
        pxy[j] = f32x2{x, y};
        pzw[j] = f32x2{z, w};
        pts[p] = f32x4{x, y, z, w};
        sx += x; sy += y; sz += z; sw += w;
        md[j] = __builtin_inff();
    }
#pragma unroll
    for (int j = 0; j < 8; ++j) {
        asm volatile("" : "+v"(pxy[j]), "+v"(pzw[j]));
    }

#pragma unroll
    for (int off = 32; off > 0; off >>= 1) {
        sx += __shfl_down(sx, off);
        sy += __shfl_down(sy, off);
        sz += __shfl_down(sz, off);
        sw += __shfl_down(sw, off);
    }
    if (lane == 0) { redv[wid][0] = sx; redv[wid][1] = sy; redv[wid][2] = sz; redv[wid][3] = sw; }
    __syncthreads();
    float c0 = 0.f, c1 = 0.f, c2 = 0.f, c3 = 0.f;
#pragma unroll
    for (int w = 0; w < 16; ++w) { c0 += redv[w][0]; c1 += redv[w][1]; c2 += redv[w][2]; c3 += redv[w][3]; }
    c0 *= (1.0f / 8192.0f);
    c1 *= (1.0f / 8192.0f);
    c2 *= (1.0f / 8192.0f);
    c3 *= (1.0f / 8192.0f);
    f32x2 cxy = f32x2{c0, c1};
    f32x2 czw = f32x2{c2, c3};

    for (int t = 0; t < 128; ++t) {
        float v = -__builtin_inff();
        int jb = 0;
        if (t == 0) {
            // distances to the mean: pick argmax only, do NOT touch md
#pragma unroll
            for (int j = 0; j < 8; ++j) {
                const f32x2 d01 = pxy[j] - cxy;
                const f32x2 d23 = pzw[j] - czw;
                f32x2 s = d01 * d01;
                s += d23 * d23;
                const float d2 = s[0] + s[1];
                if (d2 > v) { v = d2; jb = j; }
            }
        } else {
#pragma unroll
            for (int j = 0; j < 8; ++j) {
                const f32x2 d01 = pxy[j] - cxy;
                const f32x2 d23 = pzw[j] - czw;
                f32x2 s = d01 * d01;
                s += d23 * d23;
                const float d2 = s[0] + s[1];
                const float nm = fminf(md[j], d2);
                md[j] = nm;
                if (nm > v) { v = nm; jb = j; }
            }
        }
        int idx = jb * 1024 + tid;
        argmax_wave(v, idx);
        if (lane == 63) {
            const uint32_t bv = __builtin_bit_cast(uint32_t, v);
            const uint32_t mk = (bv & 0x80000000u) ? ~bv : (bv | 0x80000000u);
            kslot[t & 1][wid] = ((unsigned long long)mk << 32) | (uint32_t)(0x7FFFFFFF - idx);
        }
        __syncthreads();
        unsigned long long k = kslot[t & 1][lane & 15];
        k = dppmax_u64<0x111, 0xf>(k);
        k = dppmax_u64<0x112, 0xf>(k);
        k = dppmax_u64<0x114, 0xf>(k);
        k = dppmax_u64<0x118, 0xf>(k);  // lane15 of each row = max
        const int klo = __builtin_amdgcn_readlane((int)(uint32_t)(k & 0xffffffffull), 15);
        const int sel = 0x7FFFFFFF - klo;
        const f32x4 C = pts[sel];   // same address across all lanes: broadcast
        cxy = f32x2{C[0], C[1]};
        czw = f32x2{C[2], C[3]};
        if (tid == (sel & 1023)) {
            const int js = sel >> 10;
#pragma unroll
            for (int j = 0; j < 8; ++j)
                if (j == js) md[j] = NEG_F;
        }
        if (tid == 0) {
            const int o = (b * 128 + t) * 4;
            cent_out[o + 0] = C[0]; cent_out[o + 1] = C[1];
            cent_out[o + 2] = C[2]; cent_out[o + 3] = C[3];
        }
    }
    if (tid < 128) mask_out[b * 128 + tid] = 1.0f;
}

// ---------------------------------------------------------------------------
// KNN v2: one block per centroid, d2 kept in 32 REGISTERS per thread (no LDS
// array, no 512KB/block LDS rescan). Per round: unrolled local argmin (strict
// <, ascending s -> first-index-wins), full-wave DPP u64-min, 4-slot ping-pong
// combine with one barrier. Same d2 values, same tie rules, same semilattice
// as the passing LDS version -> identical selection.
// ---------------------------------------------------------------------------
__global__ __launch_bounds__(256) void knn_kernel(const float* __restrict__ coords,
                                                  const float* __restrict__ times,
                                                  const float* __restrict__ cent,
                                                  int* __restrict__ knn) {
    __shared__ unsigned long long kslot[2][4];
    const int q = blockIdx.x;
    const int b = q >> 7;
    const int tid = threadIdx.x;
    const int lane = tid & 63;
    const int wid = tid >> 6;
    const float c0 = cent[q * 4 + 0], c1 = cent[q * 4 + 1], c2 = cent[q * 4 + 2], c3 = cent[q * 4 + 3];
    const float cc = c0 * c0 + c1 * c1 + c2 * c2 + c3 * c3;
    float d2r[32];
#pragma unroll
    for (int s = 0; s < 32; ++s) {
        const int n = b * 8192 + s * 256 + tid;
        const float x0 = coords[3 * n], x1 = coords[3 * n + 1], x2 = coords[3 * n + 2], x3 = times[n];
        const float pp = x0 * x0 + x1 * x1 + x2 * x2 + x3 * x3;
        const float dt = x0 * c0 + x1 * c1 + x2 * c2 + x3 * c3;
        d2r[s] = cc + pp - 2.0f * dt;
    }
    for (int r = 0; r < 16; ++r) {
        float v = __builtin_inff();
        int idx = 1 << 30;
#pragma unroll
        for (int s = 0; s < 32; ++s) {
            if (d2r[s] < v) { v = d2r[s]; idx = s * 256 + tid; }
        }
        const uint32_t bv = __builtin_bit_cast(uint32_t, v);
        const uint32_t mk = (bv & 0x80000000u) ? ~bv : (bv | 0x80000000u);  // ascending map
        unsigned long long key = ((unsigned long long)mk << 32) | (uint32_t)idx;
        key = dppmin_u64<0x111, 0xf>(key);
        key = dppmin_u64<0x112, 0xf>(key);
        key = dppmin_u64<0x114, 0xf>(key);
        key = dppmin_u64<0x118, 0xf>(key);
        key = dppmin_u64<0x142, 0xa>(key);  // row_bcast:15 -> rows 1,3
        key = dppmin_u64<0x143, 0xc>(key);  // row_bcast:31 -> rows 2,3 (lane63 = wave min)
        if (lane == 63) kslot[r & 1][wid] = key;
        __syncthreads();
        unsigned long long k = kslot[r & 1][lane & 3];
        k = dppmin_u64<0x111, 0xf>(k);
        k = dppmin_u64<0x112, 0xf>(k);      // lane3 of each row = min of 4
        const int sel = __builtin_amdgcn_readlane((int)(uint32_t)(k & 0xffffffffull), 3);
        if (tid == 0) knn[q * 16 + r] = sel;
        if (tid == (sel & 255)) {
            const int js = sel >> 8;
#pragma unroll
            for (int s = 0; s < 32; ++s)
                if (s == js) d2r[s] = __builtin_inff();
        }
    }
}

// ---------------------------------------------------------------------------
// Gather features for the 16384 knn rows into bf16 A0 (K padded 32->64 with 0)
// ---------------------------------------------------------------------------
__global__ __launch_bounds__(256) void gather_kernel(const float* __restrict__ feat,
                                                     const int* __restrict__ knn,
                                                     u16* __restrict__ A0) {
    const int idx = blockIdx.x * 256 + threadIdx.x;  // 16384*64
    const int g = idx >> 6;
    const int c = idx & 63;
    const int b = g >> 11;  // g / (T*K)=g/2048
    const int n = b * 8192 + knn[g];
    const float v = (c < 32) ? feat[(size_t)n * 32 + c] : 0.0f;
    A0[idx] = f2bf(v);
}

// All six weight transposes in ONE launch. Segment boundaries are 256-aligned
// so each block is branch-uniform.
template <int K, int N, int KP>
__device__ __forceinline__ void tp_one(const float* __restrict__ W, u16* __restrict__ Wt, int local) {
    const int n = local / KP;
    const int k = local - n * KP;
    const float v = (k < K) ? W[(size_t)k * N + n] : 0.0f;
    Wt[local] = f2bf(v);
}

__global__ __launch_bounds__(256) void transpose_all(const float* __restrict__ W0,
                                                     const float* __restrict__ W1,
                                                     const float* __restrict__ W2,
                                                     const float* __restrict__ W3,
                                                     const float* __restrict__ Wn0,
                                                     const float* __restrict__ Wn1,
                                                     u16* __restrict__ W0t, u16* __restrict__ W1t,
                                                     u16* __restrict__ W2t, u16* __restrict__ W3t,
                                                     u16* __restrict__ Wn0t, u16* __restrict__ Wn1t) {
    const int idx = blockIdx.x * 256 + threadIdx.x;
    if (idx < 16384) tp_one<32, 256, 64>(W0, W0t, idx);
    else if (idx < 147456) tp_one<256, 512, 256>(W1, W1t, idx - 16384);
    else if (idx < 540672) tp_one<512, 768, 512>(W2, W2t, idx - 147456);
    else if (idx < 1130496) tp_one<768, 768, 768>(W3, W3t, idx - 540672);
    else if (idx < 1720320) tp_one<768, 768, 768>(Wn0, Wn0t, idx - 1130496);
    else tp_one<768, 768, 768>(Wn1, Wn1t, idx - 1720320);
}

// ---------------------------------------------------------------------------
// bf16 MFMA GEMM: C(M,N) = relu?(A(M,K) @ W(K,N) + bias), W given as Wt(N,K).
// 128x128 tile, BK=64, 4 waves (2x2 of 64x64), global_load_lds width 16,
// source-side XOR swizzle so ds_read_b128 is ~conflict-free.
// POOL=1: fuse the 16-row max-pool into the epilogue (fragment m holds
// exactly one pool group; 3 fmax + shfl_xor(16,32) + bias; lanes<16 store
// pooled row (brow+wm)/16+m). Monotone bf16 rounding commutes with max ->
// bit-identical to the old pool kernel's output.
// ---------------------------------------------------------------------------
template <int RELU, int OUTF32, int POOL>
__global__ __launch_bounds__(256) void gemm_kernel(const u16* __restrict__ A,
                                                   const u16* __restrict__ Bt,
                                                   const float* __restrict__ bias,
                                                   void* __restrict__ Cv,
                                                   int M, int N, int K) {
    (void)M;
    __shared__ __align__(16) u16 As[128 * 64];
    __shared__ __align__(16) u16 Bs[128 * 64];
    const int tid = threadIdx.x;
    const int lane = tid & 63;
    const int wid = tid >> 6;
    const int brow = blockIdx.x * 128;
    const int bcol = blockIdx.y * 128;
    const int wm = (wid >> 1) * 64;
    const int wn = (wid & 1) * 64;

    f32x4 acc[4][4];
#pragma unroll
    for (int m = 0; m < 4; ++m)
#pragma unroll
        for (int n = 0; n < 4; ++n)
            acc[m][n] = f32x4{0.f, 0.f, 0.f, 0.f};

    const int srow = tid >> 3;    // 0..31
    const int schunk = tid & 7;   // 16B chunk within a 128B row
    const uint32_t lds_wave_base = (uint32_t)(wid * 1024);

    for (int k0 = 0; k0 < K; k0 += 64) {
#pragma unroll
        for (int i = 0; i < 4; ++i) {
            const int row = i * 32 + srow;
            const int sc = schunk ^ (row & 7);  // inverse-swizzled SOURCE chunk
            const u16* ga = A + (size_t)(brow + row) * K + (size_t)(k0 + sc * 8);
            const u16* gb = Bt + (size_t)(bcol + row) * K + (size_t)(k0 + sc * 8);
            const uint32_t lb = (uint32_t)(i * 4096) + lds_wave_base;  // wave-uniform base
            gload_lds16(ga, (char*)As + lb);
            gload_lds16(gb, (char*)Bs + lb);
        }
        __syncthreads();
#pragma unroll
        for (int kc = 0; kc < 2; ++kc) {
            short8 af[4], bfr[4];
#pragma unroll
            for (int m = 0; m < 4; ++m) {
                const int row = wm + m * 16 + (lane & 15);
                const int sc = (kc * 4 + (lane >> 4)) ^ (row & 7);
                af[m] = *(const short8*)(As + row * 64 + sc * 8);
            }
#pragma unroll
            for (int n = 0; n < 4; ++n) {
                const int row = wn + n * 16 + (lane & 15);
                const int sc = (kc * 4 + (lane >> 4)) ^ (row & 7);
                bfr[n] = *(const short8*)(Bs + row * 64 + sc * 8);
            }
#pragma unroll
            for (int m = 0; m < 4; ++m)
#pragma unroll
                for (int n = 0; n < 4; ++n)
                    acc[m][n] = __builtin_amdgcn_mfma_f32_16x16x32_bf16(af[m], bfr[n], acc[m][n], 0, 0, 0);
        }
        __syncthreads();
    }

    if (POOL) {
#pragma unroll
        for (int m = 0; m < 4; ++m) {
            const int prow = (brow >> 4) + (wm >> 4) + m;
#pragma unroll
            for (int n = 0; n < 4; ++n) {
                float v = fmaxf(fmaxf(acc[m][n][0], acc[m][n][1]),
                                fmaxf(acc[m][n][2], acc[m][n][3]));
                v = fmaxf(v, __shfl_xor(v, 16));
                v = fmaxf(v, __shfl_xor(v, 32));
                const int col = bcol + wn + n * 16 + (lane & 15);
                v += bias[col];
                if (lane < 16) ((u16*)Cv)[(size_t)prow * N + col] = f2bf(v);
            }
        }
    } else {
#pragma unroll
        for (int m = 0; m < 4; ++m) {
            const int row0 = brow + wm + m * 16 + ((lane >> 4) << 2);
#pragma unroll
            for (int n = 0; n < 4; ++n) {
                const int col = bcol + wn + n * 16 + (lane & 15);
                const float bv = bias[col];
#pragma unroll
                for (int r = 0; r < 4; ++r) {
                    float v = acc[m][n][r] + bv;
                    if (RELU) v = fmaxf(v, 0.0f);
                    if (OUTF32) ((float*)Cv)[(size_t)(row0 + r) * N + col] = v;
                    else ((u16*)Cv)[(size_t)(row0 + r) * N + col] = f2bf(v);
                }
            }
        }
    }
}

// ---------------------------------------------------------------------------
extern "C" void kernel_launch(void* const* d_in, const int* in_sizes, int n_in,
                              void* d_out, int out_size, void* d_ws, size_t ws_size,
                              hipStream_t stream) {
    (void)in_sizes; (void)n_in; (void)out_size; (void)ws_size;
    const float* coords = (const float*)d_in[0];
    const float* features = (const float*)d_in[1];
    const float* times = (const float*)d_in[3];
    const float* W0 = (const float*)d_in[4];
    const float* b0 = (const float*)d_in[5];
    const float* W1 = (const float*)d_in[6];
    const float* b1 = (const float*)d_in[7];
    const float* W2 = (const float*)d_in[8];
    const float* b2 = (const float*)d_in[9];
    const float* W3 = (const float*)d_in[10];
    const float* b3 = (const float*)d_in[11];
    const float* Wn0 = (const float*)d_in[12];
    const float* bn0 = (const float*)d_in[13];
    const float* Wn1 = (const float*)d_in[14];
    const float* bn1 = (const float*)d_in[15];

    char* ws = (char*)d_ws;
    int* knn = (int*)(ws + 16384);            // 16384 int
    u16* W0t = (u16*)(ws + 81920);            // 256x64
    u16* W1t = (u16*)(ws + 114688);           // 512x256
    u16* W2t = (u16*)(ws + 376832);           // 768x512
    u16* W3t = (u16*)(ws + 1163264);          // 768x768
    u16* Wn0t = (u16*)(ws + 2342912);         // 768x768
    u16* Wn1t = (u16*)(ws + 3522560);         // 768x768
    u16* bufX = (u16*)(ws + 4702208);         // 16384x768 bf16 max
    u16* bufY = (u16*)(ws + 29868032);        // 16384x768 bf16 max

    float* tokens_out = (float*)d_out;                    // (8,128,768)
    float* cent_out = (float*)d_out + 786432;             // (8,128,4)
    float* mask_out = (float*)d_out + 786432 + 4096;      // (8,128)

    // all weight transposes in one launch
    transpose_all<<<9024, 256, 0, stream>>>(W0, W1, W2, W3, Wn0, Wn1,
                                            W0t, W1t, W2t, W3t, Wn0t, Wn1t);

    // FPS -> centroids (fills centroid + mask outputs; knn reads cent_out)
    fps_kernel<<<8, 1024, 0, stream>>>(coords, times, cent_out, mask_out);
    // KNN top-16 per centroid (register-resident)
    knn_kernel<<<1024, 256, 0, stream>>>(coords, times, cent_out, knn);
    // gather knn rows' features (bf16, K padded to 64)
    gather_kernel<<<4096, 256, 0, stream>>>(features, knn, bufX);

    // MLP on gathered rows (M = 16384)
    gemm_kernel<1, 0, 0><<<dim3(128, 2), 256, 0, stream>>>(bufX, W0t, b0, bufY, 16384, 256, 64);
    gemm_kernel<1, 0, 0><<<dim3(128, 4), 256, 0, stream>>>(bufY, W1t, b1, bufX, 16384, 512, 256);
    gemm_kernel<1, 0, 0><<<dim3(128, 6), 256, 0, stream>>>(bufX, W2t, b2, bufY, 16384, 768, 512);
    // layer 4 with fused 16-row max-pool -> pooled (1024x768) in bufX
    gemm_kernel<0, 0, 1><<<dim3(128, 6), 256, 0, stream>>>(bufY, W3t, b3, bufX, 16384, 768, 768);

    // token MLP (M = 1024)
    gemm_kernel<1, 0, 0><<<dim3(8, 6), 256, 0, stream>>>(bufX, Wn0t, bn0, bufY, 1024, 768, 768);
    gemm_kernel<0, 1, 0><<<dim3(8, 6), 256, 0, stream>>>(bufY, Wn1t, bn1, tokens_out, 1024, 768, 768);
}

// Round 11
// 323.010 us; speedup vs baseline: 1.2669x; 1.0479x over previous
//
#include <hip/hip_runtime.h>
#include <stdint.h>

typedef unsigned short u16;
typedef __attribute__((ext_vector_type(8))) short short8;
typedef __attribute__((ext_vector_type(4))) float f32x4;
typedef __attribute__((ext_vector_type(2))) float f32x2;

#define NEG_F (-3.402823466e+38f)

__device__ __forceinline__ u16 f2bf(float x) {
    uint32_t u = __builtin_bit_cast(uint32_t, x);
    u = (u + 0x7fffu + ((u >> 16) & 1u)) >> 16;
    return (u16)u;
}
__device__ __forceinline__ float bf2f(u16 b) {
    uint32_t u = ((uint32_t)b) << 16;
    return __builtin_bit_cast(float, u);
}

__device__ __forceinline__ void gload_lds16(const void* g, void* l) {
    __builtin_amdgcn_global_load_lds((const __attribute__((address_space(1))) void*)g,
                                     (__attribute__((address_space(3))) void*)l, 16, 0, 0);
}

// One DPP argmax step: pull (v,idx) from another lane per CTRL, keep the
// larger v (ties -> smaller idx).
template <int CTRL, int RMASK>
__device__ __forceinline__ void argmax_dpp_step(float& v, int& i) {
    const int vb = __builtin_bit_cast(int, v);
    const int vv = __builtin_amdgcn_update_dpp(vb, vb, CTRL, RMASK, 0xf, false);
    const int ii = __builtin_amdgcn_update_dpp(i, i, CTRL, RMASK, 0xf, false);
    const float fv = __builtin_bit_cast(float, vv);
    if (fv > v || (fv == v && ii < i)) { v = fv; i = ii; }
}

// Full wave64 argmax -> result lands in lane 63.
__device__ __forceinline__ void argmax_wave(float& v, int& i) {
    argmax_dpp_step<0x111, 0xf>(v, i);  // row_shr:1
    argmax_dpp_step<0x112, 0xf>(v, i);  // row_shr:2
    argmax_dpp_step<0x114, 0xf>(v, i);  // row_shr:4
    argmax_dpp_step<0x118, 0xf>(v, i);  // row_shr:8
    argmax_dpp_step<0x142, 0xa>(v, i);  // row_bcast:15 -> rows 1,3
    argmax_dpp_step<0x143, 0xc>(v, i);  // row_bcast:31 -> rows 2,3
}

// DPP u64-max / u64-min steps (register-only).
template <int CTRL, int RMASK>
__device__ __forceinline__ unsigned long long dppmax_u64(unsigned long long k) {
    const int lo = (int)(uint32_t)(k & 0xffffffffull);
    const int hi = (int)(uint32_t)(k >> 32);
    const int lo2 = __builtin_amdgcn_update_dpp(lo, lo, CTRL, RMASK, 0xf, false);
    const int hi2 = __builtin_amdgcn_update_dpp(hi, hi, CTRL, RMASK, 0xf, false);
    const unsigned long long o =
        ((unsigned long long)(uint32_t)hi2 << 32) | (uint32_t)lo2;
    return (o > k) ? o : k;
}
template <int CTRL, int RMASK>
__device__ __forceinline__ unsigned long long dppmin_u64(unsigned long long k) {
    const int lo = (int)(uint32_t)(k & 0xffffffffull);
    const int hi = (int)(uint32_t)(k >> 32);
    const int lo2 = __builtin_amdgcn_update_dpp(lo, lo, CTRL, RMASK, 0xf, false);
    const int hi2 = __builtin_amdgcn_update_dpp(hi, hi, CTRL, RMASK, 0xf, false);
    const unsigned long long o =
        ((unsigned long long)(uint32_t)hi2 << 32) | (uint32_t)lo2;
    return (o < k) ? o : k;
}

// weight transpose helper: (K,N) f32 -> (N,KP) bf16, zero-padded in K
template <int K, int N, int KP>
__device__ __forceinline__ void tp_one(const float* __restrict__ W, u16* __restrict__ Wt, int local) {
    const int n = local / KP;
    const int k = local - n * KP;
    const float v = (k < K) ? W[(size_t)k * N + n] : 0.0f;
    Wt[local] = f2bf(v);
}

// ---------------------------------------------------------------------------
// FPS v9 + fused weight transpose (block specialization).
//
// Round-10 post-mortem: fps invariant ~200us across 5 structures; packed math
// (-25% j-loop VALU) moved it only 5% -> a ~3000cy serial tail dominates. The
// one thing every version shared: the tid==0 GLOBAL store of the centroid
// inside the t-loop. __syncthreads() = s_waitcnt vmcnt(0) lgkmcnt(0) +
// s_barrier, so every iteration wave 0 drains an HBM store (~900cy) before
// the barrier and 15 waves wait on it. v9 buffers centroids in LDS
// (cent_lds[t], written by thread t, read back by the same thread at the end
// -> no extra barrier) and writes global ONCE after the loop. The loop now
// has ZERO VMEM ops.
//
// Blocks 8.. do the weight transposes (independent of fps, other 248 CUs,
// hidden under fps). All segment boundaries are 1024-aligned -> block-uniform
// branches.
//
// Selection arithmetic identical to the passing round-10 kernel.
// ---------------------------------------------------------------------------
__global__ __launch_bounds__(1024, 4) void fps_kernel(const float* __restrict__ coords,
                                                      const float* __restrict__ times,
                                                      float* __restrict__ cent_out,
                                                      float* __restrict__ mask_out,
                                                      const float* __restrict__ W0,
                                                      const float* __restrict__ W1,
                                                      const float* __restrict__ W2,
                                                      const float* __restrict__ W3,
                                                      const float* __restrict__ Wn0,
                                                      const float* __restrict__ Wn1,
                                                      u16* __restrict__ W0t, u16* __restrict__ W1t,
                                                      u16* __restrict__ W2t, u16* __restrict__ W3t,
                                                      u16* __restrict__ Wn0t, u16* __restrict__ Wn1t) {
    const int tid = threadIdx.x;   // 0..1023

    if (blockIdx.x >= 8) {
        // ---- weight-transpose blocks ----
        const int idx = (blockIdx.x - 8) * 1024 + tid;
        if (idx < 16384) tp_one<32, 256, 64>(W0, W0t, idx);
        else if (idx < 147456) tp_one<256, 512, 256>(W1, W1t, idx - 16384);
        else if (idx < 540672) tp_one<512, 768, 512>(W2, W2t, idx - 147456);
        else if (idx < 1130496) tp_one<768, 768, 768>(W3, W3t, idx - 540672);
        else if (idx < 1720320) tp_one<768, 768, 768>(Wn0, Wn0t, idx - 1130496);
        else tp_one<768, 768, 768>(Wn1, Wn1t, idx - 1720320);
        return;
    }

    // ---- FPS blocks ----
    const int b = blockIdx.x;
    const int lane = tid & 63;
    const int wid = tid >> 6;      // 0..15

    __shared__ f32x4 pts[8192];            // 128 KiB (broadcast centroid fetch)
    __shared__ f32x4 cent_lds[128];
    __shared__ unsigned long long kslot[2][16];
    __shared__ float redv[16][4];

    f32x2 pxy[8], pzw[8];
    float md[8];
    float sx = 0.f, sy = 0.f, sz = 0.f, sw = 0.f;
#pragma unroll
    for (int j = 0; j < 8; ++j) {
        const int p = j * 1024 + tid;
        const int n = b * 8192 + p;
        const float x = coords[3 * n + 0];
        const float y = coords[3 * n + 1];
        const float z = coords[3 * n + 2];
        const float w = times[n];
        pxy[j] = f32x2{x, y};
        pzw[j] = f32x2{z, w};
        pts[p] = f32x4{x, y, z, w};
        sx += x; sy += y; sz += z; sw += w;
        md[j] = __builtin_inff();
    }
#pragma unroll
    for (int j = 0; j < 8; ++j) {
        asm volatile("" : "+v"(pxy[j]), "+v"(pzw[j]));
    }

#pragma unroll
    for (int off = 32; off > 0; off >>= 1) {
        sx += __shfl_down(sx, off);
        sy += __shfl_down(sy, off);
        sz += __shfl_down(sz, off);
        sw += __shfl_down(sw, off);
    }
    if (lane == 0) { redv[wid][0] = sx; redv[wid][1] = sy; redv[wid][2] = sz; redv[wid][3] = sw; }
    __syncthreads();
    float c0 = 0.f, c1 = 0.f, c2 = 0.f, c3 = 0.f;
#pragma unroll
    for (int w = 0; w < 16; ++w) { c0 += redv[w][0]; c1 += redv[w][1]; c2 += redv[w][2]; c3 += redv[w][3]; }
    c0 *= (1.0f / 8192.0f);
    c1 *= (1.0f / 8192.0f);
    c2 *= (1.0f / 8192.0f);
    c3 *= (1.0f / 8192.0f);
    f32x2 cxy = f32x2{c0, c1};
    f32x2 czw = f32x2{c2, c3};

    for (int t = 0; t < 128; ++t) {
        float v = -__builtin_inff();
        int jb = 0;
        if (t == 0) {
            // distances to the mean: pick argmax only, do NOT touch md
#pragma unroll
            for (int j = 0; j < 8; ++j) {
                const f32x2 d01 = pxy[j] - cxy;
                const f32x2 d23 = pzw[j] - czw;
                f32x2 s = d01 * d01;
                s += d23 * d23;
                const float d2 = s[0] + s[1];
                if (d2 > v) { v = d2; jb = j; }
            }
        } else {
#pragma unroll
            for (int j = 0; j < 8; ++j) {
                const f32x2 d01 = pxy[j] - cxy;
                const f32x2 d23 = pzw[j] - czw;
                f32x2 s = d01 * d01;
                s += d23 * d23;
                const float d2 = s[0] + s[1];
                const float nm = fminf(md[j], d2);
                md[j] = nm;
                if (nm > v) { v = nm; jb = j; }
            }
        }
        int idx = jb * 1024 + tid;
        argmax_wave(v, idx);
        if (lane == 63) {
            const uint32_t bv = __builtin_bit_cast(uint32_t, v);
            const uint32_t mk = (bv & 0x80000000u) ? ~bv : (bv | 0x80000000u);
            kslot[t & 1][wid] = ((unsigned long long)mk << 32) | (uint32_t)(0x7FFFFFFF - idx);
        }
        __syncthreads();
        unsigned long long k = kslot[t & 1][lane & 15];
        k = dppmax_u64<0x111, 0xf>(k);
        k = dppmax_u64<0x112, 0xf>(k);
        k = dppmax_u64<0x114, 0xf>(k);
        k = dppmax_u64<0x118, 0xf>(k);  // lane15 of each row = max
        const int klo = __builtin_amdgcn_readlane((int)(uint32_t)(k & 0xffffffffull), 15);
        const int sel = 0x7FFFFFFF - klo;
        const f32x4 C = pts[sel];   // same address across all lanes: broadcast
        cxy = f32x2{C[0], C[1]};
        czw = f32x2{C[2], C[3]};
        if (tid == (sel & 1023)) {
            const int js = sel >> 10;
#pragma unroll
            for (int j = 0; j < 8; ++j)
                if (j == js) md[j] = NEG_F;
        }
        // buffer in LDS; thread t writes and thread t reads back at the end
        if (tid == t) cent_lds[t] = C;
    }
    // single global write after the loop (no per-iteration vmcnt drain)
    if (tid < 128) {
        const f32x4 C = cent_lds[tid];
        f32x4* dst = (f32x4*)(cent_out + (size_t)(b * 128 + tid) * 4);
        *dst = C;
        mask_out[b * 128 + tid] = 1.0f;
    }
}

// ---------------------------------------------------------------------------
// KNN v2: one block per centroid, d2 kept in 32 REGISTERS per thread. Per
// round: unrolled local argmin (strict <, ascending s -> first-index-wins),
// full-wave DPP u64-min, 4-slot ping-pong combine with one barrier.
// ---------------------------------------------------------------------------
__global__ __launch_bounds__(256) void knn_kernel(const float* __restrict__ coords,
                                                  const float* __restrict__ times,
                                                  const float* __restrict__ cent,
                                                  int* __restrict__ knn) {
    __shared__ unsigned long long kslot[2][4];
    const int q = blockIdx.x;
    const int b = q >> 7;
    const int tid = threadIdx.x;
    const int lane = tid & 63;
    const int wid = tid >> 6;
    const float c0 = cent[q * 4 + 0], c1 = cent[q * 4 + 1], c2 = cent[q * 4 + 2], c3 = cent[q * 4 + 3];
    const float cc = c0 * c0 + c1 * c1 + c2 * c2 + c3 * c3;
    float d2r[32];
#pragma unroll
    for (int s = 0; s < 32; ++s) {
        const int n = b * 8192 + s * 256 + tid;
        const float x0 = coords[3 * n], x1 = coords[3 * n + 1], x2 = coords[3 * n + 2], x3 = times[n];
        const float pp = x0 * x0 + x1 * x1 + x2 * x2 + x3 * x3;
        const float dt = x0 * c0 + x1 * c1 + x2 * c2 + x3 * c3;
        d2r[s] = cc + pp - 2.0f * dt;
    }
    for (int r = 0; r < 16; ++r) {
        float v = __builtin_inff();
        int idx = 1 << 30;
#pragma unroll
        for (int s = 0; s < 32; ++s) {
            if (d2r[s] < v) { v = d2r[s]; idx = s * 256 + tid; }
        }
        const uint32_t bv = __builtin_bit_cast(uint32_t, v);
        const uint32_t mk = (bv & 0x80000000u) ? ~bv : (bv | 0x80000000u);  // ascending map
        unsigned long long key = ((unsigned long long)mk << 32) | (uint32_t)idx;
        key = dppmin_u64<0x111, 0xf>(key);
        key = dppmin_u64<0x112, 0xf>(key);
        key = dppmin_u64<0x114, 0xf>(key);
        key = dppmin_u64<0x118, 0xf>(key);
        key = dppmin_u64<0x142, 0xa>(key);  // row_bcast:15 -> rows 1,3
        key = dppmin_u64<0x143, 0xc>(key);  // row_bcast:31 -> rows 2,3 (lane63 = wave min)
        if (lane == 63) kslot[r & 1][wid] = key;
        __syncthreads();
        unsigned long long k = kslot[r & 1][lane & 3];
        k = dppmin_u64<0x111, 0xf>(k);
        k = dppmin_u64<0x112, 0xf>(k);      // lane3 of each row = min of 4
        const int sel = __builtin_amdgcn_readlane((int)(uint32_t)(k & 0xffffffffull), 3);
        if (tid == 0) knn[q * 16 + r] = sel;
        if (tid == (sel & 255)) {
            const int js = sel >> 8;
#pragma unroll
            for (int s = 0; s < 32; ++s)
                if (s == js) d2r[s] = __builtin_inff();
        }
    }
}

// ---------------------------------------------------------------------------
// Gather features for the 16384 knn rows into bf16 A0 (K padded 32->64 with 0)
// ---------------------------------------------------------------------------
__global__ __launch_bounds__(256) void gather_kernel(const float* __restrict__ feat,
                                                     const int* __restrict__ knn,
                                                     u16* __restrict__ A0) {
    const int idx = blockIdx.x * 256 + threadIdx.x;  // 16384*64
    const int g = idx >> 6;
    const int c = idx & 63;
    const int b = g >> 11;  // g / (T*K)=g/2048
    const int n = b * 8192 + knn[g];
    const float v = (c < 32) ? feat[(size_t)n * 32 + c] : 0.0f;
    A0[idx] = f2bf(v);
}

// ---------------------------------------------------------------------------
// bf16 MFMA GEMM: C(M,N) = relu?(A(M,K) @ W(K,N) + bias), W given as Wt(N,K).
// 128x128 tile, BK=64, 4 waves (2x2 of 64x64), global_load_lds width 16,
// source-side XOR swizzle so ds_read_b128 is ~conflict-free.
// POOL=1: fuse the 16-row max-pool into the epilogue.
// ---------------------------------------------------------------------------
template <int RELU, int OUTF32, int POOL>
__global__ __launch_bounds__(256) void gemm_kernel(const u16* __restrict__ A,
                                                   const u16* __restrict__ Bt,
                                                   const float* __restrict__ bias,
                                                   void* __restrict__ Cv,
                                                   int M, int N, int K) {
    (void)M;
    __shared__ __align__(16) u16 As[128 * 64];
    __shared__ __align__(16) u16 Bs[128 * 64];
    const int tid = threadIdx.x;
    const int lane = tid & 63;
    const int wid = tid >> 6;
    const int brow = blockIdx.x * 128;
    const int bcol = blockIdx.y * 128;
    const int wm = (wid >> 1) * 64;
    const int wn = (wid & 1) * 64;

    f32x4 acc[4][4];
#pragma unroll
    for (int m = 0; m < 4; ++m)
#pragma unroll
        for (int n = 0; n < 4; ++n)
            acc[m][n] = f32x4{0.f, 0.f, 0.f, 0.f};

    const int srow = tid >> 3;    // 0..31
    const int schunk = tid & 7;   // 16B chunk within a 128B row
    const uint32_t lds_wave_base = (uint32_t)(wid * 1024);

    for (int k0 = 0; k0 < K; k0 += 64) {
#pragma unroll
        for (int i = 0; i < 4; ++i) {
            const int row = i * 32 + srow;
            const int sc = schunk ^ (row & 7);  // inverse-swizzled SOURCE chunk
            const u16* ga = A + (size_t)(brow + row) * K + (size_t)(k0 + sc * 8);
            const u16* gb = Bt + (size_t)(bcol + row) * K + (size_t)(k0 + sc * 8);
            const uint32_t lb = (uint32_t)(i * 4096) + lds_wave_base;  // wave-uniform base
            gload_lds16(ga, (char*)As + lb);
            gload_lds16(gb, (char*)Bs + lb);
        }
        __syncthreads();
#pragma unroll
        for (int kc = 0; kc < 2; ++kc) {
            short8 af[4], bfr[4];
#pragma unroll
            for (int m = 0; m < 4; ++m) {
                const int row = wm + m * 16 + (lane & 15);
                const int sc = (kc * 4 + (lane >> 4)) ^ (row & 7);
                af[m] = *(const short8*)(As + row * 64 + sc * 8);
            }
#pragma unroll
            for (int n = 0; n < 4; ++n) {
                const int row = wn + n * 16 + (lane & 15);
                const int sc = (kc * 4 + (lane >> 4)) ^ (row & 7);
                bfr[n] = *(const short8*)(Bs + row * 64 + sc * 8);
            }
#pragma unroll
            for (int m = 0; m < 4; ++m)
#pragma unroll
                for (int n = 0; n < 4; ++n)
                    acc[m][n] = __builtin_amdgcn_mfma_f32_16x16x32_bf16(af[m], bfr[n], acc[m][n], 0, 0, 0);
        }
        __syncthreads();
    }

    if (POOL) {
#pragma unroll
        for (int m = 0; m < 4; ++m) {
            const int prow = (brow >> 4) + (wm >> 4) + m;
#pragma unroll
            for (int n = 0; n < 4; ++n) {
                float v = fmaxf(fmaxf(acc[m][n][0], acc[m][n][1]),
                                fmaxf(acc[m][n][2], acc[m][n][3]));
                v = fmaxf(v, __shfl_xor(v, 16));
                v = fmaxf(v, __shfl_xor(v, 32));
                const int col = bcol + wn + n * 16 + (lane & 15);
                v += bias[col];
                if (lane < 16) ((u16*)Cv)[(size_t)prow * N + col] = f2bf(v);
            }
        }
    } else {
#pragma unroll
        for (int m = 0; m < 4; ++m) {
            const int row0 = brow + wm + m * 16 + ((lane >> 4) << 2);
#pragma unroll
            for (int n = 0; n < 4; ++n) {
                const int col = bcol + wn + n * 16 + (lane & 15);
                const float bv = bias[col];
#pragma unroll
                for (int r = 0; r < 4; ++r) {
                    float v = acc[m][n][r] + bv;
                    if (RELU) v = fmaxf(v, 0.0f);
                    if (OUTF32) ((float*)Cv)[(size_t)(row0 + r) * N + col] = v;
                    else ((u16*)Cv)[(size_t)(row0 + r) * N + col] = f2bf(v);
                }
            }
        }
    }
}

// ---------------------------------------------------------------------------
extern "C" void kernel_launch(void* const* d_in, const int* in_sizes, int n_in,
                              void* d_out, int out_size, void* d_ws, size_t ws_size,
                              hipStream_t stream) {
    (void)in_sizes; (void)n_in; (void)out_size; (void)ws_size;
    const float* coords = (const float*)d_in[0];
    const float* features = (const float*)d_in[1];
    const float* times = (const float*)d_in[3];
    const float* W0 = (const float*)d_in[4];
    const float* b0 = (const float*)d_in[5];
    const float* W1 = (const float*)d_in[6];
    const float* b1 = (const float*)d_in[7];
    const float* W2 = (const float*)d_in[8];
    const float* b2 = (const float*)d_in[9];
    const float* W3 = (const float*)d_in[10];
    const float* b3 = (const float*)d_in[11];
    const float* Wn0 = (const float*)d_in[12];
    const float* bn0 = (const float*)d_in[13];
    const float* Wn1 = (const float*)d_in[14];
    const float* bn1 = (const float*)d_in[15];

    char* ws = (char*)d_ws;
    int* knn = (int*)(ws + 16384);            // 16384 int
    u16* W0t = (u16*)(ws + 81920);            // 256x64
    u16* W1t = (u16*)(ws + 114688);           // 512x256
    u16* W2t = (u16*)(ws + 376832);           // 768x512
    u16* W3t = (u16*)(ws + 1163264);          // 768x768
    u16* Wn0t = (u16*)(ws + 2342912);         // 768x768
    u16* Wn1t = (u16*)(ws + 3522560);         // 768x768
    u16* bufX = (u16*)(ws + 4702208);         // 16384x768 bf16 max
    u16* bufY = (u16*)(ws + 29868032);        // 16384x768 bf16 max

    float* tokens_out = (float*)d_out;                    // (8,128,768)
    float* cent_out = (float*)d_out + 786432;             // (8,128,4)
    float* mask_out = (float*)d_out + 786432 + 4096;      // (8,128)

    // FPS (blocks 0-7) + all weight transposes (blocks 8..2263) in one launch
    fps_kernel<<<2264, 1024, 0, stream>>>(coords, times, cent_out, mask_out,
                                          W0, W1, W2, W3, Wn0, Wn1,
                                          W0t, W1t, W2t, W3t, Wn0t, Wn1t);
    // KNN top-16 per centroid (register-resident)
    knn_kernel<<<1024, 256, 0, stream>>>(coords, times, cent_out, knn);
    // gather knn rows' features (bf16, K padded to 64)
    gather_kernel<<<4096, 256, 0, stream>>>(features, knn, bufX);

    // MLP on gathered rows (M = 16384)
    gemm_kernel<1, 0, 0><<<dim3(128, 2), 256, 0, stream>>>(bufX, W0t, b0, bufY, 16384, 256, 64);
    gemm_kernel<1, 0, 0><<<dim3(128, 4), 256, 0, stream>>>(bufY, W1t, b1, bufX, 16384, 512, 256);
    gemm_kernel<1, 0, 0><<<dim3(128, 6), 256, 0, stream>>>(bufX, W2t, b2, bufY, 16384, 768, 512);
    // layer 4 with fused 16-row max-pool -> pooled (1024x768) in bufX
    gemm_kernel<0, 0, 1><<<dim3(128, 6), 256, 0, stream>>>(bufY, W3t, b3, bufX, 16384, 768, 768);

    // token MLP (M = 1024)
    gemm_kernel<1, 0, 0><<<dim3(8, 6), 256, 0, stream>>>(bufX, Wn0t, bn0, bufY, 1024, 768, 768);
    gemm_kernel<0, 1, 0><<<dim3(8, 6), 256, 0, stream>>>(bufY, Wn1t, bn1, tokens_out, 1024, 768, 768);
}

// Round 12
// 291.113 us; speedup vs baseline: 1.4057x; 1.1096x over previous
//
#include <hip/hip_runtime.h>
#include <stdint.h>

typedef unsigned short u16;
typedef __attribute__((ext_vector_type(8))) short short8;
typedef __attribute__((ext_vector_type(4))) float f32x4;
typedef __attribute__((ext_vector_type(2))) float f32x2;

#define NEG_F (-3.402823466e+38f)

__device__ __forceinline__ u16 f2bf(float x) {
    uint32_t u = __builtin_bit_cast(uint32_t, x);
    u = (u + 0x7fffu + ((u >> 16) & 1u)) >> 16;
    return (u16)u;
}

__device__ __forceinline__ void gload_lds16(const void* g, void* l) {
    __builtin_amdgcn_global_load_lds((const __attribute__((address_space(1))) void*)g,
                                     (__attribute__((address_space(3))) void*)l, 16, 0, 0);
}

// One DPP argmax step: pull (v,idx) from another lane per CTRL, keep the
// larger v (ties -> smaller idx).
template <int CTRL, int RMASK>
__device__ __forceinline__ void argmax_dpp_step(float& v, int& i) {
    const int vb = __builtin_bit_cast(int, v);
    const int vv = __builtin_amdgcn_update_dpp(vb, vb, CTRL, RMASK, 0xf, false);
    const int ii = __builtin_amdgcn_update_dpp(i, i, CTRL, RMASK, 0xf, false);
    const float fv = __builtin_bit_cast(float, vv);
    if (fv > v || (fv == v && ii < i)) { v = fv; i = ii; }
}

// Full wave64 argmax -> result lands in lane 63.
__device__ __forceinline__ void argmax_wave(float& v, int& i) {
    argmax_dpp_step<0x111, 0xf>(v, i);  // row_shr:1
    argmax_dpp_step<0x112, 0xf>(v, i);  // row_shr:2
    argmax_dpp_step<0x114, 0xf>(v, i);  // row_shr:4
    argmax_dpp_step<0x118, 0xf>(v, i);  // row_shr:8
    argmax_dpp_step<0x142, 0xa>(v, i);  // row_bcast:15 -> rows 1,3
    argmax_dpp_step<0x143, 0xc>(v, i);  // row_bcast:31 -> rows 2,3
}

// DPP u64-max / u64-min steps (register-only).
template <int CTRL, int RMASK>
__device__ __forceinline__ unsigned long long dppmax_u64(unsigned long long k) {
    const int lo = (int)(uint32_t)(k & 0xffffffffull);
    const int hi = (int)(uint32_t)(k >> 32);
    const int lo2 = __builtin_amdgcn_update_dpp(lo, lo, CTRL, RMASK, 0xf, false);
    const int hi2 = __builtin_amdgcn_update_dpp(hi, hi, CTRL, RMASK, 0xf, false);
    const unsigned long long o =
        ((unsigned long long)(uint32_t)hi2 << 32) | (uint32_t)lo2;
    return (o > k) ? o : k;
}
template <int CTRL, int RMASK>
__device__ __forceinline__ unsigned long long dppmin_u64(unsigned long long k) {
    const int lo = (int)(uint32_t)(k & 0xffffffffull);
    const int hi = (int)(uint32_t)(k >> 32);
    const int lo2 = __builtin_amdgcn_update_dpp(lo, lo, CTRL, RMASK, 0xf, false);
    const int hi2 = __builtin_amdgcn_update_dpp(hi, hi, CTRL, RMASK, 0xf, false);
    const unsigned long long o =
        ((unsigned long long)(uint32_t)hi2 << 32) | (uint32_t)lo2;
    return (o < k) ? o : k;
}

// weight transpose helper: (K,N) f32 -> (N,KP) bf16, zero-padded in K
template <int K, int N, int KP>
__device__ __forceinline__ void tp_one(const float* __restrict__ W, u16* __restrict__ Wt, int local) {
    const int n = local / KP;
    const int k = local - n * KP;
    const float v = (k < K) ? W[(size_t)k * N + n] : 0.0f;
    Wt[local] = f2bf(v);
}

// ---------------------------------------------------------------------------
// FPS v10 + fused weight transpose.
//
// Round-11 post-mortem: fps is ISSUE-bound at ~80-90% per-active-CU VALUBusy
// with effective clock ~1.1-1.2GHz (8/256 CUs -> low DPM). Per-wave overhead
// (argmax 30 + combine 25 + key/misc 25 instr) is paid PER WAVE, so fewer,
// fatter waves cut per-SIMD issue: 16 waves = 4x(72+80)=608 instr/SIMD/iter;
// 8 waves = 2x(144+80)=448 (-26%). Round-4's 4-wave attempt at this was
// confounded by register rematerialization; 8 waves x 16 pts needs only ~80
// state VGPRs (budget 256 at launch_bounds(512,2)).
//  - 512 threads, 8 waves, 16 pts/thread pinned via asm "+v".
//  - mean replicates the 1024-thread summation order exactly (virtual thread
//    vt = tid + 512q owns p = (2j+q)*512 + tid; redv[wid+8q]; ascending-w
//    combine) -> bit-identical mean.
//  - selection = argmax with smallest-global-index tie-break (partition-
//    independent, identical to all passing rounds).
//  - t==0 (distances to mean, md untouched) peeled out of the loop.
//  - centroids buffered in LDS, written to global once at the end.
// Blocks 8.. do weight transposes (512-aligned boundaries).
// ---------------------------------------------------------------------------
__global__ __launch_bounds__(512, 2) void fps_kernel(const float* __restrict__ coords,
                                                     const float* __restrict__ times,
                                                     float* __restrict__ cent_out,
                                                     float* __restrict__ mask_out,
                                                     const float* __restrict__ W0,
                                                     const float* __restrict__ W1,
                                                     const float* __restrict__ W2,
                                                     const float* __restrict__ W3,
                                                     const float* __restrict__ Wn0,
                                                     const float* __restrict__ Wn1,
                                                     u16* __restrict__ W0t, u16* __restrict__ W1t,
                                                     u16* __restrict__ W2t, u16* __restrict__ W3t,
                                                     u16* __restrict__ Wn0t, u16* __restrict__ Wn1t) {
    const int tid = threadIdx.x;   // 0..511

    if (blockIdx.x >= 8) {
        // ---- weight-transpose blocks ----
        const int idx = (blockIdx.x - 8) * 512 + tid;
        if (idx < 16384) tp_one<32, 256, 64>(W0, W0t, idx);
        else if (idx < 147456) tp_one<256, 512, 256>(W1, W1t, idx - 16384);
        else if (idx < 540672) tp_one<512, 768, 512>(W2, W2t, idx - 147456);
        else if (idx < 1130496) tp_one<768, 768, 768>(W3, W3t, idx - 540672);
        else if (idx < 1720320) tp_one<768, 768, 768>(Wn0, Wn0t, idx - 1130496);
        else tp_one<768, 768, 768>(Wn1, Wn1t, idx - 1720320);
        return;
    }

    // ---- FPS blocks ----
    const int b = blockIdx.x;
    const int lane = tid & 63;
    const int wid = tid >> 6;      // physical wave 0..7

    __shared__ f32x4 pts[8192];            // 128 KiB (broadcast centroid fetch)
    __shared__ f32x4 cent_lds[128];
    __shared__ unsigned long long kslot[2][8];
    __shared__ float redv[16][4];

    f32x2 pxy[16], pzw[16];
    float md[16];
    // mean partials: q in {0,1}; point jj=2j+q belongs to virtual thread
    // vt = tid + 512q, accumulated in ascending j (== ascending jj per q)
    float sx[2] = {0.f, 0.f}, sy[2] = {0.f, 0.f}, sz[2] = {0.f, 0.f}, sw[2] = {0.f, 0.f};
#pragma unroll
    for (int jj = 0; jj < 16; ++jj) {
        const int p = jj * 512 + tid;
        const int n = b * 8192 + p;
        const float x = coords[3 * n + 0];
        const float y = coords[3 * n + 1];
        const float z = coords[3 * n + 2];
        const float w = times[n];
        pxy[jj] = f32x2{x, y};
        pzw[jj] = f32x2{z, w};
        pts[p] = f32x4{x, y, z, w};
        const int q = jj & 1;
        sx[q] += x; sy[q] += y; sz[q] += z; sw[q] += w;
        md[jj] = __builtin_inff();
    }
#pragma unroll
    for (int jj = 0; jj < 16; ++jj) {
        asm volatile("" : "+v"(pxy[jj]), "+v"(pzw[jj]));
    }

#pragma unroll
    for (int q = 0; q < 2; ++q) {
        float ax = sx[q], ay = sy[q], az = sz[q], aw = sw[q];
#pragma unroll
        for (int off = 32; off > 0; off >>= 1) {
            ax += __shfl_down(ax, off);
            ay += __shfl_down(ay, off);
            az += __shfl_down(az, off);
            aw += __shfl_down(aw, off);
        }
        if (lane == 0) {
            redv[wid + 8 * q][0] = ax;
            redv[wid + 8 * q][1] = ay;
            redv[wid + 8 * q][2] = az;
            redv[wid + 8 * q][3] = aw;
        }
    }
    __syncthreads();
    float c0 = 0.f, c1 = 0.f, c2 = 0.f, c3 = 0.f;
#pragma unroll
    for (int w = 0; w < 16; ++w) { c0 += redv[w][0]; c1 += redv[w][1]; c2 += redv[w][2]; c3 += redv[w][3]; }
    c0 *= (1.0f / 8192.0f);
    c1 *= (1.0f / 8192.0f);
    c2 *= (1.0f / 8192.0f);
    c3 *= (1.0f / 8192.0f);
    f32x2 cxy = f32x2{c0, c1};
    f32x2 czw = f32x2{c2, c3};

    // ---- t = 0 (peeled): distances to the mean, md untouched ----
    {
        float v = -__builtin_inff();
        int jb = 0;
#pragma unroll
        for (int jj = 0; jj < 16; ++jj) {
            const f32x2 d01 = pxy[jj] - cxy;
            const f32x2 d23 = pzw[jj] - czw;
            f32x2 s = d01 * d01;
            s += d23 * d23;
            const float d2 = s[0] + s[1];
            if (d2 > v) { v = d2; jb = jj; }
        }
        int idx = jb * 512 + tid;
        argmax_wave(v, idx);
        if (lane == 63) {
            const uint32_t bv = __builtin_bit_cast(uint32_t, v);
            const uint32_t mk = (bv & 0x80000000u) ? ~bv : (bv | 0x80000000u);
            kslot[0][wid] = ((unsigned long long)mk << 32) | (uint32_t)(0x7FFFFFFF - idx);
        }
        __syncthreads();
        unsigned long long k = kslot[0][lane & 7];
        k = dppmax_u64<0x111, 0xf>(k);
        k = dppmax_u64<0x112, 0xf>(k);
        k = dppmax_u64<0x114, 0xf>(k);  // lane7 of each 16-row = max of 8
        const int klo = __builtin_amdgcn_readlane((int)(uint32_t)(k & 0xffffffffull), 7);
        const int sel = 0x7FFFFFFF - klo;
        const f32x4 C = pts[sel];
        cxy = f32x2{C[0], C[1]};
        czw = f32x2{C[2], C[3]};
        if (tid == (sel & 511)) {
            const int js = sel >> 9;
#pragma unroll
            for (int jj = 0; jj < 16; ++jj)
                if (jj == js) md[jj] = NEG_F;
        }
        if (tid == 0) cent_lds[0] = C;
    }

    // ---- t = 1..127 ----
    for (int t = 1; t < 128; ++t) {
        float v = -__builtin_inff();
        int jb = 0;
#pragma unroll
        for (int jj = 0; jj < 16; ++jj) {
            const f32x2 d01 = pxy[jj] - cxy;
            const f32x2 d23 = pzw[jj] - czw;
            f32x2 s = d01 * d01;
            s += d23 * d23;
            const float d2 = s[0] + s[1];
            const float nm = fminf(md[jj], d2);
            md[jj] = nm;
            if (nm > v) { v = nm; jb = jj; }
        }
        int idx = jb * 512 + tid;
        argmax_wave(v, idx);
        if (lane == 63) {
            const uint32_t bv = __builtin_bit_cast(uint32_t, v);
            const uint32_t mk = (bv & 0x80000000u) ? ~bv : (bv | 0x80000000u);
            kslot[t & 1][wid] = ((unsigned long long)mk << 32) | (uint32_t)(0x7FFFFFFF - idx);
        }
        __syncthreads();
        unsigned long long k = kslot[t & 1][lane & 7];
        k = dppmax_u64<0x111, 0xf>(k);
        k = dppmax_u64<0x112, 0xf>(k);
        k = dppmax_u64<0x114, 0xf>(k);
        const int klo = __builtin_amdgcn_readlane((int)(uint32_t)(k & 0xffffffffull), 7);
        const int sel = 0x7FFFFFFF - klo;
        const f32x4 C = pts[sel];   // same address across all lanes: broadcast
        cxy = f32x2{C[0], C[1]};
        czw = f32x2{C[2], C[3]};
        if (tid == (sel & 511)) {
            const int js = sel >> 9;
#pragma unroll
            for (int jj = 0; jj < 16; ++jj)
                if (jj == js) md[jj] = NEG_F;
        }
        if (tid == t) cent_lds[t] = C;
    }
    // single global write after the loop
    if (tid < 128) {
        const f32x4 C = cent_lds[tid];
        f32x4* dst = (f32x4*)(cent_out + (size_t)(b * 128 + tid) * 4);
        *dst = C;
        mask_out[b * 128 + tid] = 1.0f;
    }
}

// ---------------------------------------------------------------------------
// KNN v3 (+fused gather): one block per centroid, d2 in 32 registers, DPP
// u64-min reduction, one barrier per round. After the 16 rounds the block
// gathers its 16 selected rows' features into A0 (bf16, K padded 32->64).
// knn indices never leave the block (global knn[] removed).
// ---------------------------------------------------------------------------
__global__ __launch_bounds__(256) void knn_gather_kernel(const float* __restrict__ coords,
                                                         const float* __restrict__ times,
                                                         const float* __restrict__ cent,
                                                         const float* __restrict__ feat,
                                                         u16* __restrict__ A0) {
    __shared__ unsigned long long kslot[2][4];
    __shared__ int sel_lds[16];
    const int q = blockIdx.x;
    const int b = q >> 7;
    const int tid = threadIdx.x;
    const int lane = tid & 63;
    const int wid = tid >> 6;
    const float c0 = cent[q * 4 + 0], c1 = cent[q * 4 + 1], c2 = cent[q * 4 + 2], c3 = cent[q * 4 + 3];
    const float cc = c0 * c0 + c1 * c1 + c2 * c2 + c3 * c3;
    float d2r[32];
#pragma unroll
    for (int s = 0; s < 32; ++s) {
        const int n = b * 8192 + s * 256 + tid;
        const float x0 = coords[3 * n], x1 = coords[3 * n + 1], x2 = coords[3 * n + 2], x3 = times[n];
        const float pp = x0 * x0 + x1 * x1 + x2 * x2 + x3 * x3;
        const float dt = x0 * c0 + x1 * c1 + x2 * c2 + x3 * c3;
        d2r[s] = cc + pp - 2.0f * dt;
    }
    for (int r = 0; r < 16; ++r) {
        float v = __builtin_inff();
        int idx = 1 << 30;
#pragma unroll
        for (int s = 0; s < 32; ++s) {
            if (d2r[s] < v) { v = d2r[s]; idx = s * 256 + tid; }
        }
        const uint32_t bv = __builtin_bit_cast(uint32_t, v);
        const uint32_t mk = (bv & 0x80000000u) ? ~bv : (bv | 0x80000000u);  // ascending map
        unsigned long long key = ((unsigned long long)mk << 32) | (uint32_t)idx;
        key = dppmin_u64<0x111, 0xf>(key);
        key = dppmin_u64<0x112, 0xf>(key);
        key = dppmin_u64<0x114, 0xf>(key);
        key = dppmin_u64<0x118, 0xf>(key);
        key = dppmin_u64<0x142, 0xa>(key);  // row_bcast:15 -> rows 1,3
        key = dppmin_u64<0x143, 0xc>(key);  // row_bcast:31 -> rows 2,3 (lane63 = wave min)
        if (lane == 63) kslot[r & 1][wid] = key;
        __syncthreads();
        unsigned long long k = kslot[r & 1][lane & 3];
        k = dppmin_u64<0x111, 0xf>(k);
        k = dppmin_u64<0x112, 0xf>(k);      // lane3 of each row = min of 4
        const int sel = __builtin_amdgcn_readlane((int)(uint32_t)(k & 0xffffffffull), 3);
        if (tid == 0) sel_lds[r] = sel;
        if (tid == (sel & 255)) {
            const int js = sel >> 8;
#pragma unroll
            for (int s = 0; s < 32; ++s)
                if (s == js) d2r[s] = __builtin_inff();
        }
    }
    __syncthreads();
    // fused gather: 16 rows x 64 cols for this centroid
#pragma unroll
    for (int i = 0; i < 4; ++i) {
        const int e = i * 256 + tid;        // 0..1023
        const int r = e >> 6;
        const int c = e & 63;
        const int n = b * 8192 + sel_lds[r];
        const float v = (c < 32) ? feat[(size_t)n * 32 + c] : 0.0f;
        A0[(size_t)(q * 16 + r) * 64 + c] = f2bf(v);
    }
}

// ---------------------------------------------------------------------------
// bf16 MFMA GEMM: C(M,N) = relu?(A(M,K) @ W(K,N) + bias), W given as Wt(N,K).
// 128x128 tile, BK=64, 4 waves (2x2 of 64x64), global_load_lds width 16,
// source-side XOR swizzle so ds_read_b128 is ~conflict-free.
// POOL=1: fuse the 16-row max-pool into the epilogue.
// ---------------------------------------------------------------------------
template <int RELU, int OUTF32, int POOL>
__global__ __launch_bounds__(256) void gemm_kernel(const u16* __restrict__ A,
                                                   const u16* __restrict__ Bt,
                                                   const float* __restrict__ bias,
                                                   void* __restrict__ Cv,
                                                   int M, int N, int K) {
    (void)M;
    __shared__ __align__(16) u16 As[128 * 64];
    __shared__ __align__(16) u16 Bs[128 * 64];
    const int tid = threadIdx.x;
    const int lane = tid & 63;
    const int wid = tid >> 6;
    const int brow = blockIdx.x * 128;
    const int bcol = blockIdx.y * 128;
    const int wm = (wid >> 1) * 64;
    const int wn = (wid & 1) * 64;

    f32x4 acc[4][4];
#pragma unroll
    for (int m = 0; m < 4; ++m)
#pragma unroll
        for (int n = 0; n < 4; ++n)
            acc[m][n] = f32x4{0.f, 0.f, 0.f, 0.f};

    const int srow = tid >> 3;    // 0..31
    const int schunk = tid & 7;   // 16B chunk within a 128B row
    const uint32_t lds_wave_base = (uint32_t)(wid * 1024);

    for (int k0 = 0; k0 < K; k0 += 64) {
#pragma unroll
        for (int i = 0; i < 4; ++i) {
            const int row = i * 32 + srow;
            const int sc = schunk ^ (row & 7);  // inverse-swizzled SOURCE chunk
            const u16* ga = A + (size_t)(brow + row) * K + (size_t)(k0 + sc * 8);
            const u16* gb = Bt + (size_t)(bcol + row) * K + (size_t)(k0 + sc * 8);
            const uint32_t lb = (uint32_t)(i * 4096) + lds_wave_base;  // wave-uniform base
            gload_lds16(ga, (char*)As + lb);
            gload_lds16(gb, (char*)Bs + lb);
        }
        __syncthreads();
#pragma unroll
        for (int kc = 0; kc < 2; ++kc) {
            short8 af[4], bfr[4];
#pragma unroll
            for (int m = 0; m < 4; ++m) {
                const int row = wm + m * 16 + (lane & 15);
                const int sc = (kc * 4 + (lane >> 4)) ^ (row & 7);
                af[m] = *(const short8*)(As + row * 64 + sc * 8);
            }
#pragma unroll
            for (int n = 0; n < 4; ++n) {
                const int row = wn + n * 16 + (lane & 15);
                const int sc = (kc * 4 + (lane >> 4)) ^ (row & 7);
                bfr[n] = *(const short8*)(Bs + row * 64 + sc * 8);
            }
#pragma unroll
            for (int m = 0; m < 4; ++m)
#pragma unroll
                for (int n = 0; n < 4; ++n)
                    acc[m][n] = __builtin_amdgcn_mfma_f32_16x16x32_bf16(af[m], bfr[n], acc[m][n], 0, 0, 0);
        }
        __syncthreads();
    }

    if (POOL) {
#pragma unroll
        for (int m = 0; m < 4; ++m) {
            const int prow = (brow >> 4) + (wm >> 4) + m;
#pragma unroll
            for (int n = 0; n < 4; ++n) {
                float v = fmaxf(fmaxf(acc[m][n][0], acc[m][n][1]),
                                fmaxf(acc[m][n][2], acc[m][n][3]));
                v = fmaxf(v, __shfl_xor(v, 16));
                v = fmaxf(v, __shfl_xor(v, 32));
                const int col = bcol + wn + n * 16 + (lane & 15);
                v += bias[col];
                if (lane < 16) ((u16*)Cv)[(size_t)prow * N + col] = f2bf(v);
            }
        }
    } else {
#pragma unroll
        for (int m = 0; m < 4; ++m) {
            const int row0 = brow + wm + m * 16 + ((lane >> 4) << 2);
#pragma unroll
            for (int n = 0; n < 4; ++n) {
                const int col = bcol + wn + n * 16 + (lane & 15);
                const float bv = bias[col];
#pragma unroll
                for (int r = 0; r < 4; ++r) {
                    float v = acc[m][n][r] + bv;
                    if (RELU) v = fmaxf(v, 0.0f);
                    if (OUTF32) ((float*)Cv)[(size_t)(row0 + r) * N + col] = v;
                    else ((u16*)Cv)[(size_t)(row0 + r) * N + col] = f2bf(v);
                }
            }
        }
    }
}

// ---------------------------------------------------------------------------
extern "C" void kernel_launch(void* const* d_in, const int* in_sizes, int n_in,
                              void* d_out, int out_size, void* d_ws, size_t ws_size,
                              hipStream_t stream) {
    (void)in_sizes; (void)n_in; (void)out_size; (void)ws_size;
    const float* coords = (const float*)d_in[0];
    const float* features = (const float*)d_in[1];
    const float* times = (const float*)d_in[3];
    const float* W0 = (const float*)d_in[4];
    const float* b0 = (const float*)d_in[5];
    const float* W1 = (const float*)d_in[6];
    const float* b1 = (const float*)d_in[7];
    const float* W2 = (const float*)d_in[8];
    const float* b2 = (const float*)d_in[9];
    const float* W3 = (const float*)d_in[10];
    const float* b3 = (const float*)d_in[11];
    const float* Wn0 = (const float*)d_in[12];
    const float* bn0 = (const float*)d_in[13];
    const float* Wn1 = (const float*)d_in[14];
    const float* bn1 = (const float*)d_in[15];

    char* ws = (char*)d_ws;
    u16* W0t = (u16*)(ws + 81920);            // 256x64
    u16* W1t = (u16*)(ws + 114688);           // 512x256
    u16* W2t = (u16*)(ws + 376832);           // 768x512
    u16* W3t = (u16*)(ws + 1163264);          // 768x768
    u16* Wn0t = (u16*)(ws + 2342912);         // 768x768
    u16* Wn1t = (u16*)(ws + 3522560);         // 768x768
    u16* bufX = (u16*)(ws + 4702208);         // 16384x768 bf16 max
    u16* bufY = (u16*)(ws + 29868032);        // 16384x768 bf16 max

    float* tokens_out = (float*)d_out;                    // (8,128,768)
    float* cent_out = (float*)d_out + 786432;             // (8,128,4)
    float* mask_out = (float*)d_out + 786432 + 4096;      // (8,128)

    // FPS (blocks 0-7) + all weight transposes (blocks 8..4519) in one launch
    fps_kernel<<<4520, 512, 0, stream>>>(coords, times, cent_out, mask_out,
                                         W0, W1, W2, W3, Wn0, Wn1,
                                         W0t, W1t, W2t, W3t, Wn0t, Wn1t);
    // KNN top-16 per centroid + fused feature gather -> A0 (bufX)
    knn_gather_kernel<<<1024, 256, 0, stream>>>(coords, times, cent_out, features, bufX);

    // MLP on gathered rows (M = 16384)
    gemm_kernel<1, 0, 0><<<dim3(128, 2), 256, 0, stream>>>(bufX, W0t, b0, bufY, 16384, 256, 64);
    gemm_kernel<1, 0, 0><<<dim3(128, 4), 256, 0, stream>>>(bufY, W1t, b1, bufX, 16384, 512, 256);
    gemm_kernel<1, 0, 0><<<dim3(128, 6), 256, 0, stream>>>(bufX, W2t, b2, bufY, 16384, 768, 512);
    // layer 4 with fused 16-row max-pool -> pooled (1024x768) in bufX
    gemm_kernel<0, 0, 1><<<dim3(128, 6), 256, 0, stream>>>(bufY, W3t, b3, bufX, 16384, 768, 768);

    // token MLP (M = 1024)
    gemm_kernel<1, 0, 0><<<dim3(8, 6), 256, 0, stream>>>(bufX, Wn0t, bn0, bufY, 1024, 768, 768);
    gemm_kernel<0, 1, 0><<<dim3(8, 6), 256, 0, stream>>>(bufY, Wn1t, bn1, tokens_out, 1024, 768, 768);
}

// Round 13
// 291.096 us; speedup vs baseline: 1.4058x; 1.0001x over previous
//
#include <hip/hip_runtime.h>
#include <stdint.h>

typedef unsigned short u16;
typedef __attribute__((ext_vector_type(8))) short short8;
typedef __attribute__((ext_vector_type(4))) float f32x4;
typedef __attribute__((ext_vector_type(2))) float f32x2;

#define NEG_F (-3.402823466e+38f)

__device__ __forceinline__ u16 f2bf(float x) {
    uint32_t u = __builtin_bit_cast(uint32_t, x);
    u = (u + 0x7fffu + ((u >> 16) & 1u)) >> 16;
    return (u16)u;
}

__device__ __forceinline__ void gload_lds16(const void* g, void* l) {
    __builtin_amdgcn_global_load_lds((const __attribute__((address_space(1))) void*)g,
                                     (__attribute__((address_space(3))) void*)l, 16, 0, 0);
}

// One DPP argmax step: pull (v,idx) from another lane per CTRL, keep the
// larger v (ties -> smaller idx).
template <int CTRL, int RMASK>
__device__ __forceinline__ void argmax_dpp_step(float& v, int& i) {
    const int vb = __builtin_bit_cast(int, v);
    const int vv = __builtin_amdgcn_update_dpp(vb, vb, CTRL, RMASK, 0xf, false);
    const int ii = __builtin_amdgcn_update_dpp(i, i, CTRL, RMASK, 0xf, false);
    const float fv = __builtin_bit_cast(float, vv);
    if (fv > v || (fv == v && ii < i)) { v = fv; i = ii; }
}

// Full wave64 argmax -> result lands in lane 63.
__device__ __forceinline__ void argmax_wave(float& v, int& i) {
    argmax_dpp_step<0x111, 0xf>(v, i);  // row_shr:1
    argmax_dpp_step<0x112, 0xf>(v, i);  // row_shr:2
    argmax_dpp_step<0x114, 0xf>(v, i);  // row_shr:4
    argmax_dpp_step<0x118, 0xf>(v, i);  // row_shr:8
    argmax_dpp_step<0x142, 0xa>(v, i);  // row_bcast:15 -> rows 1,3
    argmax_dpp_step<0x143, 0xc>(v, i);  // row_bcast:31 -> rows 2,3
}

// DPP u64-max / u64-min steps (register-only).
template <int CTRL, int RMASK>
__device__ __forceinline__ unsigned long long dppmax_u64(unsigned long long k) {
    const int lo = (int)(uint32_t)(k & 0xffffffffull);
    const int hi = (int)(uint32_t)(k >> 32);
    const int lo2 = __builtin_amdgcn_update_dpp(lo, lo, CTRL, RMASK, 0xf, false);
    const int hi2 = __builtin_amdgcn_update_dpp(hi, hi, CTRL, RMASK, 0xf, false);
    const unsigned long long o =
        ((unsigned long long)(uint32_t)hi2 << 32) | (uint32_t)lo2;
    return (o > k) ? o : k;
}
template <int CTRL, int RMASK>
__device__ __forceinline__ unsigned long long dppmin_u64(unsigned long long k) {
    const int lo = (int)(uint32_t)(k & 0xffffffffull);
    const int hi = (int)(uint32_t)(k >> 32);
    const int lo2 = __builtin_amdgcn_update_dpp(lo, lo, CTRL, RMASK, 0xf, false);
    const int hi2 = __builtin_amdgcn_update_dpp(hi, hi, CTRL, RMASK, 0xf, false);
    const unsigned long long o =
        ((unsigned long long)(uint32_t)hi2 << 32) | (uint32_t)lo2;
    return (o < k) ? o : k;
}

// weight transpose helper: (K,N) f32 -> (N,KP) bf16, zero-padded in K
template <int K, int N, int KP>
__device__ __forceinline__ void tp_one(const float* __restrict__ W, u16* __restrict__ Wt, int local) {
    const int n = local / KP;
    const int k = local - n * KP;
    const float v = (k < K) ? W[(size_t)k * N + n] : 0.0f;
    Wt[local] = f2bf(v);
}

// ---------------------------------------------------------------------------
// FPS v10 + fused weight transpose (unchanged from the passing round-12
// kernel except W0t is now transposed at Kpad=32 -- boundaries re-derived,
// all 512-aligned: 8192 / 139264 / 532480 / 1122304 / 1712128 / 2301952).
// ---------------------------------------------------------------------------
__global__ __launch_bounds__(512, 2) void fps_kernel(const float* __restrict__ coords,
                                                     const float* __restrict__ times,
                                                     float* __restrict__ cent_out,
                                                     float* __restrict__ mask_out,
                                                     const float* __restrict__ W0,
                                                     const float* __restrict__ W1,
                                                     const float* __restrict__ W2,
                                                     const float* __restrict__ W3,
                                                     const float* __restrict__ Wn0,
                                                     const float* __restrict__ Wn1,
                                                     u16* __restrict__ W0t, u16* __restrict__ W1t,
                                                     u16* __restrict__ W2t, u16* __restrict__ W3t,
                                                     u16* __restrict__ Wn0t, u16* __restrict__ Wn1t) {
    const int tid = threadIdx.x;   // 0..511

    if (blockIdx.x >= 8) {
        // ---- weight-transpose blocks ----
        const int idx = (blockIdx.x - 8) * 512 + tid;
        if (idx < 8192) tp_one<32, 256, 32>(W0, W0t, idx);
        else if (idx < 139264) tp_one<256, 512, 256>(W1, W1t, idx - 8192);
        else if (idx < 532480) tp_one<512, 768, 512>(W2, W2t, idx - 139264);
        else if (idx < 1122304) tp_one<768, 768, 768>(W3, W3t, idx - 532480);
        else if (idx < 1712128) tp_one<768, 768, 768>(Wn0, Wn0t, idx - 1122304);
        else tp_one<768, 768, 768>(Wn1, Wn1t, idx - 1712128);
        return;
    }

    // ---- FPS blocks ----
    const int b = blockIdx.x;
    const int lane = tid & 63;
    const int wid = tid >> 6;      // physical wave 0..7

    __shared__ f32x4 pts[8192];            // 128 KiB (broadcast centroid fetch)
    __shared__ f32x4 cent_lds[128];
    __shared__ unsigned long long kslot[2][8];
    __shared__ float redv[16][4];

    f32x2 pxy[16], pzw[16];
    float md[16];
    float sx[2] = {0.f, 0.f}, sy[2] = {0.f, 0.f}, sz[2] = {0.f, 0.f}, sw[2] = {0.f, 0.f};
#pragma unroll
    for (int jj = 0; jj < 16; ++jj) {
        const int p = jj * 512 + tid;
        const int n = b * 8192 + p;
        const float x = coords[3 * n + 0];
        const float y = coords[3 * n + 1];
        const float z = coords[3 * n + 2];
        const float w = times[n];
        pxy[jj] = f32x2{x, y};
        pzw[jj] = f32x2{z, w};
        pts[p] = f32x4{x, y, z, w};
        const int q = jj & 1;
        sx[q] += x; sy[q] += y; sz[q] += z; sw[q] += w;
        md[jj] = __builtin_inff();
    }
#pragma unroll
    for (int jj = 0; jj < 16; ++jj) {
        asm volatile("" : "+v"(pxy[jj]), "+v"(pzw[jj]));
    }

#pragma unroll
    for (int q = 0; q < 2; ++q) {
        float ax = sx[q], ay = sy[q], az = sz[q], aw = sw[q];
#pragma unroll
        for (int off = 32; off > 0; off >>= 1) {
            ax += __shfl_down(ax, off);
            ay += __shfl_down(ay, off);
            az += __shfl_down(az, off);
            aw += __shfl_down(aw, off);
        }
        if (lane == 0) {
            redv[wid + 8 * q][0] = ax;
            redv[wid + 8 * q][1] = ay;
            redv[wid + 8 * q][2] = az;
            redv[wid + 8 * q][3] = aw;
        }
    }
    __syncthreads();
    float c0 = 0.f, c1 = 0.f, c2 = 0.f, c3 = 0.f;
#pragma unroll
    for (int w = 0; w < 16; ++w) { c0 += redv[w][0]; c1 += redv[w][1]; c2 += redv[w][2]; c3 += redv[w][3]; }
    c0 *= (1.0f / 8192.0f);
    c1 *= (1.0f / 8192.0f);
    c2 *= (1.0f / 8192.0f);
    c3 *= (1.0f / 8192.0f);
    f32x2 cxy = f32x2{c0, c1};
    f32x2 czw = f32x2{c2, c3};

    // ---- t = 0 (peeled): distances to the mean, md untouched ----
    {
        float v = -__builtin_inff();
        int jb = 0;
#pragma unroll
        for (int jj = 0; jj < 16; ++jj) {
            const f32x2 d01 = pxy[jj] - cxy;
            const f32x2 d23 = pzw[jj] - czw;
            f32x2 s = d01 * d01;
            s += d23 * d23;
            const float d2 = s[0] + s[1];
            if (d2 > v) { v = d2; jb = jj; }
        }
        int idx = jb * 512 + tid;
        argmax_wave(v, idx);
        if (lane == 63) {
            const uint32_t bv = __builtin_bit_cast(uint32_t, v);
            const uint32_t mk = (bv & 0x80000000u) ? ~bv : (bv | 0x80000000u);
            kslot[0][wid] = ((unsigned long long)mk << 32) | (uint32_t)(0x7FFFFFFF - idx);
        }
        __syncthreads();
        unsigned long long k = kslot[0][lane & 7];
        k = dppmax_u64<0x111, 0xf>(k);
        k = dppmax_u64<0x112, 0xf>(k);
        k = dppmax_u64<0x114, 0xf>(k);
        const int klo = __builtin_amdgcn_readlane((int)(uint32_t)(k & 0xffffffffull), 7);
        const int sel = 0x7FFFFFFF - klo;
        const f32x4 C = pts[sel];
        cxy = f32x2{C[0], C[1]};
        czw = f32x2{C[2], C[3]};
        if (tid == (sel & 511)) {
            const int js = sel >> 9;
#pragma unroll
            for (int jj = 0; jj < 16; ++jj)
                if (jj == js) md[jj] = NEG_F;
        }
        if (tid == 0) cent_lds[0] = C;
    }

    // ---- t = 1..127 ----
    for (int t = 1; t < 128; ++t) {
        float v = -__builtin_inff();
        int jb = 0;
#pragma unroll
        for (int jj = 0; jj < 16; ++jj) {
            const f32x2 d01 = pxy[jj] - cxy;
            const f32x2 d23 = pzw[jj] - czw;
            f32x2 s = d01 * d01;
            s += d23 * d23;
            const float d2 = s[0] + s[1];
            const float nm = fminf(md[jj], d2);
            md[jj] = nm;
            if (nm > v) { v = nm; jb = jj; }
        }
        int idx = jb * 512 + tid;
        argmax_wave(v, idx);
        if (lane == 63) {
            const uint32_t bv = __builtin_bit_cast(uint32_t, v);
            const uint32_t mk = (bv & 0x80000000u) ? ~bv : (bv | 0x80000000u);
            kslot[t & 1][wid] = ((unsigned long long)mk << 32) | (uint32_t)(0x7FFFFFFF - idx);
        }
        __syncthreads();
        unsigned long long k = kslot[t & 1][lane & 7];
        k = dppmax_u64<0x111, 0xf>(k);
        k = dppmax_u64<0x112, 0xf>(k);
        k = dppmax_u64<0x114, 0xf>(k);
        const int klo = __builtin_amdgcn_readlane((int)(uint32_t)(k & 0xffffffffull), 7);
        const int sel = 0x7FFFFFFF - klo;
        const f32x4 C = pts[sel];   // same address across all lanes: broadcast
        cxy = f32x2{C[0], C[1]};
        czw = f32x2{C[2], C[3]};
        if (tid == (sel & 511)) {
            const int js = sel >> 9;
#pragma unroll
            for (int jj = 0; jj < 16; ++jj)
                if (jj == js) md[jj] = NEG_F;
        }
        if (tid == t) cent_lds[t] = C;
    }
    // single global write after the loop
    if (tid < 128) {
        const f32x4 C = cent_lds[tid];
        f32x4* dst = (f32x4*)(cent_out + (size_t)(b * 128 + tid) * 4);
        *dst = C;
        mask_out[b * 128 + tid] = 1.0f;
    }
}

// ---------------------------------------------------------------------------
// KNN v4 (+fused gather +fused L1): one block per centroid.
//  - d2 in 32 registers, DPP u64-min reduction, one barrier per round
//    (selection identical to the passing round-12 kernel).
//  - then gathers its 16 rows' features into LDS (bf16, 16x32),
//  - and computes h1 = relu(feat16x32 @ W0 + b0) (16x256) with 16 MFMA
//    16x16x32 ops (W0t staged in LDS, 256x32 bf16 = 16KB).
// Numerics identical to the old gather+L1-GEMM path: same f2bf rounding,
// same MFMA fragment convention, and the old K=64 zero-padding only added
// exact 0.0 to the f32 accumulator.
// ---------------------------------------------------------------------------
__global__ __launch_bounds__(256) void knn_l1_kernel(const float* __restrict__ coords,
                                                     const float* __restrict__ times,
                                                     const float* __restrict__ cent,
                                                     const float* __restrict__ feat,
                                                     const u16* __restrict__ W0t,
                                                     const float* __restrict__ b0,
                                                     u16* __restrict__ h1) {
    __shared__ unsigned long long kslot[2][4];
    __shared__ int sel_lds[16];
    __shared__ __align__(16) u16 At[16 * 32];    // 1KB gathered rows
    __shared__ __align__(16) u16 Wt[256 * 32];   // 16KB W0t
    const int q = blockIdx.x;
    const int b = q >> 7;
    const int tid = threadIdx.x;
    const int lane = tid & 63;
    const int wid = tid >> 6;

    // stage W0t (8192 u16 = 1024 short8 chunks, 4 per thread)
#pragma unroll
    for (int i = 0; i < 4; ++i) {
        const int e = i * 256 + tid;            // 0..1023
        ((short8*)Wt)[e] = ((const short8*)W0t)[e];
    }

    const float c0 = cent[q * 4 + 0], c1 = cent[q * 4 + 1], c2 = cent[q * 4 + 2], c3 = cent[q * 4 + 3];
    const float cc = c0 * c0 + c1 * c1 + c2 * c2 + c3 * c3;
    float d2r[32];
#pragma unroll
    for (int s = 0; s < 32; ++s) {
        const int n = b * 8192 + s * 256 + tid;
        const float x0 = coords[3 * n], x1 = coords[3 * n + 1], x2 = coords[3 * n + 2], x3 = times[n];
        const float pp = x0 * x0 + x1 * x1 + x2 * x2 + x3 * x3;
        const float dt = x0 * c0 + x1 * c1 + x2 * c2 + x3 * c3;
        d2r[s] = cc + pp - 2.0f * dt;
    }
    for (int r = 0; r < 16; ++r) {
        float v = __builtin_inff();
        int idx = 1 << 30;
#pragma unroll
        for (int s = 0; s < 32; ++s) {
            if (d2r[s] < v) { v = d2r[s]; idx = s * 256 + tid; }
        }
        const uint32_t bv = __builtin_bit_cast(uint32_t, v);
        const uint32_t mk = (bv & 0x80000000u) ? ~bv : (bv | 0x80000000u);  // ascending map
        unsigned long long key = ((unsigned long long)mk << 32) | (uint32_t)idx;
        key = dppmin_u64<0x111, 0xf>(key);
        key = dppmin_u64<0x112, 0xf>(key);
        key = dppmin_u64<0x114, 0xf>(key);
        key = dppmin_u64<0x118, 0xf>(key);
        key = dppmin_u64<0x142, 0xa>(key);  // row_bcast:15 -> rows 1,3
        key = dppmin_u64<0x143, 0xc>(key);  // row_bcast:31 -> rows 2,3 (lane63 = wave min)
        if (lane == 63) kslot[r & 1][wid] = key;
        __syncthreads();
        unsigned long long k = kslot[r & 1][lane & 3];
        k = dppmin_u64<0x111, 0xf>(k);
        k = dppmin_u64<0x112, 0xf>(k);      // lane3 of each row = min of 4
        const int sel = __builtin_amdgcn_readlane((int)(uint32_t)(k & 0xffffffffull), 3);
        if (tid == 0) sel_lds[r] = sel;
        if (tid == (sel & 255)) {
            const int js = sel >> 8;
#pragma unroll
            for (int s = 0; s < 32; ++s)
                if (s == js) d2r[s] = __builtin_inff();
        }
    }
    __syncthreads();
    // gather 16 rows x 32 feats into At (bf16)
#pragma unroll
    for (int i = 0; i < 2; ++i) {
        const int e = i * 256 + tid;        // 0..511
        const int r = e >> 5;
        const int c = e & 31;
        const int n = b * 8192 + sel_lds[r];
        At[e] = f2bf(feat[(size_t)n * 32 + c]);
    }
    __syncthreads();
    // L1: h1(16x256) = relu(At(16x32) @ W0 + b0); 4 n-tiles per wave
    const int arow = lane & 15;
    const int koff = (lane >> 4) * 8;
    const short8 afrag = *(const short8*)(At + arow * 32 + koff);
#pragma unroll
    for (int i = 0; i < 4; ++i) {
        const int nbase = (wid * 4 + i) * 16;
        const short8 bfrag = *(const short8*)(Wt + (nbase + (lane & 15)) * 32 + koff);
        f32x4 acc = f32x4{0.f, 0.f, 0.f, 0.f};
        acc = __builtin_amdgcn_mfma_f32_16x16x32_bf16(afrag, bfrag, acc, 0, 0, 0);
        const int col = nbase + (lane & 15);
        const float bv = b0[col];
        const int row0 = (lane >> 4) * 4;
#pragma unroll
        for (int rg = 0; rg < 4; ++rg) {
            const float vv = fmaxf(acc[rg] + bv, 0.0f);
            h1[(size_t)(q * 16 + row0 + rg) * 256 + col] = f2bf(vv);
        }
    }
}

// ---------------------------------------------------------------------------
// bf16 MFMA GEMM: C(M,N) = relu?(A(M,K) @ W(K,N) + bias), W given as Wt(N,K).
// 128x128 tile, BK=64, 4 waves (2x2 of 64x64), global_load_lds width 16,
// source-side XOR swizzle so ds_read_b128 is ~conflict-free.
// POOL=1: fuse the 16-row max-pool into the epilogue.
// ---------------------------------------------------------------------------
template <int RELU, int OUTF32, int POOL>
__global__ __launch_bounds__(256) void gemm_kernel(const u16* __restrict__ A,
                                                   const u16* __restrict__ Bt,
                                                   const float* __restrict__ bias,
                                                   void* __restrict__ Cv,
                                                   int M, int N, int K) {
    (void)M;
    __shared__ __align__(16) u16 As[128 * 64];
    __shared__ __align__(16) u16 Bs[128 * 64];
    const int tid = threadIdx.x;
    const int lane = tid & 63;
    const int wid = tid >> 6;
    const int brow = blockIdx.x * 128;
    const int bcol = blockIdx.y * 128;
    const int wm = (wid >> 1) * 64;
    const int wn = (wid & 1) * 64;

    f32x4 acc[4][4];
#pragma unroll
    for (int m = 0; m < 4; ++m)
#pragma unroll
        for (int n = 0; n < 4; ++n)
            acc[m][n] = f32x4{0.f, 0.f, 0.f, 0.f};

    const int srow = tid >> 3;    // 0..31
    const int schunk = tid & 7;   // 16B chunk within a 128B row
    const uint32_t lds_wave_base = (uint32_t)(wid * 1024);

    for (int k0 = 0; k0 < K; k0 += 64) {
#pragma unroll
        for (int i = 0; i < 4; ++i) {
            const int row = i * 32 + srow;
            const int sc = schunk ^ (row & 7);  // inverse-swizzled SOURCE chunk
            const u16* ga = A + (size_t)(brow + row) * K + (size_t)(k0 + sc * 8);
            const u16* gb = Bt + (size_t)(bcol + row) * K + (size_t)(k0 + sc * 8);
            const uint32_t lb = (uint32_t)(i * 4096) + lds_wave_base;  // wave-uniform base
            gload_lds16(ga, (char*)As + lb);
            gload_lds16(gb, (char*)Bs + lb);
        }
        __syncthreads();
#pragma unroll
        for (int kc = 0; kc < 2; ++kc) {
            short8 af[4], bfr[4];
#pragma unroll
            for (int m = 0; m < 4; ++m) {
                const int row = wm + m * 16 + (lane & 15);
                const int sc = (kc * 4 + (lane >> 4)) ^ (row & 7);
                af[m] = *(const short8*)(As + row * 64 + sc * 8);
            }
#pragma unroll
            for (int n = 0; n < 4; ++n) {
                const int row = wn + n * 16 + (lane & 15);
                const int sc = (kc * 4 + (lane >> 4)) ^ (row & 7);
                bfr[n] = *(const short8*)(Bs + row * 64 + sc * 8);
            }
#pragma unroll
            for (int m = 0; m < 4; ++m)
#pragma unroll
                for (int n = 0; n < 4; ++n)
                    acc[m][n] = __builtin_amdgcn_mfma_f32_16x16x32_bf16(af[m], bfr[n], acc[m][n], 0, 0, 0);
        }
        __syncthreads();
    }

    if (POOL) {
#pragma unroll
        for (int m = 0; m < 4; ++m) {
            const int prow = (brow >> 4) + (wm >> 4) + m;
#pragma unroll
            for (int n = 0; n < 4; ++n) {
                float v = fmaxf(fmaxf(acc[m][n][0], acc[m][n][1]),
                                fmaxf(acc[m][n][2], acc[m][n][3]));
                v = fmaxf(v, __shfl_xor(v, 16));
                v = fmaxf(v, __shfl_xor(v, 32));
                const int col = bcol + wn + n * 16 + (lane & 15);
                v += bias[col];
                if (lane < 16) ((u16*)Cv)[(size_t)prow * N + col] = f2bf(v);
            }
        }
    } else {
#pragma unroll
        for (int m = 0; m < 4; ++m) {
            const int row0 = brow + wm + m * 16 + ((lane >> 4) << 2);
#pragma unroll
            for (int n = 0; n < 4; ++n) {
                const int col = bcol + wn + n * 16 + (lane & 15);
                const float bv = bias[col];
#pragma unroll
                for (int r = 0; r < 4; ++r) {
                    float v = acc[m][n][r] + bv;
                    if (RELU) v = fmaxf(v, 0.0f);
                    if (OUTF32) ((float*)Cv)[(size_t)(row0 + r) * N + col] = v;
                    else ((u16*)Cv)[(size_t)(row0 + r) * N + col] = f2bf(v);
                }
            }
        }
    }
}

// ---------------------------------------------------------------------------
extern "C" void kernel_launch(void* const* d_in, const int* in_sizes, int n_in,
                              void* d_out, int out_size, void* d_ws, size_t ws_size,
                              hipStream_t stream) {
    (void)in_sizes; (void)n_in; (void)out_size; (void)ws_size;
    const float* coords = (const float*)d_in[0];
    const float* features = (const float*)d_in[1];
    const float* times = (const float*)d_in[3];
    const float* W0 = (const float*)d_in[4];
    const float* b0 = (const float*)d_in[5];
    const float* W1 = (const float*)d_in[6];
    const float* b1 = (const float*)d_in[7];
    const float* W2 = (const float*)d_in[8];
    const float* b2 = (const float*)d_in[9];
    const float* W3 = (const float*)d_in[10];
    const float* b3 = (const float*)d_in[11];
    const float* Wn0 = (const float*)d_in[12];
    const float* bn0 = (const float*)d_in[13];
    const float* Wn1 = (const float*)d_in[14];
    const float* bn1 = (const float*)d_in[15];

    char* ws = (char*)d_ws;
    u16* W0t = (u16*)(ws + 81920);            // 256x32
    u16* W1t = (u16*)(ws + 114688);           // 512x256
    u16* W2t = (u16*)(ws + 376832);           // 768x512
    u16* W3t = (u16*)(ws + 1163264);          // 768x768
    u16* Wn0t = (u16*)(ws + 2342912);         // 768x768
    u16* Wn1t = (u16*)(ws + 3522560);         // 768x768
    u16* bufX = (u16*)(ws + 4702208);         // 16384x768 bf16 max
    u16* bufY = (u16*)(ws + 29868032);        // 16384x768 bf16 max

    float* tokens_out = (float*)d_out;                    // (8,128,768)
    float* cent_out = (float*)d_out + 786432;             // (8,128,4)
    float* mask_out = (float*)d_out + 786432 + 4096;      // (8,128)

    // FPS (blocks 0-7) + all weight transposes (blocks 8..4503) in one launch
    fps_kernel<<<4504, 512, 0, stream>>>(coords, times, cent_out, mask_out,
                                         W0, W1, W2, W3, Wn0, Wn1,
                                         W0t, W1t, W2t, W3t, Wn0t, Wn1t);
    // KNN top-16 + fused gather + fused L1 -> h1 (16384x256 bf16) in bufX
    knn_l1_kernel<<<1024, 256, 0, stream>>>(coords, times, cent_out, features,
                                            W0t, b0, bufX);

    // MLP layers 2-4 on gathered rows (M = 16384)
    gemm_kernel<1, 0, 0><<<dim3(128, 4), 256, 0, stream>>>(bufX, W1t, b1, bufY, 16384, 512, 256);
    gemm_kernel<1, 0, 0><<<dim3(128, 6), 256, 0, stream>>>(bufY, W2t, b2, bufX, 16384, 768, 512);
    // layer 4 with fused 16-row max-pool -> pooled (1024x768) in bufY
    gemm_kernel<0, 0, 1><<<dim3(128, 6), 256, 0, stream>>>(bufX, W3t, b3, bufY, 16384, 768, 768);

    // token MLP (M = 1024)
    gemm_kernel<1, 0, 0><<<dim3(8, 6), 256, 0, stream>>>(bufY, Wn0t, bn0, bufX, 1024, 768, 768);
    gemm_kernel<0, 1, 0><<<dim3(8, 6), 256, 0, stream>>>(bufX, Wn1t, bn1, tokens_out, 1024, 768, 768);
}

// Round 14
// 284.362 us; speedup vs baseline: 1.4390x; 1.0237x over previous
//
#include <hip/hip_runtime.h>
#include <stdint.h>

typedef unsigned short u16;
typedef __attribute__((ext_vector_type(8))) short short8;
typedef __attribute__((ext_vector_type(4))) float f32x4;
typedef __attribute__((ext_vector_type(2))) float f32x2;

#define NEG_F (-3.402823466e+38f)

__device__ __forceinline__ u16 f2bf(float x) {
    uint32_t u = __builtin_bit_cast(uint32_t, x);
    u = (u + 0x7fffu + ((u >> 16) & 1u)) >> 16;
    return (u16)u;
}

__device__ __forceinline__ void gload_lds16(const void* g, void* l) {
    __builtin_amdgcn_global_load_lds((const __attribute__((address_space(1))) void*)g,
                                     (__attribute__((address_space(3))) void*)l, 16, 0, 0);
}

__device__ __forceinline__ f32x2 pkmin2(f32x2 a, f32x2 b) {
    return f32x2{fminf(a[0], b[0]), fminf(a[1], b[1])};
}
__device__ __forceinline__ f32x2 pkmax2(f32x2 a, f32x2 b) {
    return f32x2{fmaxf(a[0], b[0]), fmaxf(a[1], b[1])};
}

// One DPP argmax step: pull (v,idx) from another lane per CTRL, keep the
// larger v (ties -> smaller idx).
template <int CTRL, int RMASK>
__device__ __forceinline__ void argmax_dpp_step(float& v, int& i) {
    const int vb = __builtin_bit_cast(int, v);
    const int vv = __builtin_amdgcn_update_dpp(vb, vb, CTRL, RMASK, 0xf, false);
    const int ii = __builtin_amdgcn_update_dpp(i, i, CTRL, RMASK, 0xf, false);
    const float fv = __builtin_bit_cast(float, vv);
    if (fv > v || (fv == v && ii < i)) { v = fv; i = ii; }
}

// Full wave64 argmax -> result lands in lane 63.
__device__ __forceinline__ void argmax_wave(float& v, int& i) {
    argmax_dpp_step<0x111, 0xf>(v, i);  // row_shr:1
    argmax_dpp_step<0x112, 0xf>(v, i);  // row_shr:2
    argmax_dpp_step<0x114, 0xf>(v, i);  // row_shr:4
    argmax_dpp_step<0x118, 0xf>(v, i);  // row_shr:8
    argmax_dpp_step<0x142, 0xa>(v, i);  // row_bcast:15 -> rows 1,3
    argmax_dpp_step<0x143, 0xc>(v, i);  // row_bcast:31 -> rows 2,3
}

// DPP u64-max / u64-min steps (register-only).
template <int CTRL, int RMASK>
__device__ __forceinline__ unsigned long long dppmax_u64(unsigned long long k) {
    const int lo = (int)(uint32_t)(k & 0xffffffffull);
    const int hi = (int)(uint32_t)(k >> 32);
    const int lo2 = __builtin_amdgcn_update_dpp(lo, lo, CTRL, RMASK, 0xf, false);
    const int hi2 = __builtin_amdgcn_update_dpp(hi, hi, CTRL, RMASK, 0xf, false);
    const unsigned long long o =
        ((unsigned long long)(uint32_t)hi2 << 32) | (uint32_t)lo2;
    return (o > k) ? o : k;
}
template <int CTRL, int RMASK>
__device__ __forceinline__ unsigned long long dppmin_u64(unsigned long long k) {
    const int lo = (int)(uint32_t)(k & 0xffffffffull);
    const int hi = (int)(uint32_t)(k >> 32);
    const int lo2 = __builtin_amdgcn_update_dpp(lo, lo, CTRL, RMASK, 0xf, false);
    const int hi2 = __builtin_amdgcn_update_dpp(hi, hi, CTRL, RMASK, 0xf, false);
    const unsigned long long o =
        ((unsigned long long)(uint32_t)hi2 << 32) | (uint32_t)lo2;
    return (o < k) ? o : k;
}

// weight transpose helper: (K,N) f32 -> (N,KP) bf16, zero-padded in K
template <int K, int N, int KP>
__device__ __forceinline__ void tp_one(const float* __restrict__ W, u16* __restrict__ Wt, int local) {
    const int n = local / KP;
    const int k = local - n * KP;
    const float v = (k < K) ? W[(size_t)k * N + n] : 0.0f;
    Wt[local] = f2bf(v);
}

// ---------------------------------------------------------------------------
// FPS v11 + fused weight transpose.
//
// Round-13 model: fps is issue-bound (round-12 confirmed: -24% issue ->
// -15% time). v11 packs TWO POINTS per f32x2 register (X[p]={x_2p,x_2p+1}):
//  - d2 for a pair costs 9 pk-ops (4 sub, 2 mul, 2 fma, 1 add) vs 2x5;
//  - running max is VALUE-ONLY pk_max (no per-point index select);
//  - the argmax index is recovered once per iteration by an exact-equality
//    descending scan over md2 (smallest jj wins -> same tie rule as the
//    strict-> ascending loop of the passing kernel).
// d2 rounding is BIT-IDENTICAL: sA=dx^2+dz^2, sB=dy^2+dw^2, d2=sA+sB --
// exactly the round-12 order. Mean summation order preserved per-component.
// ~224 -> ~188 instr/wave/iter.
// ---------------------------------------------------------------------------
__global__ __launch_bounds__(512, 2) void fps_kernel(const float* __restrict__ coords,
                                                     const float* __restrict__ times,
                                                     float* __restrict__ cent_out,
                                                     float* __restrict__ mask_out,
                                                     const float* __restrict__ W0,
                                                     const float* __restrict__ W1,
                                                     const float* __restrict__ W2,
                                                     const float* __restrict__ W3,
                                                     const float* __restrict__ Wn0,
                                                     const float* __restrict__ Wn1,
                                                     u16* __restrict__ W0t, u16* __restrict__ W1t,
                                                     u16* __restrict__ W2t, u16* __restrict__ W3t,
                                                     u16* __restrict__ Wn0t, u16* __restrict__ Wn1t) {
    const int tid = threadIdx.x;   // 0..511

    if (blockIdx.x >= 8) {
        // ---- weight-transpose blocks ----
        const int idx = (blockIdx.x - 8) * 512 + tid;
        if (idx < 8192) tp_one<32, 256, 32>(W0, W0t, idx);
        else if (idx < 139264) tp_one<256, 512, 256>(W1, W1t, idx - 8192);
        else if (idx < 532480) tp_one<512, 768, 512>(W2, W2t, idx - 139264);
        else if (idx < 1122304) tp_one<768, 768, 768>(W3, W3t, idx - 532480);
        else if (idx < 1712128) tp_one<768, 768, 768>(Wn0, Wn0t, idx - 1122304);
        else tp_one<768, 768, 768>(Wn1, Wn1t, idx - 1712128);
        return;
    }

    // ---- FPS blocks ----
    const int b = blockIdx.x;
    const int lane = tid & 63;
    const int wid = tid >> 6;      // physical wave 0..7

    __shared__ f32x4 pts[8192];            // 128 KiB (broadcast centroid fetch)
    __shared__ f32x4 cent_lds[128];
    __shared__ unsigned long long kslot[2][8];
    __shared__ float redv[16][4];

    // two points per vector: element 0 = point jj=2p, element 1 = jj=2p+1
    f32x2 X[8], Y[8], Z[8], W_[8], md2[8];
    f32x2 sxv = f32x2{0.f, 0.f}, syv = f32x2{0.f, 0.f};
    f32x2 szv = f32x2{0.f, 0.f}, swv = f32x2{0.f, 0.f};
#pragma unroll
    for (int p = 0; p < 8; ++p) {
        const int pa = (2 * p) * 512 + tid;
        const int pb = (2 * p + 1) * 512 + tid;
        const int na = b * 8192 + pa;
        const int nb = b * 8192 + pb;
        const float xa = coords[3 * na + 0], ya = coords[3 * na + 1], za = coords[3 * na + 2], wa = times[na];
        const float xb = coords[3 * nb + 0], yb = coords[3 * nb + 1], zb = coords[3 * nb + 2], wb = times[nb];
        pts[pa] = f32x4{xa, ya, za, wa};
        pts[pb] = f32x4{xb, yb, zb, wb};
        X[p] = f32x2{xa, xb};
        Y[p] = f32x2{ya, yb};
        Z[p] = f32x2{za, zb};
        W_[p] = f32x2{wa, wb};
        sxv += X[p]; syv += Y[p]; szv += Z[p]; swv += W_[p];
        md2[p] = f32x2{__builtin_inff(), __builtin_inff()};
    }
#pragma unroll
    for (int p = 0; p < 8; ++p) {
        asm volatile("" : "+v"(X[p]), "+v"(Y[p]), "+v"(Z[p]), "+v"(W_[p]));
    }

    // mean: q=jj&1 partials; sxv[q] accumulated in ascending p == ascending
    // even/odd jj -> identical order to the passing round-12 kernel
#pragma unroll
    for (int q = 0; q < 2; ++q) {
        float ax = (q == 0) ? sxv[0] : sxv[1];
        float ay = (q == 0) ? syv[0] : syv[1];
        float az = (q == 0) ? szv[0] : szv[1];
        float aw = (q == 0) ? swv[0] : swv[1];
#pragma unroll
        for (int off = 32; off > 0; off >>= 1) {
            ax += __shfl_down(ax, off);
            ay += __shfl_down(ay, off);
            az += __shfl_down(az, off);
            aw += __shfl_down(aw, off);
        }
        if (lane == 0) {
            redv[wid + 8 * q][0] = ax;
            redv[wid + 8 * q][1] = ay;
            redv[wid + 8 * q][2] = az;
            redv[wid + 8 * q][3] = aw;
        }
    }
    __syncthreads();
    float c0 = 0.f, c1 = 0.f, c2 = 0.f, c3 = 0.f;
#pragma unroll
    for (int w = 0; w < 16; ++w) { c0 += redv[w][0]; c1 += redv[w][1]; c2 += redv[w][2]; c3 += redv[w][3]; }
    c0 *= (1.0f / 8192.0f);
    c1 *= (1.0f / 8192.0f);
    c2 *= (1.0f / 8192.0f);
    c3 *= (1.0f / 8192.0f);
    f32x2 cX = f32x2{c0, c0}, cY = f32x2{c1, c1}, cZ = f32x2{c2, c2}, cW = f32x2{c3, c3};

    // ---- t = 0 (peeled): distances to the mean, md untouched ----
    {
        f32x2 vp = f32x2{-__builtin_inff(), -__builtin_inff()};
        f32x2 t2[8];
#pragma unroll
        for (int p = 0; p < 8; ++p) {
            const f32x2 dX = X[p] - cX;
            const f32x2 dY = Y[p] - cY;
            const f32x2 dZ = Z[p] - cZ;
            const f32x2 dW = W_[p] - cW;
            f32x2 sA = dX * dX;
            sA += dZ * dZ;          // {dx^2+dz^2, ...}
            f32x2 sB = dY * dY;
            sB += dW * dW;          // {dy^2+dw^2, ...}
            const f32x2 d2p = sA + sB;  // same rounding as round-12
            t2[p] = d2p;
            vp = pkmax2(vp, d2p);
        }
        float v = fmaxf(vp[0], vp[1]);
        int jb = 0;
#pragma unroll
        for (int p = 7; p >= 0; --p) {
            if (t2[p][1] == v) jb = 2 * p + 1;
            if (t2[p][0] == v) jb = 2 * p;
        }
        int idx = jb * 512 + tid;
        argmax_wave(v, idx);
        if (lane == 63) {
            const uint32_t bv = __builtin_bit_cast(uint32_t, v);
            const uint32_t mk = (bv & 0x80000000u) ? ~bv : (bv | 0x80000000u);
            kslot[0][wid] = ((unsigned long long)mk << 32) | (uint32_t)(0x7FFFFFFF - idx);
        }
        __syncthreads();
        unsigned long long k = kslot[0][lane & 7];
        k = dppmax_u64<0x111, 0xf>(k);
        k = dppmax_u64<0x112, 0xf>(k);
        k = dppmax_u64<0x114, 0xf>(k);
        const int klo = __builtin_amdgcn_readlane((int)(uint32_t)(k & 0xffffffffull), 7);
        const int sel = 0x7FFFFFFF - klo;
        const f32x4 C = pts[sel];
        cX = f32x2{C[0], C[0]}; cY = f32x2{C[1], C[1]};
        cZ = f32x2{C[2], C[2]}; cW = f32x2{C[3], C[3]};
        if (tid == (sel & 511)) {
            const int js = sel >> 9;
#pragma unroll
            for (int p = 0; p < 8; ++p) {
                if (2 * p == js) md2[p][0] = NEG_F;
                if (2 * p + 1 == js) md2[p][1] = NEG_F;
            }
        }
        if (tid == 0) cent_lds[0] = C;
    }

    // ---- t = 1..127 ----
    for (int t = 1; t < 128; ++t) {
        f32x2 vp = f32x2{-__builtin_inff(), -__builtin_inff()};
#pragma unroll
        for (int p = 0; p < 8; ++p) {
            const f32x2 dX = X[p] - cX;
            const f32x2 dY = Y[p] - cY;
            const f32x2 dZ = Z[p] - cZ;
            const f32x2 dW = W_[p] - cW;
            f32x2 sA = dX * dX;
            sA += dZ * dZ;
            f32x2 sB = dY * dY;
            sB += dW * dW;
            const f32x2 d2p = sA + sB;
            const f32x2 nmp = pkmin2(md2[p], d2p);
            md2[p] = nmp;
            vp = pkmax2(vp, nmp);
        }
        float v = fmaxf(vp[0], vp[1]);
        int jb = 0;
#pragma unroll
        for (int p = 7; p >= 0; --p) {
            if (md2[p][1] == v) jb = 2 * p + 1;
            if (md2[p][0] == v) jb = 2 * p;
        }
        int idx = jb * 512 + tid;
        argmax_wave(v, idx);
        if (lane == 63) {
            const uint32_t bv = __builtin_bit_cast(uint32_t, v);
            const uint32_t mk = (bv & 0x80000000u) ? ~bv : (bv | 0x80000000u);
            kslot[t & 1][wid] = ((unsigned long long)mk << 32) | (uint32_t)(0x7FFFFFFF - idx);
        }
        __syncthreads();
        unsigned long long k = kslot[t & 1][lane & 7];
        k = dppmax_u64<0x111, 0xf>(k);
        k = dppmax_u64<0x112, 0xf>(k);
        k = dppmax_u64<0x114, 0xf>(k);
        const int klo = __builtin_amdgcn_readlane((int)(uint32_t)(k & 0xffffffffull), 7);
        const int sel = 0x7FFFFFFF - klo;
        const f32x4 C = pts[sel];   // same address across all lanes: broadcast
        cX = f32x2{C[0], C[0]}; cY = f32x2{C[1], C[1]};
        cZ = f32x2{C[2], C[2]}; cW = f32x2{C[3], C[3]};
        if (tid == (sel & 511)) {
            const int js = sel >> 9;
#pragma unroll
            for (int p = 0; p < 8; ++p) {
                if (2 * p == js) md2[p][0] = NEG_F;
                if (2 * p + 1 == js) md2[p][1] = NEG_F;
            }
        }
        if (tid == t) cent_lds[t] = C;
    }
    // single global write after the loop
    if (tid < 128) {
        const f32x4 C = cent_lds[tid];
        f32x4* dst = (f32x4*)(cent_out + (size_t)(b * 128 + tid) * 4);
        *dst = C;
        mask_out[b * 128 + tid] = 1.0f;
    }
}

// ---------------------------------------------------------------------------
// KNN v4 (+fused gather +fused L1): unchanged from the passing round-13
// kernel.
// ---------------------------------------------------------------------------
__global__ __launch_bounds__(256) void knn_l1_kernel(const float* __restrict__ coords,
                                                     const float* __restrict__ times,
                                                     const float* __restrict__ cent,
                                                     const float* __restrict__ feat,
                                                     const u16* __restrict__ W0t,
                                                     const float* __restrict__ b0,
                                                     u16* __restrict__ h1) {
    __shared__ unsigned long long kslot[2][4];
    __shared__ int sel_lds[16];
    __shared__ __align__(16) u16 At[16 * 32];    // 1KB gathered rows
    __shared__ __align__(16) u16 Wt[256 * 32];   // 16KB W0t
    const int q = blockIdx.x;
    const int b = q >> 7;
    const int tid = threadIdx.x;
    const int lane = tid & 63;
    const int wid = tid >> 6;

    // stage W0t (8192 u16 = 1024 short8 chunks, 4 per thread)
#pragma unroll
    for (int i = 0; i < 4; ++i) {
        const int e = i * 256 + tid;            // 0..1023
        ((short8*)Wt)[e] = ((const short8*)W0t)[e];
    }

    const float c0 = cent[q * 4 + 0], c1 = cent[q * 4 + 1], c2 = cent[q * 4 + 2], c3 = cent[q * 4 + 3];
    const float cc = c0 * c0 + c1 * c1 + c2 * c2 + c3 * c3;
    float d2r[32];
#pragma unroll
    for (int s = 0; s < 32; ++s) {
        const int n = b * 8192 + s * 256 + tid;
        const float x0 = coords[3 * n], x1 = coords[3 * n + 1], x2 = coords[3 * n + 2], x3 = times[n];
        const float pp = x0 * x0 + x1 * x1 + x2 * x2 + x3 * x3;
        const float dt = x0 * c0 + x1 * c1 + x2 * c2 + x3 * c3;
        d2r[s] = cc + pp - 2.0f * dt;
    }
    for (int r = 0; r < 16; ++r) {
        float v = __builtin_inff();
        int idx = 1 << 30;
#pragma unroll
        for (int s = 0; s < 32; ++s) {
            if (d2r[s] < v) { v = d2r[s]; idx = s * 256 + tid; }
        }
        const uint32_t bv = __builtin_bit_cast(uint32_t, v);
        const uint32_t mk = (bv & 0x80000000u) ? ~bv : (bv | 0x80000000u);  // ascending map
        unsigned long long key = ((unsigned long long)mk << 32) | (uint32_t)idx;
        key = dppmin_u64<0x111, 0xf>(key);
        key = dppmin_u64<0x112, 0xf>(key);
        key = dppmin_u64<0x114, 0xf>(key);
        key = dppmin_u64<0x118, 0xf>(key);
        key = dppmin_u64<0x142, 0xa>(key);  // row_bcast:15 -> rows 1,3
        key = dppmin_u64<0x143, 0xc>(key);  // row_bcast:31 -> rows 2,3 (lane63 = wave min)
        if (lane == 63) kslot[r & 1][wid] = key;
        __syncthreads();
        unsigned long long k = kslot[r & 1][lane & 3];
        k = dppmin_u64<0x111, 0xf>(k);
        k = dppmin_u64<0x112, 0xf>(k);      // lane3 of each row = min of 4
        const int sel = __builtin_amdgcn_readlane((int)(uint32_t)(k & 0xffffffffull), 3);
        if (tid == 0) sel_lds[r] = sel;
        if (tid == (sel & 255)) {
            const int js = sel >> 8;
#pragma unroll
            for (int s = 0; s < 32; ++s)
                if (s == js) d2r[s] = __builtin_inff();
        }
    }
    __syncthreads();
    // gather 16 rows x 32 feats into At (bf16)
#pragma unroll
    for (int i = 0; i < 2; ++i) {
        const int e = i * 256 + tid;        // 0..511
        const int r = e >> 5;
        const int c = e & 31;
        const int n = b * 8192 + sel_lds[r];
        At[e] = f2bf(feat[(size_t)n * 32 + c]);
    }
    __syncthreads();
    // L1: h1(16x256) = relu(At(16x32) @ W0 + b0); 4 n-tiles per wave
    const int arow = lane & 15;
    const int koff = (lane >> 4) * 8;
    const short8 afrag = *(const short8*)(At + arow * 32 + koff);
#pragma unroll
    for (int i = 0; i < 4; ++i) {
        const int nbase = (wid * 4 + i) * 16;
        const short8 bfrag = *(const short8*)(Wt + (nbase + (lane & 15)) * 32 + koff);
        f32x4 acc = f32x4{0.f, 0.f, 0.f, 0.f};
        acc = __builtin_amdgcn_mfma_f32_16x16x32_bf16(afrag, bfrag, acc, 0, 0, 0);
        const int col = nbase + (lane & 15);
        const float bv = b0[col];
        const int row0 = (lane >> 4) * 4;
#pragma unroll
        for (int rg = 0; rg < 4; ++rg) {
            const float vv = fmaxf(acc[rg] + bv, 0.0f);
            h1[(size_t)(q * 16 + row0 + rg) * 256 + col] = f2bf(vv);
        }
    }
}

// ---------------------------------------------------------------------------
// bf16 MFMA GEMM: C(M,N) = relu?(A(M,K) @ W(K,N) + bias), W given as Wt(N,K).
// BM x 128 tile (BM = 128 or 64), BK=64, 4 waves, global_load_lds width 16,
// source-side XOR swizzle so ds_read_b128 is ~conflict-free.
// BM=128: waves in 2x2 of 64x64 (4x4 frags). BM=64: waves own 64x32 column
// strips (4x2 frags) -- doubles grid parallelism for small-M GEMMs.
// POOL=1 (BM=128 only): fuse the 16-row max-pool into the epilogue.
// ---------------------------------------------------------------------------
template <int BM, int RELU, int OUTF32, int POOL>
__global__ __launch_bounds__(256) void gemm_kernel(const u16* __restrict__ A,
                                                   const u16* __restrict__ Bt,
                                                   const float* __restrict__ bias,
                                                   void* __restrict__ Cv,
                                                   int M, int N, int K) {
    (void)M;
    constexpr int NREP = (BM == 128) ? 4 : 2;
    __shared__ __align__(16) u16 As[BM * 64];
    __shared__ __align__(16) u16 Bs[128 * 64];
    const int tid = threadIdx.x;
    const int lane = tid & 63;
    const int wid = tid >> 6;
    const int brow = blockIdx.x * BM;
    const int bcol = blockIdx.y * 128;
    const int wm = (BM == 128) ? (wid >> 1) * 64 : 0;
    const int wn = (BM == 128) ? (wid & 1) * 64 : wid * 32;

    f32x4 acc[4][NREP];
#pragma unroll
    for (int m = 0; m < 4; ++m)
#pragma unroll
        for (int n = 0; n < NREP; ++n)
            acc[m][n] = f32x4{0.f, 0.f, 0.f, 0.f};

    const int srow = tid >> 3;    // 0..31
    const int schunk = tid & 7;   // 16B chunk within a 128B row
    const uint32_t lds_wave_base = (uint32_t)(wid * 1024);

    for (int k0 = 0; k0 < K; k0 += 64) {
#pragma unroll
        for (int i = 0; i < BM / 32; ++i) {
            const int row = i * 32 + srow;
            const int sc = schunk ^ (row & 7);  // inverse-swizzled SOURCE chunk
            const u16* ga = A + (size_t)(brow + row) * K + (size_t)(k0 + sc * 8);
            const uint32_t lb = (uint32_t)(i * 4096) + lds_wave_base;
            gload_lds16(ga, (char*)As + lb);
        }
#pragma unroll
        for (int i = 0; i < 4; ++i) {
            const int row = i * 32 + srow;
            const int sc = schunk ^ (row & 7);
            const u16* gb = Bt + (size_t)(bcol + row) * K + (size_t)(k0 + sc * 8);
            const uint32_t lb = (uint32_t)(i * 4096) + lds_wave_base;
            gload_lds16(gb, (char*)Bs + lb);
        }
        __syncthreads();
#pragma unroll
        for (int kc = 0; kc < 2; ++kc) {
            short8 af[4], bfr[NREP];
#pragma unroll
            for (int m = 0; m < 4; ++m) {
                const int row = wm + m * 16 + (lane & 15);
                const int sc = (kc * 4 + (lane >> 4)) ^ (row & 7);
                af[m] = *(const short8*)(As + row * 64 + sc * 8);
            }
#pragma unroll
            for (int n = 0; n < NREP; ++n) {
                const int row = wn + n * 16 + (lane & 15);
                const int sc = (kc * 4 + (lane >> 4)) ^ (row & 7);
                bfr[n] = *(const short8*)(Bs + row * 64 + sc * 8);
            }
#pragma unroll
            for (int m = 0; m < 4; ++m)
#pragma unroll
                for (int n = 0; n < NREP; ++n)
                    acc[m][n] = __builtin_amdgcn_mfma_f32_16x16x32_bf16(af[m], bfr[n], acc[m][n], 0, 0, 0);
        }
        __syncthreads();
    }

    if (POOL) {
#pragma unroll
        for (int m = 0; m < 4; ++m) {
            const int prow = (brow >> 4) + (wm >> 4) + m;
#pragma unroll
            for (int n = 0; n < NREP; ++n) {
                float v = fmaxf(fmaxf(acc[m][n][0], acc[m][n][1]),
                                fmaxf(acc[m][n][2], acc[m][n][3]));
                v = fmaxf(v, __shfl_xor(v, 16));
                v = fmaxf(v, __shfl_xor(v, 32));
                const int col = bcol + wn + n * 16 + (lane & 15);
                v += bias[col];
                if (lane < 16) ((u16*)Cv)[(size_t)prow * N + col] = f2bf(v);
            }
        }
    } else {
#pragma unroll
        for (int m = 0; m < 4; ++m) {
            const int row0 = brow + wm + m * 16 + ((lane >> 4) << 2);
#pragma unroll
            for (int n = 0; n < NREP; ++n) {
                const int col = bcol + wn + n * 16 + (lane & 15);
                const float bv = bias[col];
#pragma unroll
                for (int r = 0; r < 4; ++r) {
                    float v = acc[m][n][r] + bv;
                    if (RELU) v = fmaxf(v, 0.0f);
                    if (OUTF32) ((float*)Cv)[(size_t)(row0 + r) * N + col] = v;
                    else ((u16*)Cv)[(size_t)(row0 + r) * N + col] = f2bf(v);
                }
            }
        }
    }
}

// ---------------------------------------------------------------------------
extern "C" void kernel_launch(void* const* d_in, const int* in_sizes, int n_in,
                              void* d_out, int out_size, void* d_ws, size_t ws_size,
                              hipStream_t stream) {
    (void)in_sizes; (void)n_in; (void)out_size; (void)ws_size;
    const float* coords = (const float*)d_in[0];
    const float* features = (const float*)d_in[1];
    const float* times = (const float*)d_in[3];
    const float* W0 = (const float*)d_in[4];
    const float* b0 = (const float*)d_in[5];
    const float* W1 = (const float*)d_in[6];
    const float* b1 = (const float*)d_in[7];
    const float* W2 = (const float*)d_in[8];
    const float* b2 = (const float*)d_in[9];
    const float* W3 = (const float*)d_in[10];
    const float* b3 = (const float*)d_in[11];
    const float* Wn0 = (const float*)d_in[12];
    const float* bn0 = (const float*)d_in[13];
    const float* Wn1 = (const float*)d_in[14];
    const float* bn1 = (const float*)d_in[15];

    char* ws = (char*)d_ws;
    u16* W0t = (u16*)(ws + 81920);            // 256x32
    u16* W1t = (u16*)(ws + 114688);           // 512x256
    u16* W2t = (u16*)(ws + 376832);           // 768x512
    u16* W3t = (u16*)(ws + 1163264);          // 768x768
    u16* Wn0t = (u16*)(ws + 2342912);         // 768x768
    u16* Wn1t = (u16*)(ws + 3522560);         // 768x768
    u16* bufX = (u16*)(ws + 4702208);         // 16384x768 bf16 max
    u16* bufY = (u16*)(ws + 29868032);        // 16384x768 bf16 max

    float* tokens_out = (float*)d_out;                    // (8,128,768)
    float* cent_out = (float*)d_out + 786432;             // (8,128,4)
    float* mask_out = (float*)d_out + 786432 + 4096;      // (8,128)

    // FPS (blocks 0-7) + all weight transposes (blocks 8..4503) in one launch
    fps_kernel<<<4504, 512, 0, stream>>>(coords, times, cent_out, mask_out,
                                         W0, W1, W2, W3, Wn0, Wn1,
                                         W0t, W1t, W2t, W3t, Wn0t, Wn1t);
    // KNN top-16 + fused gather + fused L1 -> h1 (16384x256 bf16) in bufX
    knn_l1_kernel<<<1024, 256, 0, stream>>>(coords, times, cent_out, features,
                                            W0t, b0, bufX);

    // MLP layers 2-4 on gathered rows (M = 16384)
    gemm_kernel<128, 1, 0, 0><<<dim3(128, 4), 256, 0, stream>>>(bufX, W1t, b1, bufY, 16384, 512, 256);
    gemm_kernel<128, 1, 0, 0><<<dim3(128, 6), 256, 0, stream>>>(bufY, W2t, b2, bufX, 16384, 768, 512);
    // layer 4 with fused 16-row max-pool -> pooled (1024x768) in bufY
    gemm_kernel<128, 0, 0, 1><<<dim3(128, 6), 256, 0, stream>>>(bufX, W3t, b3, bufY, 16384, 768, 768);

    // token MLP (M = 1024) -- BM=64 tiles double the grid to 96 blocks
    gemm_kernel<64, 1, 0, 0><<<dim3(16, 6), 256, 0, stream>>>(bufY, Wn0t, bn0, bufX, 1024, 768, 768);
    gemm_kernel<64, 0, 1, 0><<<dim3(16, 6), 256, 0, stream>>>(bufX, Wn1t, bn1, tokens_out, 1024, 768, 768);
}